// Round 9
// baseline (429.591 us; speedup 1.0000x reference)
//
#include <hip/hip_runtime.h>
#include <hip/hip_bf16.h>

// Problem constants (B=4, L=2048, D=512, H=8, DK=64, FF=2048, U=40)
#define BB 4
#define LL 2048
#define DD 512
#define HH 8
#define DKK 64
#define FF 2048

typedef __bf16  bf16x8  __attribute__((ext_vector_type(8)));
typedef float   floatx4 __attribute__((ext_vector_type(4)));

// async 16B global->LDS copy (global_load_lds_dwordx4)
__device__ __forceinline__ void async_cp16(const void* g, void* l) {
    __builtin_amdgcn_global_load_lds(
        (const __attribute__((address_space(1))) unsigned int*)g,
        (__attribute__((address_space(3))) unsigned int*)l,
        16, 0, 0);
}

// exact-grade GELU: A&S 7.1.26 erf, |err| < 1.5e-7 (fp32-exact at our scale).
__device__ __forceinline__ float gelu_f(float v) {
    float z  = v * 0.70710678118654752f;
    float az = fabsf(z);
    float t  = __builtin_amdgcn_rcpf(1.0f + 0.3275911f * az);
    float p  = ((((1.061405429f * t - 1.453152027f) * t + 1.421413741f) * t
                 - 0.284496736f) * t + 0.254829592f) * t;
    float e  = __expf(-z * z);
    float er = 1.0f - p * e;
    er = (z < 0.0f) ? -er : er;
    return 0.5f * v * (1.0f + er);
}

// ---------- prep: transpose 512x512 fp32 -> bf16 (N,K); Wq/Wk also lo-part ----
__global__ __launch_bounds__(256) void prep_w(
    const float* __restrict__ Wq, const float* __restrict__ Wk,
    const float* __restrict__ Wv, const float* __restrict__ Wo,
    __bf16* __restrict__ wb)
{
    const size_t SZ = (size_t)DD * DD;
    int z = blockIdx.z;
    const float* s = (z == 0) ? Wq : (z == 1) ? Wk : (z == 2) ? Wv : Wo;
    __bf16* hi; __bf16* lo = nullptr;
    if (z == 0)      { hi = wb;          lo = wb + SZ; }
    else if (z == 1) { hi = wb + 2 * SZ; lo = wb + 3 * SZ; }
    else if (z == 2) { hi = wb + 4 * SZ; }
    else             { hi = wb + 5 * SZ; }
    int idx = blockIdx.x * 256 + threadIdx.x;   // 0..512*512-1
    int k = idx >> 9, n = idx & 511;
    float v = s[idx];
    __bf16 h = (__bf16)v;
    hi[(size_t)n * DD + k] = h;
    if (lo) lo[(size_t)n * DD + k] = (__bf16)(v - (float)h);
}

// ---------- cast conv weights fp32 (N,K) -> bf16 -----------------------------
__global__ __launch_bounds__(256) void cast_cw(
    const float* __restrict__ c1w, const float* __restrict__ c2w,
    __bf16* __restrict__ d1, __bf16* __restrict__ d2)
{
    const float* s = blockIdx.z ? c2w : c1w;
    __bf16* d = blockIdx.z ? d2 : d1;
    int idx = blockIdx.x * 256 + threadIdx.x;   // 0..FF*DD-1
    d[idx] = (__bf16)s[idx];
}

// ---------- split-cast x fp32 -> bf16 hi + lo --------------------------------
__global__ __launch_bounds__(256) void split_cast_x(
    const float* __restrict__ x, __bf16* __restrict__ xhi, __bf16* __restrict__ xlo)
{
    int idx = blockIdx.x * 256 + threadIdx.x;
    float v = x[idx];
    __bf16 h = (__bf16)v;
    xhi[idx] = h;
    xlo[idx] = (__bf16)(v - (float)h);
}

// ---------- MFMA GEMM: C[M,N] = act(A[M,K] @ B[N,K]^T + bias) ----------------
// 128x128 tile, 3-buffer 2-deep pipeline, SINGLE barrier + counted vmcnt per
// k-step (stage at iter t targets the buffer last read before the END-of-iter
// t-1 barrier -> second barrier redundant). Bank swizzle per rule #21 (r8:
// verified conflicts -> 0). XCD swizzle + swapped-operand vector epilogue.
template<int ACT, bool BIAS, bool OUT_BF16>
__global__ __launch_bounds__(256) void gemm_mfma(
    const __bf16* __restrict__ A, const __bf16* __restrict__ B,
    const float* __restrict__ bias, void* __restrict__ Cv,
    int M, int N, int K)
{
    __shared__ __bf16 As[3][128 * 32];
    __shared__ __bf16 Bs[3][128 * 32];
    const int tid = threadIdx.x;
    const int wave = tid >> 6, lane = tid & 63;
    const int gx = gridDim.x;
    const int nwg = gx * gridDim.y;
    const int hw = blockIdx.y * gx + blockIdx.x;
    const int virt = ((nwg & 7) == 0) ? ((hw & 7) * (nwg >> 3) + (hw >> 3)) : hw;
    const int m0 = (virt / gx) * 128, n0 = (virt % gx) * 128;
    const int wm = (wave >> 1) * 64, wn = (wave & 1) * 64;
    const int l15 = lane & 15, kq = lane >> 4;

    auto stage = [&](int buf, int k0) {           // 4 vmem insts per wave
        #pragma unroll
        for (int p = 0; p < 2; p++) {
            int c = p * 256 + tid;                // 16B chunk id 0..511
            int row = c >> 2;
            int col = ((c & 3) ^ ((row >> 1) & 3)) * 8;   // inverse-swizzled src
            async_cp16(A + (size_t)(m0 + row) * K + k0 + col, &As[buf][c * 8]);
            async_cp16(B + (size_t)(n0 + row) * K + k0 + col, &Bs[buf][c * 8]);
        }
    };

    floatx4 acc[4][4] = {};

    const int nt = K >> 5;
    stage(0, 0);
    stage(1, 32);
    asm volatile("s_waitcnt vmcnt(4)" ::: "memory");   // tile0 ready, tile1 in flight
    __builtin_amdgcn_s_barrier();
    int bi = 0;                                   // buffer of current tile
    for (int t = 0; t < nt; t++) {
        int k2 = (t + 2) << 5;
        if (k2 < K) {
            int b2 = bi + 2; if (b2 >= 3) b2 -= 3;
            stage(b2, k2);                        // overwrites buffer read at t-1
        }
        asm volatile("" ::: "memory");
        bf16x8 af[4], bfr[4];
        #pragma unroll
        for (int i = 0; i < 4; i++) {
            int ra = wm + i * 16 + l15;
            af[i] = *(const bf16x8*)(&As[bi][ra * 32 + ((kq ^ ((ra >> 1) & 3)) << 3)]);
        }
        #pragma unroll
        for (int j = 0; j < 4; j++) {
            int rb = wn + j * 16 + l15;
            bfr[j] = *(const bf16x8*)(&Bs[bi][rb * 32 + ((kq ^ ((rb >> 1) & 3)) << 3)]);
        }
        #pragma unroll
        for (int i = 0; i < 4; i++)
            #pragma unroll
            for (int j = 0; j < 4; j++)
                acc[i][j] = __builtin_amdgcn_mfma_f32_16x16x32_bf16(bfr[j], af[i], acc[i][j], 0, 0, 0);
        asm volatile("" ::: "memory");
        if (t + 2 < nt)      asm volatile("s_waitcnt vmcnt(4)" ::: "memory"); // tile t+1 done
        else if (t + 1 < nt) asm volatile("s_waitcnt vmcnt(0)" ::: "memory");
        if (t + 1 < nt) __builtin_amdgcn_s_barrier();
        if (++bi == 3) bi = 0;
    }
    // epilogue: thread holds C[m][n..n+3], m = m0+wm+i*16+l15, n = n0+wn+j*16+kq*4
    #pragma unroll
    for (int i = 0; i < 4; i++) {
        int m = m0 + wm + i * 16 + l15;
        #pragma unroll
        for (int j = 0; j < 4; j++) {
            int n = n0 + wn + j * 16 + kq * 4;
            floatx4 v4 = acc[i][j];
            if (BIAS) {
                float4 bv = *(const float4*)&bias[n];
                v4[0] += bv.x; v4[1] += bv.y; v4[2] += bv.z; v4[3] += bv.w;
            }
            if (ACT == 1) {
                v4[0] = gelu_f(v4[0]); v4[1] = gelu_f(v4[1]);
                v4[2] = gelu_f(v4[2]); v4[3] = gelu_f(v4[3]);
            }
            if (OUT_BF16) {
                union { __bf16 b[4]; uint2 u; } pk;
                pk.b[0] = (__bf16)v4[0]; pk.b[1] = (__bf16)v4[1];
                pk.b[2] = (__bf16)v4[2]; pk.b[3] = (__bf16)v4[3];
                *(uint2*)((__bf16*)Cv + (size_t)m * N + n) = pk.u;
            } else {
                *(float4*)((float*)Cv + (size_t)m * N + n) = *(float4*)&v4;
            }
        }
    }
}

// ---------- split-precision MFMA GEMM (near-fp32): C = (Ah+Al)(Bh+Bl)^T ------
// Same 3-buffer single-barrier pipeline (8 vmem/stage -> vmcnt(8)).
__global__ __launch_bounds__(256) void gemm_mfma_split(
    const __bf16* __restrict__ Ah, const __bf16* __restrict__ Al,
    const __bf16* __restrict__ Bh, const __bf16* __restrict__ Bl,
    float* __restrict__ C, int M, int N, int K)
{
    __shared__ __bf16 Ahs[3][128 * 32];
    __shared__ __bf16 Als[3][128 * 32];
    __shared__ __bf16 Bhs[3][128 * 32];
    __shared__ __bf16 Bls[3][128 * 32];
    const int tid = threadIdx.x;
    const int wave = tid >> 6, lane = tid & 63;
    const int gx = gridDim.x;
    const int nwg = gx * gridDim.y;
    const int hw = blockIdx.y * gx + blockIdx.x;
    const int virt = ((nwg & 7) == 0) ? ((hw & 7) * (nwg >> 3) + (hw >> 3)) : hw;
    const int m0 = (virt / gx) * 128, n0 = (virt % gx) * 128;
    const int wm = (wave >> 1) * 64, wn = (wave & 1) * 64;
    const int l15 = lane & 15, kq = lane >> 4;

    auto stage = [&](int buf, int k0) {           // 8 vmem insts per wave
        #pragma unroll
        for (int p = 0; p < 2; p++) {
            int c = p * 256 + tid;
            int row = c >> 2;
            int col = ((c & 3) ^ ((row >> 1) & 3)) * 8;
            size_t goA = (size_t)(m0 + row) * K + k0 + col;
            size_t goB = (size_t)(n0 + row) * K + k0 + col;
            async_cp16(Ah + goA, &Ahs[buf][c * 8]);
            async_cp16(Al + goA, &Als[buf][c * 8]);
            async_cp16(Bh + goB, &Bhs[buf][c * 8]);
            async_cp16(Bl + goB, &Bls[buf][c * 8]);
        }
    };

    floatx4 acc[4][4] = {};

    const int nt = K >> 5;
    stage(0, 0);
    stage(1, 32);
    asm volatile("s_waitcnt vmcnt(8)" ::: "memory");
    __builtin_amdgcn_s_barrier();
    int bi = 0;
    for (int t = 0; t < nt; t++) {
        int k2 = (t + 2) << 5;
        if (k2 < K) {
            int b2 = bi + 2; if (b2 >= 3) b2 -= 3;
            stage(b2, k2);
        }
        asm volatile("" ::: "memory");
        bf16x8 ah[4], al[4], bh[4], bl[4];
        #pragma unroll
        for (int i = 0; i < 4; i++) {
            int ra = wm + i * 16 + l15;
            int off = ra * 32 + ((kq ^ ((ra >> 1) & 3)) << 3);
            ah[i] = *(const bf16x8*)(&Ahs[bi][off]);
            al[i] = *(const bf16x8*)(&Als[bi][off]);
        }
        #pragma unroll
        for (int j = 0; j < 4; j++) {
            int rb = wn + j * 16 + l15;
            int off = rb * 32 + ((kq ^ ((rb >> 1) & 3)) << 3);
            bh[j] = *(const bf16x8*)(&Bhs[bi][off]);
            bl[j] = *(const bf16x8*)(&Bls[bi][off]);
        }
        #pragma unroll
        for (int i = 0; i < 4; i++)
            #pragma unroll
            for (int j = 0; j < 4; j++) {
                acc[i][j] = __builtin_amdgcn_mfma_f32_16x16x32_bf16(bh[j], ah[i], acc[i][j], 0, 0, 0);
                acc[i][j] = __builtin_amdgcn_mfma_f32_16x16x32_bf16(bl[j], ah[i], acc[i][j], 0, 0, 0);
                acc[i][j] = __builtin_amdgcn_mfma_f32_16x16x32_bf16(bh[j], al[i], acc[i][j], 0, 0, 0);
            }
        asm volatile("" ::: "memory");
        if (t + 2 < nt)      asm volatile("s_waitcnt vmcnt(8)" ::: "memory");
        else if (t + 1 < nt) asm volatile("s_waitcnt vmcnt(0)" ::: "memory");
        if (t + 1 < nt) __builtin_amdgcn_s_barrier();
        if (++bi == 3) bi = 0;
    }
    #pragma unroll
    for (int i = 0; i < 4; i++) {
        int m = m0 + wm + i * 16 + l15;
        #pragma unroll
        for (int j = 0; j < 4; j++) {
            int n = n0 + wn + j * 16 + kq * 4;
            *(float4*)(C + (size_t)m * N + n) = *(float4*)&acc[i][j];
        }
    }
}

// ------------- M[b,h,l] = max_s(q·k_s) - sum_s(q·k_s)/L  (sampled) ---------
// 16-lane sum via DPP-fused v_add_f32 (pure VALU; no LDS-pipe ds_swizzle).
__device__ __forceinline__ float dpp_sum16(float p) {
    int t;
    t = __builtin_amdgcn_update_dpp(0, __float_as_int(p), 0xB1,  0xF, 0xF, true); // quad_perm [1,0,3,2]
    p += __int_as_float(t);
    t = __builtin_amdgcn_update_dpp(0, __float_as_int(p), 0x4E,  0xF, 0xF, true); // quad_perm [2,3,0,1]
    p += __int_as_float(t);
    t = __builtin_amdgcn_update_dpp(0, __float_as_int(p), 0x141, 0xF, 0xF, true); // row_half_mirror
    p += __int_as_float(t);
    t = __builtin_amdgcn_update_dpp(0, __float_as_int(p), 0x140, 0xF, 0xF, true); // row_mirror
    p += __int_as_float(t);
    return p;
}

__global__ __launch_bounds__(256) void calc_m(
    const float* __restrict__ Q, const float* __restrict__ Kb,
    const int* __restrict__ sidx, float* __restrict__ Mo, int U)
{
    __shared__ int   js[64];
    __shared__ float red_mx[2][HH];
    __shared__ float red_sm[2][HH];
    int i = blockIdx.x;
    int b = i & 3, l = i >> 2;
    int tid = threadIdx.x;
    if (tid < U) js[tid] = sidx[l * U + tid];
    int e    = (tid & 127) * 4;          // element index within 512-wide row
    int slot = tid >> 7;                 // 0/1: even/odd samples
    const float* qr = Q + ((size_t)(b * LL + l) * DD);
    float4 q = *(const float4*)(qr + e);
    const float* kbase = Kb + ((size_t)b * LL) * DD + e;
    __syncthreads();
    float mx = -1e30f, sm = 0.f;
    for (int s = slot; s < U; s += 2) {
        int j = js[s];
        float4 kv = *(const float4*)(kbase + (size_t)j * DD);
        float p = q.x * kv.x + q.y * kv.y + q.z * kv.z + q.w * kv.w;
        p = dpp_sum16(p);
        mx = fmaxf(mx, p);
        sm += p;
    }
    if ((tid & 15) == 0) {
        int head = (tid >> 4) & 7;
        red_mx[slot][head] = mx;
        red_sm[slot][head] = sm;
    }
    __syncthreads();
    if (tid < HH) {
        float m2 = fmaxf(red_mx[0][tid], red_mx[1][tid]);
        float s2 = red_sm[0][tid] + red_sm[1][tid];
        Mo[((size_t)(b * HH + tid)) * LL + l] = m2 - s2 * (1.0f / (float)LL);
    }
}

// ------------- radix-select top-40 per (b,h) row of M ----------------------
__global__ __launch_bounds__(256) void topk_k(
    const float* __restrict__ Mo, int* __restrict__ top, int U)
{
    __shared__ unsigned int hist[256];
    __shared__ unsigned int wsum[4];
    __shared__ unsigned int bc[2];
    __shared__ int ties[LL];
    __shared__ int cnt2[2];
    int bh = blockIdx.x, tid = threadIdx.x;
    int lane = tid & 63, w = tid >> 6;

    unsigned int my[8];
    #pragma unroll
    for (int i = 0; i < 8; i++) {
        unsigned int u = __float_as_uint(Mo[(size_t)bh * LL + tid + i * 256]);
        my[i] = u ^ ((u >> 31) ? 0xFFFFFFFFu : 0x80000000u);  // order-preserving
    }

    unsigned int prefix = 0, pmask = 0;
    unsigned int need = (unsigned int)U;
    unsigned int above = 0;

    for (int pass = 0; pass < 4; pass++) {
        int shift = 24 - pass * 8;
        hist[tid] = 0;
        __syncthreads();
        #pragma unroll
        for (int i = 0; i < 8; i++) {
            unsigned int u = my[i];
            if ((u & pmask) == prefix)
                atomicAdd(&hist[(u >> shift) & 255u], 1u);
        }
        __syncthreads();
        unsigned int h = hist[tid];
        #pragma unroll
        for (int off = 1; off < 64; off <<= 1) {
            unsigned int o = __shfl_down(h, off);
            if (lane + off < 64) h += o;
        }
        if (lane == 0) wsum[w] = h;
        __syncthreads();
        unsigned int tail = 0;
        #pragma unroll
        for (int w2 = 1; w2 < 4; w2++) if (w2 > w) tail += wsum[w2];
        h += tail;
        hist[tid] = h;
        __syncthreads();
        unsigned int St = h;
        unsigned int St1 = (tid < 255) ? hist[tid + 1] : 0u;
        if (St >= need && St1 < need) { bc[0] = (unsigned int)tid; bc[1] = St1; }
        __syncthreads();
        unsigned int dig = bc[0], abv = bc[1];
        above += abv;
        need -= abv;
        prefix |= dig << shift;
        pmask |= 0xFFu << shift;
        __syncthreads();
    }

    if (tid == 0) { cnt2[0] = 0; cnt2[1] = 0; }
    __syncthreads();
    #pragma unroll
    for (int i = 0; i < 8; i++) {
        unsigned int u = my[i];
        int idx = tid + i * 256;
        if (u > prefix) {
            int pos = atomicAdd(&cnt2[0], 1);
            top[bh * U + pos] = idx;
        } else if (u == prefix) {
            int pos = atomicAdd(&cnt2[1], 1);
            ties[pos] = idx;
        }
    }
    __syncthreads();
    int tcnt = cnt2[1];
    #pragma unroll
    for (int i = 0; i < 8; i++) {
        unsigned int u = my[i];
        if (u == prefix) {
            int idx = tid + i * 256;
            int rank = 0;
            for (int j = 0; j < tcnt; j++) rank += (ties[j] < idx) ? 1 : 0;
            if (rank < (int)need) top[bh * U + (int)above + rank] = idx;
        }
    }
}

// ------------- Vmean[b,h,d] (V bf16), 256 threads/block --------------------
__global__ __launch_bounds__(256) void vmean_k(
    const __bf16* __restrict__ V, float* __restrict__ Vm)
{
    __shared__ float osum[4][DKK];
    int bh = blockIdx.x;
    int b = bh >> 3, h = bh & 7;
    int tid = threadIdx.x, d = tid & 63, part = tid >> 6;
    const __bf16* vp = V + ((size_t)(b * LL + part * 512) * DD + h * DKK + d);
    float s = 0.f;
    for (int i = 0; i < 512; i++) s += (float)vp[(size_t)i * DD];
    osum[part][d] = s;
    __syncthreads();
    if (tid < DKK)
        Vm[bh * DKK + tid] = (osum[0][tid] + osum[1][tid] + osum[2][tid] + osum[3][tid]) * (1.0f / (float)LL);
}

// ------------- gather Q[top] -> qred[32][48][64] bf16, scaled by 1/8 -------
__global__ __launch_bounds__(256) void gather_qred(
    const float* __restrict__ Q, const int* __restrict__ top,
    __bf16* __restrict__ qred, int U)
{
    int bh = blockIdx.y;
    int b = bh >> 3, h = bh & 7;
    int e = blockIdx.x * 256 + threadIdx.x;   // 0..48*64-1
    int u = e >> 6, d = e & 63;
    float v = 0.f;
    if (u < U) {
        int l = top[bh * U + u];
        v = Q[((size_t)(b * LL + l) * DD + h * DKK) + d] * 0.125f;
    }
    qred[(size_t)bh * 48 * DKK + e] = (__bf16)v;
}

// ------------- batched S[bh][48][2048] = qred[bh] @ K[bh]^T (MFMA) ---------
// Swapped-operand MFMA -> float4 stores of S.
__global__ __launch_bounds__(256) void gemm_s(
    const __bf16* __restrict__ qred, const float* __restrict__ Kb,
    float* __restrict__ S)
{
    __shared__ __bf16 Qs[2 * 48 * 32];    // 2 panels of BK=32
    __shared__ __bf16 Ks[2 * 128 * 32];
    int bh = blockIdx.y, nc = blockIdx.x;
    int b = bh >> 3, h = bh & 7, l0 = nc * 128;
    int tid = threadIdx.x;
    const unsigned int* qsrc = (const unsigned int*)(qred + (size_t)bh * 48 * DKK);
    unsigned int* qdst = (unsigned int*)Qs;
    #pragma unroll
    for (int t = 0; t < 6; t++) {
        int ui = tid + t * 256;            // 0..1535
        int u = ui >> 5, kp = ui & 31;
        int p = kp >> 4, kl2 = kp & 15;
        qdst[p * 768 + u * 16 + kl2] = qsrc[ui];
    }
    #pragma unroll
    for (int t = 0; t < 8; t++) {
        int fi = tid + t * 256;            // 0..2047
        int row = fi >> 4, k4 = fi & 15;
        int p = k4 >> 3, kl = (k4 & 7) * 4;
        float4 kv = *(const float4*)(Kb + ((size_t)(b * LL + l0 + row) * DD + h * DKK + k4 * 4));
        __bf16* dst = Ks + p * 128 * 32 + row * 32 + kl;
        dst[0] = (__bf16)kv.x; dst[1] = (__bf16)kv.y;
        dst[2] = (__bf16)kv.z; dst[3] = (__bf16)kv.w;
    }
    __syncthreads();
    int wave = tid >> 6, lane = tid & 63, l15 = lane & 15, kq = lane >> 4;
    floatx4 acc[3][2] = {};
    #pragma unroll
    for (int p = 0; p < 2; p++) {
        bf16x8 bq[2];
        #pragma unroll
        for (int j = 0; j < 2; j++)
            bq[j] = *(const bf16x8*)(Ks + p * 4096 + (wave * 32 + j * 16 + l15) * 32 + kq * 8);
        #pragma unroll
        for (int i = 0; i < 3; i++) {
            bf16x8 aq = *(const bf16x8*)(Qs + p * 1536 + (i * 16 + l15) * 32 + kq * 8);
            #pragma unroll
            for (int j = 0; j < 2; j++)
                acc[i][j] = __builtin_amdgcn_mfma_f32_16x16x32_bf16(bq[j], aq, acc[i][j], 0, 0, 0);
        }
    }
    // thread holds S[row][col..col+3]: row = i*16+l15, col = l0+wave*32+j*16+kq*4
    #pragma unroll
    for (int i = 0; i < 3; i++) {
        int row = i * 16 + l15;
        #pragma unroll
        for (int j = 0; j < 2; j++) {
            int col = l0 + wave * 32 + j * 16 + kq * 4;
            *(float4*)&S[((size_t)bh * 48 + row) * LL + col] = *(float4*)&acc[i][j];
        }
    }
}

// ------------- row softmax, in-place: S row fp32 -> P row bf16 -------------
__global__ __launch_bounds__(256) void softmax_p(float* __restrict__ S, int U)
{
    __shared__ float red[256];
    int row = blockIdx.x;              // 32*U rows
    int bh = row / U, u = row % U;
    float* sr = S + ((size_t)bh * 48 + u) * LL;
    int tid = threadIdx.x;
    float sc[8]; float mx = -1e30f;
    #pragma unroll
    for (int i = 0; i < 8; i++) { sc[i] = sr[tid + i * 256]; mx = fmaxf(mx, sc[i]); }
    red[tid] = mx; __syncthreads();
    for (int s = 128; s > 0; s >>= 1) { if (tid < s) red[tid] = fmaxf(red[tid], red[tid + s]); __syncthreads(); }
    mx = red[0]; __syncthreads();
    float se = 0.f;
    #pragma unroll
    for (int i = 0; i < 8; i++) { sc[i] = __expf(sc[i] - mx); se += sc[i]; }
    red[tid] = se; __syncthreads();
    for (int s = 128; s > 0; s >>= 1) { if (tid < s) red[tid] += red[tid + s]; __syncthreads(); }
    float inv = 1.0f / red[0];
    __bf16* pr = (__bf16*)sr;
    #pragma unroll
    for (int i = 0; i < 8; i++) pr[tid + i * 256] = (__bf16)(sc[i] * inv);
}

// ------------- upd[bh][u][d] = sum_l P[u][l] * V[b,h,l,d], 4 u per block ----
__global__ __launch_bounds__(256) void pv_k(
    const float* __restrict__ S, const __bf16* __restrict__ V,
    float* __restrict__ upd, int U)
{
    __shared__ __bf16 pls[4 * LL];      // 16 KB
    __shared__ float osum[4][4][DKK];   // part, u', d
    int bh = blockIdx.y, uc = blockIdx.x;
    int b = bh >> 3, h = bh & 7, tid = threadIdx.x;
    #pragma unroll
    for (int t = 0; t < 16; t++) {
        int ui = tid + t * 256;          // 0..4095 uints
        int up = ui >> 10, lw = ui & 1023;
        const unsigned int* src = (const unsigned int*)(S + ((size_t)bh * 48 + uc * 4 + up) * LL);
        ((unsigned int*)pls)[up * 1024 + lw] = src[lw];
    }
    __syncthreads();
    int d = tid & 63, part = tid >> 6;
    float a0 = 0.f, a1 = 0.f, a2 = 0.f, a3 = 0.f;
    const __bf16* vp = V + ((size_t)(b * LL + part * 512) * DD + h * DKK + d);
    int lbase = part * 512;
    for (int i = 0; i < 512; i++) {
        float v = (float)vp[(size_t)i * DD];
        int l = lbase + i;
        a0 += (float)pls[l] * v;
        a1 += (float)pls[LL + l] * v;
        a2 += (float)pls[2 * LL + l] * v;
        a3 += (float)pls[3 * LL + l] * v;
    }
    osum[part][0][d] = a0; osum[part][1][d] = a1;
    osum[part][2][d] = a2; osum[part][3][d] = a3;
    __syncthreads();
    int u2 = tid >> 6;
    float s = osum[0][u2][d] + osum[1][u2][d] + osum[2][u2][d] + osum[3][u2][d];
    upd[((size_t)bh * U + uc * 4 + u2) * DKK + d] = s;
}

// ------------- base[b][n] = cmean[b] . Wo[:,n]  (fp32, tiny) ---------------
// cmean[b][h*64+d] = Vm[b*8+h][d]. Grid (16 n-tiles of 32, 4 b).
__global__ __launch_bounds__(256) void base_k(
    const float* __restrict__ Vm, const float* __restrict__ Wo,
    float* __restrict__ base)
{
    __shared__ float cm[DD];
    __shared__ float part[8][32];
    int b = blockIdx.y, n0 = blockIdx.x * 32, tid = threadIdx.x;
    cm[tid] = Vm[b * DD + tid];
    cm[tid + 256] = Vm[b * DD + 256 + tid];
    __syncthreads();
    int n = n0 + (tid & 31), kg = tid >> 5;      // 8 k-groups of 64
    float s = 0.f;
    for (int k = kg * 64; k < kg * 64 + 64; k++) s += cm[k] * Wo[(size_t)k * DD + n];
    part[kg][tid & 31] = s;
    __syncthreads();
    if (tid < 32) {
        float t = 0.f;
        #pragma unroll
        for (int g = 0; g < 8; g++) t += part[g][tid];
        base[b * DD + n0 + tid] = t;
    }
}

// ------------- aout init: every row of batch b <- base[b] ------------------
__global__ __launch_bounds__(256) void aout_init(
    const float* __restrict__ base, float* __restrict__ aout)
{
    int idx = blockIdx.x * 256 + threadIdx.x;    // over B*L*512
    aout[idx] = base[((idx >> 20) << 9) + (idx & 511)];
}

// ------------- aw[bh][u48][d] = bf16(upd - Vm) -----------------------------
__global__ __launch_bounds__(256) void aw_prep(
    const float* __restrict__ upd, const float* __restrict__ Vm,
    __bf16* __restrict__ aw, int U)
{
    int bh = blockIdx.x, tid = threadIdx.x;
    #pragma unroll
    for (int t = 0; t < 12; t++) {
        int e = tid + t * 256;                   // 0..3071
        int u = e >> 6, d = e & 63;
        float v = (u < U) ? upd[((size_t)bh * U + u) * DKK + d] - Vm[bh * DKK + d] : 0.f;
        aw[(size_t)bh * 48 * DKK + e] = (__bf16)v;
    }
}

// ------------- corr GEMM + scatter-add: aout[b, top[u]] += aw @ Wo_h -------
// 32 batches of (48x64) @ (64x128-tile)^T; B = WoT rows n0..n0+127, cols
// h*64..h*64+63 (bf16, already transposed in wb). Output atomicAdd'ed into
// aout rows selected by top (heads additive; per-head indices distinct).
__global__ __launch_bounds__(256) void corr_gemm(
    const __bf16* __restrict__ aw, const __bf16* __restrict__ WoT,
    const int* __restrict__ top, float* __restrict__ aout, int U)
{
    __shared__ __bf16 Qs[2 * 48 * 32];    // aw panels (BK=32)
    __shared__ __bf16 Ks[2 * 128 * 32];   // WoT-slice panels
    int bh = blockIdx.y, nc = blockIdx.x;
    int b = bh >> 3, h = bh & 7, n0 = nc * 128;
    int tid = threadIdx.x;
    const unsigned int* qsrc = (const unsigned int*)(aw + (size_t)bh * 48 * DKK);
    unsigned int* qdst = (unsigned int*)Qs;
    #pragma unroll
    for (int t = 0; t < 6; t++) {
        int ui = tid + t * 256;            // 0..1535
        int u = ui >> 5, kp = ui & 31;
        int p = kp >> 4, kl2 = kp & 15;
        qdst[p * 768 + u * 16 + kl2] = qsrc[ui];
    }
    // stage B: rows n0..n0+127 of WoT, k-cols h*64..h*64+63 (uint = 2 bf16)
    const unsigned int* wsrc = (const unsigned int*)WoT;
    unsigned int* kdst = (unsigned int*)Ks;
    #pragma unroll
    for (int t = 0; t < 16; t++) {
        int ui = tid + t * 256;            // 0..4095
        int row = ui >> 5, c2 = ui & 31;   // c2 = uint col (k = 2*c2)
        int p = c2 >> 4, col2 = c2 & 15;
        kdst[p * 2048 + row * 16 + col2] = wsrc[(size_t)(n0 + row) * (DD / 2) + h * 32 + c2];
    }
    __syncthreads();
    int wave = tid >> 6, lane = tid & 63, l15 = lane & 15, kq = lane >> 4;
    floatx4 acc[3][2] = {};
    #pragma unroll
    for (int p = 0; p < 2; p++) {
        bf16x8 bq[2];
        #pragma unroll
        for (int j = 0; j < 2; j++)
            bq[j] = *(const bf16x8*)(Ks + p * 4096 + (wave * 32 + j * 16 + l15) * 32 + kq * 8);
        #pragma unroll
        for (int i = 0; i < 3; i++) {
            bf16x8 aq = *(const bf16x8*)(Qs + p * 1536 + (i * 16 + l15) * 32 + kq * 8);
            #pragma unroll
            for (int j = 0; j < 2; j++)
                acc[i][j] = __builtin_amdgcn_mfma_f32_16x16x32_bf16(bq[j], aq, acc[i][j], 0, 0, 0);
        }
    }
    // thread holds C[u][n..n+3]: u = i*16+l15, n = n0+wave*32+j*16+kq*4
    #pragma unroll
    for (int i = 0; i < 3; i++) {
        int u = i * 16 + l15;
        if (u < U) {
            int l = top[bh * U + u];
            float* dst = aout + ((size_t)(b * LL + l)) * DD;
            #pragma unroll
            for (int j = 0; j < 2; j++) {
                int n = n0 + wave * 32 + j * 16 + kq * 4;
                atomicAdd(dst + n,     acc[i][j][0]);
                atomicAdd(dst + n + 1, acc[i][j][1]);
                atomicAdd(dst + n + 2, acc[i][j][2]);
                atomicAdd(dst + n + 3, acc[i][j][3]);
            }
        }
    }
}

// ------------- LN1: x1 = LN(x + aout) -> bf16 ------------------------------
__global__ __launch_bounds__(256) void ln1_k(
    const float* __restrict__ x, const float* __restrict__ aout,
    const float* __restrict__ g, const float* __restrict__ bb,
    __bf16* __restrict__ x1h)
{
    __shared__ float red[256];
    int row = blockIdx.x, tid = threadIdx.x;
    size_t base = (size_t)row * DD;
    float h0 = x[base + tid] + aout[base + tid];
    float h1 = x[base + 256 + tid] + aout[base + 256 + tid];
    red[tid] = h0 + h1; __syncthreads();
    for (int s = 128; s > 0; s >>= 1) { if (tid < s) red[tid] += red[tid + s]; __syncthreads(); }
    float mean = red[0] * (1.0f / DD); __syncthreads();
    float d0 = h0 - mean, d1 = h1 - mean;
    red[tid] = d0 * d0 + d1 * d1; __syncthreads();
    for (int s = 128; s > 0; s >>= 1) { if (tid < s) red[tid] += red[tid + s]; __syncthreads(); }
    float rstd = rsqrtf(red[0] * (1.0f / DD) + 1e-5f);
    x1h[base + tid]       = (__bf16)(d0 * rstd * g[tid] + bb[tid]);
    x1h[base + 256 + tid] = (__bf16)(d1 * rstd * g[256 + tid] + bb[256 + tid]);
}

// ------------- LN2: out = LN(x1 + ffn2 + b2) -> fp32 -----------------------
__global__ __launch_bounds__(256) void ln2_k(
    const __bf16* __restrict__ x1h, const float* __restrict__ f2o,
    const float* __restrict__ c2b,
    const float* __restrict__ g, const float* __restrict__ bb,
    float* __restrict__ out)
{
    __shared__ float red[256];
    int row = blockIdx.x, tid = threadIdx.x;
    size_t base = (size_t)row * DD;
    float h0 = (float)x1h[base + tid] + f2o[base + tid] + c2b[tid];
    float h1 = (float)x1h[base + 256 + tid] + f2o[base + 256 + tid] + c2b[256 + tid];
    red[tid] = h0 + h1; __syncthreads();
    for (int s = 128; s > 0; s >>= 1) { if (tid < s) red[tid] += red[tid + s]; __syncthreads(); }
    float mean = red[0] * (1.0f / DD); __syncthreads();
    float d0 = h0 - mean, d1 = h1 - mean;
    red[tid] = d0 * d0 + d1 * d1; __syncthreads();
    for (int s = 128; s > 0; s >>= 1) { if (tid < s) red[tid] += red[tid + s]; __syncthreads(); }
    float rstd = rsqrtf(red[0] * (1.0f / DD) + 1e-5f);
    out[base + tid]       = d0 * rstd * g[tid] + bb[tid];
    out[base + 256 + tid] = d1 * rstd * g[256 + tid] + bb[256 + tid];
}

// ---------------------------------------------------------------------------
extern "C" void kernel_launch(void* const* d_in, const int* in_sizes, int n_in,
                              void* d_out, int out_size, void* d_ws, size_t ws_size,
                              hipStream_t stream)
{
    const float* x   = (const float*)d_in[0];
    const float* Wq  = (const float*)d_in[1];
    const float* Wk  = (const float*)d_in[2];
    const float* Wv  = (const float*)d_in[3];
    const float* Wo  = (const float*)d_in[4];
    const float* g1  = (const float*)d_in[5];
    const float* b1  = (const float*)d_in[6];
    const float* c1w = (const float*)d_in[7];
    const float* c1b = (const float*)d_in[8];
    const float* c2w = (const float*)d_in[9];
    const float* c2b = (const float*)d_in[10];
    const float* g2  = (const float*)d_in[11];
    const float* b2  = (const float*)d_in[12];
    const int* sidx  = (const int*)d_in[13];
    float* out       = (float*)d_out;

    const int U = in_sizes[13] / LL;            // 40
    const int M = BB * LL;                       // 8192

    // ---- workspace layout (~64 MB), lifetime-safe aliasing ----
    // [0,16M)   Q fp32 -> aout fp32 (after gather_qred) -> f2o fp32 (after ln1)
    // [16,48M)  K fp32 [16,32) ; V bf16 [32,40) ; ych bf16 [16,48) after attn
    // [40,48M)  xhi ; [48,56M) xlo -> x1h ; S fp32 [40,52.6M) during attention
    // [56,59M)  wb (6 x 512KB bf16)   [59,61M) c1w bf16   [61,63M) c2w bf16
    // [63M+)    Mo 256K | upd 320K | Vm 8K | top 8K | qred 192K | aw 192K | base 8K
    char* ws = (char*)d_ws;
    const size_t MB = (size_t)1 << 20;
    float*  Q    = (float*)(ws + 0);
    float*  Kb   = (float*)(ws + 16 * MB);
    __bf16* V    = (__bf16*)(ws + 32 * MB);
    __bf16* xhi  = (__bf16*)(ws + 40 * MB);
    __bf16* xlo  = (__bf16*)(ws + 48 * MB);
    float*  S    = (float*)(ws + 40 * MB);          // 32*48*2048*4 = 12.6 MB
    __bf16* wb   = (__bf16*)(ws + 56 * MB);
    __bf16* c1wb = (__bf16*)(ws + 59 * MB);
    __bf16* c2wb = (__bf16*)(ws + 61 * MB);
    float*  Mo   = (float*)(ws + 63 * MB);
    float*  upd  = (float*)(ws + 63 * MB + 256 * 1024);
    float*  Vm   = (float*)(ws + 63 * MB + 576 * 1024);
    int*    top  = (int*)  (ws + 63 * MB + 584 * 1024);
    __bf16* qred = (__bf16*)(ws + 63 * MB + 592 * 1024);  // 192K
    __bf16* aw   = (__bf16*)(ws + 63 * MB + 784 * 1024);  // 192K
    float*  basep= (float*)(ws + 63 * MB + 976 * 1024);   // 8K
    float*  aout = Q;                               // alias: Q dead after gather_qred
    float*  f2o  = Q;                               // alias: aout dead after ln1
    __bf16* ych  = (__bf16*)(ws + 16 * MB);         // FFN intermediate (32 MB region)
    __bf16* x1h  = xlo;                             // alias: S/P dead by ln1
    (void)ws_size; (void)n_in; (void)out_size;

    const size_t SZ = (size_t)DD * DD;
    __bf16* WqThi = wb;          __bf16* WqTlo = wb + SZ;
    __bf16* WkThi = wb + 2 * SZ; __bf16* WkTlo = wb + 3 * SZ;
    __bf16* WvT   = wb + 4 * SZ; __bf16* WoT   = wb + 5 * SZ;

    // 1) weight prep + input split-cast
    prep_w<<<dim3(DD * DD / 256, 1, 4), 256, 0, stream>>>(Wq, Wk, Wv, Wo, wb);
    cast_cw<<<dim3(FF * DD / 256, 1, 2), 256, 0, stream>>>(c1w, c2w, c1wb, c2wb);
    split_cast_x<<<BB * LL * DD / 256, 256, 0, stream>>>(x, xhi, xlo);

    // 2) Q,K via split-precision MFMA (selection-faithful); V plain bf16
    dim3 gproj(DD / 128, M / 128);
    gemm_mfma_split<<<gproj, 256, 0, stream>>>(xhi, xlo, WqThi, WqTlo, Q,  M, DD, DD);
    gemm_mfma_split<<<gproj, 256, 0, stream>>>(xhi, xlo, WkThi, WkTlo, Kb, M, DD, DD);
    gemm_mfma<0, false, true ><<<gproj, 256, 0, stream>>>(xhi, WvT, nullptr, V, M, DD, DD);

    // 3) sampled sparsity measure M, top-k, V mean
    calc_m<<<BB * LL, 256, 0, stream>>>(Q, Kb, sidx, Mo, U);
    topk_k<<<BB * HH, 256, 0, stream>>>(Mo, top, U);
    vmean_k<<<BB * HH, 256, 0, stream>>>(V, Vm);

    // 4) attention: gather -> batched MFMA S -> softmax(in-place bf16 P) -> PV
    gather_qred<<<dim3(48 * DKK / 256, BB * HH), 256, 0, stream>>>(Q, top, qred, U);
    gemm_s<<<dim3(LL / 128, BB * HH), 256, 0, stream>>>(qred, Kb, S);
    softmax_p<<<BB * HH * U, 256, 0, stream>>>(S, U);
    pv_k<<<dim3(U / 4, BB * HH), 256, 0, stream>>>(S, V, upd, U);

    // 5) out-projection via base + rank-U correction (ctx/Wo-GEMM eliminated):
    //    aout[b,l] = cmean[b]@Wo + sum_{h: l in top[b,h]} (upd-Vm)@Wo_h
    base_k<<<dim3(16, BB), 256, 0, stream>>>(Vm, Wo, basep);
    aw_prep<<<BB * HH, 256, 0, stream>>>(upd, Vm, aw, U);
    aout_init<<<M * DD / 256, 256, 0, stream>>>(basep, aout);
    corr_gemm<<<dim3(DD / 128, BB * HH), 256, 0, stream>>>(aw, WoT, top, aout, U);

    // 6) LN1 -> x1h bf16 (aliases xlo; S/P dead)
    ln1_k<<<M, 256, 0, stream>>>(x, aout, g1, b1, x1h);

    // 7) FFN: gelu(x1 @ c1w^T + c1b) -> ych bf16; ych @ c2w^T -> f2o
    gemm_mfma<1, true,  true ><<<dim3(FF / 128, M / 128), 256, 0, stream>>>(x1h, c1wb, c1b, ych, M, FF, DD);
    gemm_mfma<0, false, false><<<dim3(DD / 128, M / 128), 256, 0, stream>>>(ych, c2wb, nullptr, f2o, M, DD, FF);

    // 8) LN2 -> fp32 output
    ln2_k<<<M, 256, 0, stream>>>(x1h, f2o, c2b, g2, b2, out);
}

// Round 10
// 399.700 us; speedup vs baseline: 1.0748x; 1.0748x over previous
//
#include <hip/hip_runtime.h>
#include <hip/hip_bf16.h>

// Problem constants (B=4, L=2048, D=512, H=8, DK=64, FF=2048, U=40)
#define BB 4
#define LL 2048
#define DD 512
#define HH 8
#define DKK 64
#define FF 2048

typedef __bf16  bf16x8  __attribute__((ext_vector_type(8)));
typedef float   floatx4 __attribute__((ext_vector_type(4)));

// async 16B global->LDS copy (global_load_lds_dwordx4)
__device__ __forceinline__ void async_cp16(const void* g, void* l) {
    __builtin_amdgcn_global_load_lds(
        (const __attribute__((address_space(1))) unsigned int*)g,
        (__attribute__((address_space(3))) unsigned int*)l,
        16, 0, 0);
}

// exact-grade GELU: A&S 7.1.26 erf, |err| < 1.5e-7 (fp32-exact at our scale).
__device__ __forceinline__ float gelu_f(float v) {
    float z  = v * 0.70710678118654752f;
    float az = fabsf(z);
    float t  = __builtin_amdgcn_rcpf(1.0f + 0.3275911f * az);
    float p  = ((((1.061405429f * t - 1.453152027f) * t + 1.421413741f) * t
                 - 0.284496736f) * t + 0.254829592f) * t;
    float e  = __expf(-z * z);
    float er = 1.0f - p * e;
    er = (z < 0.0f) ? -er : er;
    return 0.5f * v * (1.0f + er);
}

// ---------- prep: transpose 512x512 fp32 -> bf16 (N,K); Wq/Wk also lo-part ----
__global__ __launch_bounds__(256) void prep_w(
    const float* __restrict__ Wq, const float* __restrict__ Wk,
    const float* __restrict__ Wv, const float* __restrict__ Wo,
    __bf16* __restrict__ wb)
{
    const size_t SZ = (size_t)DD * DD;
    int z = blockIdx.z;
    const float* s = (z == 0) ? Wq : (z == 1) ? Wk : (z == 2) ? Wv : Wo;
    __bf16* hi; __bf16* lo = nullptr;
    if (z == 0)      { hi = wb;          lo = wb + SZ; }
    else if (z == 1) { hi = wb + 2 * SZ; lo = wb + 3 * SZ; }
    else if (z == 2) { hi = wb + 4 * SZ; }
    else             { hi = wb + 5 * SZ; }
    int idx = blockIdx.x * 256 + threadIdx.x;   // 0..512*512-1
    int k = idx >> 9, n = idx & 511;
    float v = s[idx];
    __bf16 h = (__bf16)v;
    hi[(size_t)n * DD + k] = h;
    if (lo) lo[(size_t)n * DD + k] = (__bf16)(v - (float)h);
}

// ---------- cast conv weights fp32 (N,K) -> bf16 -----------------------------
__global__ __launch_bounds__(256) void cast_cw(
    const float* __restrict__ c1w, const float* __restrict__ c2w,
    __bf16* __restrict__ d1, __bf16* __restrict__ d2)
{
    const float* s = blockIdx.z ? c2w : c1w;
    __bf16* d = blockIdx.z ? d2 : d1;
    int idx = blockIdx.x * 256 + threadIdx.x;   // 0..FF*DD-1
    d[idx] = (__bf16)s[idx];
}

// ---------- split-cast x fp32 -> bf16 hi + lo --------------------------------
__global__ __launch_bounds__(256) void split_cast_x(
    const float* __restrict__ x, __bf16* __restrict__ xhi, __bf16* __restrict__ xlo)
{
    int idx = blockIdx.x * 256 + threadIdx.x;
    float v = x[idx];
    __bf16 h = (__bf16)v;
    xhi[idx] = h;
    xlo[idx] = (__bf16)(v - (float)h);
}

// ---------- MFMA GEMM: C[M,N] = act(A[M,K] @ B[N,K]^T + bias) ----------------
// 128x128 tile, NB-buffer (NB-1)-deep pipeline, single barrier + counted vmcnt
// per k-step. NB=3 for grids with >=3 blocks/CU (FFN1); NB=6 for grid-limited
// N=512 GEMMs (V-proj, FFN2: 256 blocks = 1 block/CU, 4 waves -> deep prefetch
// is the only latency hiding available). Bank swizzle per rule #21 (r8:
// conflicts -> 0). XCD swizzle + swapped-operand vector epilogue.
template<int NB, int ACT, bool BIAS, bool OUT_BF16>
__global__ __launch_bounds__(256) void gemm_mfma(
    const __bf16* __restrict__ A, const __bf16* __restrict__ B,
    const float* __restrict__ bias, void* __restrict__ Cv,
    int M, int N, int K)
{
    __shared__ __bf16 As[NB][128 * 32];
    __shared__ __bf16 Bs[NB][128 * 32];
    const int tid = threadIdx.x;
    const int wave = tid >> 6, lane = tid & 63;
    const int gx = gridDim.x;
    const int nwg = gx * gridDim.y;
    const int hw = blockIdx.y * gx + blockIdx.x;
    const int virt = ((nwg & 7) == 0) ? ((hw & 7) * (nwg >> 3) + (hw >> 3)) : hw;
    const int m0 = (virt / gx) * 128, n0 = (virt % gx) * 128;
    const int wm = (wave >> 1) * 64, wn = (wave & 1) * 64;
    const int l15 = lane & 15, kq = lane >> 4;

    auto stage = [&](int buf, int k0) {           // 4 vmem insts per wave
        #pragma unroll
        for (int p = 0; p < 2; p++) {
            int c = p * 256 + tid;                // 16B chunk id 0..511
            int row = c >> 2;
            int col = ((c & 3) ^ ((row >> 1) & 3)) * 8;   // inverse-swizzled src
            async_cp16(A + (size_t)(m0 + row) * K + k0 + col, &As[buf][c * 8]);
            async_cp16(B + (size_t)(n0 + row) * K + k0 + col, &Bs[buf][c * 8]);
        }
    };

    floatx4 acc[4][4] = {};

    const int nt = K >> 5;
    #pragma unroll
    for (int pt = 0; pt < NB - 1; pt++) stage(pt, pt << 5);
    if constexpr (NB == 6) asm volatile("s_waitcnt vmcnt(16)" ::: "memory");
    else                   asm volatile("s_waitcnt vmcnt(4)"  ::: "memory");
    __builtin_amdgcn_s_barrier();
    int bi = 0;                                   // buffer of current tile
    for (int t = 0; t < nt; t++) {
        if (t + NB - 1 < nt) {
            int b2 = bi + NB - 1; if (b2 >= NB) b2 -= NB;
            stage(b2, (t + NB - 1) << 5);         // overwrites buffer read at t-1
        }
        asm volatile("" ::: "memory");
        bf16x8 af[4], bfr[4];
        #pragma unroll
        for (int i = 0; i < 4; i++) {
            int ra = wm + i * 16 + l15;
            af[i] = *(const bf16x8*)(&As[bi][ra * 32 + ((kq ^ ((ra >> 1) & 3)) << 3)]);
        }
        #pragma unroll
        for (int j = 0; j < 4; j++) {
            int rb = wn + j * 16 + l15;
            bfr[j] = *(const bf16x8*)(&Bs[bi][rb * 32 + ((kq ^ ((rb >> 1) & 3)) << 3)]);
        }
        #pragma unroll
        for (int i = 0; i < 4; i++)
            #pragma unroll
            for (int j = 0; j < 4; j++)
                acc[i][j] = __builtin_amdgcn_mfma_f32_16x16x32_bf16(bfr[j], af[i], acc[i][j], 0, 0, 0);
        asm volatile("" ::: "memory");
        if (t + 1 < nt) {                         // wait: tile t+1 landed
            int c = nt - 2 - t; if (c > NB - 2) c = NB - 2;
            if (c >= 4)      asm volatile("s_waitcnt vmcnt(16)" ::: "memory");
            else if (c == 3) asm volatile("s_waitcnt vmcnt(12)" ::: "memory");
            else if (c == 2) asm volatile("s_waitcnt vmcnt(8)"  ::: "memory");
            else if (c == 1) asm volatile("s_waitcnt vmcnt(4)"  ::: "memory");
            else             asm volatile("s_waitcnt vmcnt(0)"  ::: "memory");
            __builtin_amdgcn_s_barrier();
        }
        if (++bi == NB) bi = 0;
    }
    // epilogue: thread holds C[m][n..n+3], m = m0+wm+i*16+l15, n = n0+wn+j*16+kq*4
    #pragma unroll
    for (int i = 0; i < 4; i++) {
        int m = m0 + wm + i * 16 + l15;
        #pragma unroll
        for (int j = 0; j < 4; j++) {
            int n = n0 + wn + j * 16 + kq * 4;
            floatx4 v4 = acc[i][j];
            if (BIAS) {
                float4 bv = *(const float4*)&bias[n];
                v4[0] += bv.x; v4[1] += bv.y; v4[2] += bv.z; v4[3] += bv.w;
            }
            if (ACT == 1) {
                v4[0] = gelu_f(v4[0]); v4[1] = gelu_f(v4[1]);
                v4[2] = gelu_f(v4[2]); v4[3] = gelu_f(v4[3]);
            }
            if (OUT_BF16) {
                union { __bf16 b[4]; uint2 u; } pk;
                pk.b[0] = (__bf16)v4[0]; pk.b[1] = (__bf16)v4[1];
                pk.b[2] = (__bf16)v4[2]; pk.b[3] = (__bf16)v4[3];
                *(uint2*)((__bf16*)Cv + (size_t)m * N + n) = pk.u;
            } else {
                *(float4*)((float*)Cv + (size_t)m * N + n) = *(float4*)&v4;
            }
        }
    }
}

// ---------- split-precision MFMA GEMM (near-fp32): C = (Ah+Al)(Bh+Bl)^T ------
// 4-buffer 3-deep pipeline (grid 256 = 1 block/CU; 128 KB LDS is free).
// 8 vmem/stage -> waits in multiples of 8.
__global__ __launch_bounds__(256) void gemm_mfma_split(
    const __bf16* __restrict__ Ah, const __bf16* __restrict__ Al,
    const __bf16* __restrict__ Bh, const __bf16* __restrict__ Bl,
    float* __restrict__ C, int M, int N, int K)
{
    __shared__ __bf16 Ahs[4][128 * 32];
    __shared__ __bf16 Als[4][128 * 32];
    __shared__ __bf16 Bhs[4][128 * 32];
    __shared__ __bf16 Bls[4][128 * 32];
    const int tid = threadIdx.x;
    const int wave = tid >> 6, lane = tid & 63;
    const int gx = gridDim.x;
    const int nwg = gx * gridDim.y;
    const int hw = blockIdx.y * gx + blockIdx.x;
    const int virt = ((nwg & 7) == 0) ? ((hw & 7) * (nwg >> 3) + (hw >> 3)) : hw;
    const int m0 = (virt / gx) * 128, n0 = (virt % gx) * 128;
    const int wm = (wave >> 1) * 64, wn = (wave & 1) * 64;
    const int l15 = lane & 15, kq = lane >> 4;

    auto stage = [&](int buf, int k0) {           // 8 vmem insts per wave
        #pragma unroll
        for (int p = 0; p < 2; p++) {
            int c = p * 256 + tid;
            int row = c >> 2;
            int col = ((c & 3) ^ ((row >> 1) & 3)) * 8;
            size_t goA = (size_t)(m0 + row) * K + k0 + col;
            size_t goB = (size_t)(n0 + row) * K + k0 + col;
            async_cp16(Ah + goA, &Ahs[buf][c * 8]);
            async_cp16(Al + goA, &Als[buf][c * 8]);
            async_cp16(Bh + goB, &Bhs[buf][c * 8]);
            async_cp16(Bl + goB, &Bls[buf][c * 8]);
        }
    };

    floatx4 acc[4][4] = {};

    const int nt = K >> 5;
    stage(0, 0); stage(1, 32); stage(2, 64);
    asm volatile("s_waitcnt vmcnt(16)" ::: "memory");
    __builtin_amdgcn_s_barrier();
    int bi = 0;
    for (int t = 0; t < nt; t++) {
        if (t + 3 < nt) {
            int b2 = bi + 3; if (b2 >= 4) b2 -= 4;
            stage(b2, (t + 3) << 5);
        }
        asm volatile("" ::: "memory");
        bf16x8 ah[4], al[4], bh[4], bl[4];
        #pragma unroll
        for (int i = 0; i < 4; i++) {
            int ra = wm + i * 16 + l15;
            int off = ra * 32 + ((kq ^ ((ra >> 1) & 3)) << 3);
            ah[i] = *(const bf16x8*)(&Ahs[bi][off]);
            al[i] = *(const bf16x8*)(&Als[bi][off]);
        }
        #pragma unroll
        for (int j = 0; j < 4; j++) {
            int rb = wn + j * 16 + l15;
            int off = rb * 32 + ((kq ^ ((rb >> 1) & 3)) << 3);
            bh[j] = *(const bf16x8*)(&Bhs[bi][off]);
            bl[j] = *(const bf16x8*)(&Bls[bi][off]);
        }
        #pragma unroll
        for (int i = 0; i < 4; i++)
            #pragma unroll
            for (int j = 0; j < 4; j++) {
                acc[i][j] = __builtin_amdgcn_mfma_f32_16x16x32_bf16(bh[j], ah[i], acc[i][j], 0, 0, 0);
                acc[i][j] = __builtin_amdgcn_mfma_f32_16x16x32_bf16(bl[j], ah[i], acc[i][j], 0, 0, 0);
                acc[i][j] = __builtin_amdgcn_mfma_f32_16x16x32_bf16(bh[j], al[i], acc[i][j], 0, 0, 0);
            }
        asm volatile("" ::: "memory");
        if (t + 1 < nt) {
            int c = nt - 2 - t; if (c > 2) c = 2;
            if (c == 2)      asm volatile("s_waitcnt vmcnt(16)" ::: "memory");
            else if (c == 1) asm volatile("s_waitcnt vmcnt(8)"  ::: "memory");
            else             asm volatile("s_waitcnt vmcnt(0)"  ::: "memory");
            __builtin_amdgcn_s_barrier();
        }
        if (++bi == 4) bi = 0;
    }
    #pragma unroll
    for (int i = 0; i < 4; i++) {
        int m = m0 + wm + i * 16 + l15;
        #pragma unroll
        for (int j = 0; j < 4; j++) {
            int n = n0 + wn + j * 16 + kq * 4;
            *(float4*)(C + (size_t)m * N + n) = *(float4*)&acc[i][j];
        }
    }
}

// ------------- M[b,h,l] = max_s(q·k_s) - sum_s(q·k_s)/L  (sampled) ---------
// 16-lane sum via DPP-fused v_add_f32 (pure VALU; no LDS-pipe ds_swizzle).
__device__ __forceinline__ float dpp_sum16(float p) {
    int t;
    t = __builtin_amdgcn_update_dpp(0, __float_as_int(p), 0xB1,  0xF, 0xF, true); // quad_perm [1,0,3,2]
    p += __int_as_float(t);
    t = __builtin_amdgcn_update_dpp(0, __float_as_int(p), 0x4E,  0xF, 0xF, true); // quad_perm [2,3,0,1]
    p += __int_as_float(t);
    t = __builtin_amdgcn_update_dpp(0, __float_as_int(p), 0x141, 0xF, 0xF, true); // row_half_mirror
    p += __int_as_float(t);
    t = __builtin_amdgcn_update_dpp(0, __float_as_int(p), 0x140, 0xF, 0xF, true); // row_mirror
    p += __int_as_float(t);
    return p;
}

__global__ __launch_bounds__(256) void calc_m(
    const float* __restrict__ Q, const float* __restrict__ Kb,
    const int* __restrict__ sidx, float* __restrict__ Mo, int U)
{
    __shared__ int   js[64];
    __shared__ float red_mx[2][HH];
    __shared__ float red_sm[2][HH];
    int i = blockIdx.x;
    int b = i & 3, l = i >> 2;
    int tid = threadIdx.x;
    if (tid < U) js[tid] = sidx[l * U + tid];
    int e    = (tid & 127) * 4;          // element index within 512-wide row
    int slot = tid >> 7;                 // 0/1: even/odd samples
    const float* qr = Q + ((size_t)(b * LL + l) * DD);
    float4 q = *(const float4*)(qr + e);
    const float* kbase = Kb + ((size_t)b * LL) * DD + e;
    __syncthreads();
    float mx = -1e30f, sm = 0.f;
    for (int s = slot; s < U; s += 2) {
        int j = js[s];
        float4 kv = *(const float4*)(kbase + (size_t)j * DD);
        float p = q.x * kv.x + q.y * kv.y + q.z * kv.z + q.w * kv.w;
        p = dpp_sum16(p);
        mx = fmaxf(mx, p);
        sm += p;
    }
    if ((tid & 15) == 0) {
        int head = (tid >> 4) & 7;
        red_mx[slot][head] = mx;
        red_sm[slot][head] = sm;
    }
    __syncthreads();
    if (tid < HH) {
        float m2 = fmaxf(red_mx[0][tid], red_mx[1][tid]);
        float s2 = red_sm[0][tid] + red_sm[1][tid];
        Mo[((size_t)(b * HH + tid)) * LL + l] = m2 - s2 * (1.0f / (float)LL);
    }
}

// ------------- radix-select top-40 per (b,h) row of M ----------------------
__global__ __launch_bounds__(256) void topk_k(
    const float* __restrict__ Mo, int* __restrict__ top, int U)
{
    __shared__ unsigned int hist[256];
    __shared__ unsigned int wsum[4];
    __shared__ unsigned int bc[2];
    __shared__ int ties[LL];
    __shared__ int cnt2[2];
    int bh = blockIdx.x, tid = threadIdx.x;
    int lane = tid & 63, w = tid >> 6;

    unsigned int my[8];
    #pragma unroll
    for (int i = 0; i < 8; i++) {
        unsigned int u = __float_as_uint(Mo[(size_t)bh * LL + tid + i * 256]);
        my[i] = u ^ ((u >> 31) ? 0xFFFFFFFFu : 0x80000000u);  // order-preserving
    }

    unsigned int prefix = 0, pmask = 0;
    unsigned int need = (unsigned int)U;
    unsigned int above = 0;

    for (int pass = 0; pass < 4; pass++) {
        int shift = 24 - pass * 8;
        hist[tid] = 0;
        __syncthreads();
        #pragma unroll
        for (int i = 0; i < 8; i++) {
            unsigned int u = my[i];
            if ((u & pmask) == prefix)
                atomicAdd(&hist[(u >> shift) & 255u], 1u);
        }
        __syncthreads();
        unsigned int h = hist[tid];
        #pragma unroll
        for (int off = 1; off < 64; off <<= 1) {
            unsigned int o = __shfl_down(h, off);
            if (lane + off < 64) h += o;
        }
        if (lane == 0) wsum[w] = h;
        __syncthreads();
        unsigned int tail = 0;
        #pragma unroll
        for (int w2 = 1; w2 < 4; w2++) if (w2 > w) tail += wsum[w2];
        h += tail;
        hist[tid] = h;
        __syncthreads();
        unsigned int St = h;
        unsigned int St1 = (tid < 255) ? hist[tid + 1] : 0u;
        if (St >= need && St1 < need) { bc[0] = (unsigned int)tid; bc[1] = St1; }
        __syncthreads();
        unsigned int dig = bc[0], abv = bc[1];
        above += abv;
        need -= abv;
        prefix |= dig << shift;
        pmask |= 0xFFu << shift;
        __syncthreads();
    }

    if (tid == 0) { cnt2[0] = 0; cnt2[1] = 0; }
    __syncthreads();
    #pragma unroll
    for (int i = 0; i < 8; i++) {
        unsigned int u = my[i];
        int idx = tid + i * 256;
        if (u > prefix) {
            int pos = atomicAdd(&cnt2[0], 1);
            top[bh * U + pos] = idx;
        } else if (u == prefix) {
            int pos = atomicAdd(&cnt2[1], 1);
            ties[pos] = idx;
        }
    }
    __syncthreads();
    int tcnt = cnt2[1];
    #pragma unroll
    for (int i = 0; i < 8; i++) {
        unsigned int u = my[i];
        if (u == prefix) {
            int idx = tid + i * 256;
            int rank = 0;
            for (int j = 0; j < tcnt; j++) rank += (ties[j] < idx) ? 1 : 0;
            if (rank < (int)need) top[bh * U + (int)above + rank] = idx;
        }
    }
}

// ------------- Vmean[b,h,d] (V bf16), 256 threads/block --------------------
__global__ __launch_bounds__(256) void vmean_k(
    const __bf16* __restrict__ V, float* __restrict__ Vm)
{
    __shared__ float osum[4][DKK];
    int bh = blockIdx.x;
    int b = bh >> 3, h = bh & 7;
    int tid = threadIdx.x, d = tid & 63, part = tid >> 6;
    const __bf16* vp = V + ((size_t)(b * LL + part * 512) * DD + h * DKK + d);
    float s = 0.f;
    for (int i = 0; i < 512; i++) s += (float)vp[(size_t)i * DD];
    osum[part][d] = s;
    __syncthreads();
    if (tid < DKK)
        Vm[bh * DKK + tid] = (osum[0][tid] + osum[1][tid] + osum[2][tid] + osum[3][tid]) * (1.0f / (float)LL);
}

// ------------- gather Q[top] -> qred[32][48][64] bf16, scaled by 1/8 -------
__global__ __launch_bounds__(256) void gather_qred(
    const float* __restrict__ Q, const int* __restrict__ top,
    __bf16* __restrict__ qred, int U)
{
    int bh = blockIdx.y;
    int b = bh >> 3, h = bh & 7;
    int e = blockIdx.x * 256 + threadIdx.x;   // 0..48*64-1
    int u = e >> 6, d = e & 63;
    float v = 0.f;
    if (u < U) {
        int l = top[bh * U + u];
        v = Q[((size_t)(b * LL + l) * DD + h * DKK) + d] * 0.125f;
    }
    qred[(size_t)bh * 48 * DKK + e] = (__bf16)v;
}

// ------------- batched S[bh][48][2048] = qred[bh] @ K[bh]^T (MFMA) ---------
// Swapped-operand MFMA -> float4 stores of S.
__global__ __launch_bounds__(256) void gemm_s(
    const __bf16* __restrict__ qred, const float* __restrict__ Kb,
    float* __restrict__ S)
{
    __shared__ __bf16 Qs[2 * 48 * 32];    // 2 panels of BK=32
    __shared__ __bf16 Ks[2 * 128 * 32];
    int bh = blockIdx.y, nc = blockIdx.x;
    int b = bh >> 3, h = bh & 7, l0 = nc * 128;
    int tid = threadIdx.x;
    const unsigned int* qsrc = (const unsigned int*)(qred + (size_t)bh * 48 * DKK);
    unsigned int* qdst = (unsigned int*)Qs;
    #pragma unroll
    for (int t = 0; t < 6; t++) {
        int ui = tid + t * 256;            // 0..1535
        int u = ui >> 5, kp = ui & 31;
        int p = kp >> 4, kl2 = kp & 15;
        qdst[p * 768 + u * 16 + kl2] = qsrc[ui];
    }
    #pragma unroll
    for (int t = 0; t < 8; t++) {
        int fi = tid + t * 256;            // 0..2047
        int row = fi >> 4, k4 = fi & 15;
        int p = k4 >> 3, kl = (k4 & 7) * 4;
        float4 kv = *(const float4*)(Kb + ((size_t)(b * LL + l0 + row) * DD + h * DKK + k4 * 4));
        __bf16* dst = Ks + p * 128 * 32 + row * 32 + kl;
        dst[0] = (__bf16)kv.x; dst[1] = (__bf16)kv.y;
        dst[2] = (__bf16)kv.z; dst[3] = (__bf16)kv.w;
    }
    __syncthreads();
    int wave = tid >> 6, lane = tid & 63, l15 = lane & 15, kq = lane >> 4;
    floatx4 acc[3][2] = {};
    #pragma unroll
    for (int p = 0; p < 2; p++) {
        bf16x8 bq[2];
        #pragma unroll
        for (int j = 0; j < 2; j++)
            bq[j] = *(const bf16x8*)(Ks + p * 4096 + (wave * 32 + j * 16 + l15) * 32 + kq * 8);
        #pragma unroll
        for (int i = 0; i < 3; i++) {
            bf16x8 aq = *(const bf16x8*)(Qs + p * 1536 + (i * 16 + l15) * 32 + kq * 8);
            #pragma unroll
            for (int j = 0; j < 2; j++)
                acc[i][j] = __builtin_amdgcn_mfma_f32_16x16x32_bf16(bq[j], aq, acc[i][j], 0, 0, 0);
        }
    }
    // thread holds S[row][col..col+3]: row = i*16+l15, col = l0+wave*32+j*16+kq*4
    #pragma unroll
    for (int i = 0; i < 3; i++) {
        int row = i * 16 + l15;
        #pragma unroll
        for (int j = 0; j < 2; j++) {
            int col = l0 + wave * 32 + j * 16 + kq * 4;
            *(float4*)&S[((size_t)bh * 48 + row) * LL + col] = *(float4*)&acc[i][j];
        }
    }
}

// ------------- row softmax, in-place: S row fp32 -> P row bf16 -------------
__global__ __launch_bounds__(256) void softmax_p(float* __restrict__ S, int U)
{
    __shared__ float red[256];
    int row = blockIdx.x;              // 32*U rows
    int bh = row / U, u = row % U;
    float* sr = S + ((size_t)bh * 48 + u) * LL;
    int tid = threadIdx.x;
    float sc[8]; float mx = -1e30f;
    #pragma unroll
    for (int i = 0; i < 8; i++) { sc[i] = sr[tid + i * 256]; mx = fmaxf(mx, sc[i]); }
    red[tid] = mx; __syncthreads();
    for (int s = 128; s > 0; s >>= 1) { if (tid < s) red[tid] = fmaxf(red[tid], red[tid + s]); __syncthreads(); }
    mx = red[0]; __syncthreads();
    float se = 0.f;
    #pragma unroll
    for (int i = 0; i < 8; i++) { sc[i] = __expf(sc[i] - mx); se += sc[i]; }
    red[tid] = se; __syncthreads();
    for (int s = 128; s > 0; s >>= 1) { if (tid < s) red[tid] += red[tid + s]; __syncthreads(); }
    float inv = 1.0f / red[0];
    __bf16* pr = (__bf16*)sr;
    #pragma unroll
    for (int i = 0; i < 8; i++) pr[tid + i * 256] = (__bf16)(sc[i] * inv);
}

// ------------- zero upd (pv_k accumulates via atomicAdd) -------------------
__global__ __launch_bounds__(256) void zero_upd(float* __restrict__ upd, int n)
{
    int i = blockIdx.x * 256 + threadIdx.x;
    if (i < n) upd[i] = 0.f;
}

// ------------- upd[bh][u][d] += sum_{l in chunk} P[u][l] * V[b,h,l,d] ------
// Split L 4-way (grid 10x4x32 = 1280 blocks = 5/CU; was 320 = 1.25/CU and
// latency-starved at 10.7% occupancy). V loads vectorized to uint2 (8B/lane,
// 4 d-values). Partials reduced in LDS, atomicAdd into zeroed upd.
__global__ __launch_bounds__(256) void pv_k(
    const float* __restrict__ S, const __bf16* __restrict__ V,
    float* __restrict__ upd, int U)
{
    __shared__ __bf16 pls[4][512];        // 4 KB
    __shared__ float osum[16][4][DKK];    // 16 KB
    int uc = blockIdx.x, lc = blockIdx.y, bh = blockIdx.z;
    int b = bh >> 3, h = bh & 7, tid = threadIdx.x;
    // stage P: 4 rows x 512-l chunk (bf16 at S row starts; 256 uints/row-chunk)
    #pragma unroll
    for (int t = 0; t < 4; t++) {
        int ui = tid + t * 256;          // 0..1023
        int up = ui >> 8, lw = ui & 255;
        ((unsigned int*)pls)[up * 256 + lw] =
            ((const unsigned int*)(S + ((size_t)bh * 48 + uc * 4 + up) * LL))[lc * 256 + lw];
    }
    __syncthreads();
    int d4 = tid & 15, part = tid >> 4;   // 16 parts of 32 l; d4 covers 4 d's
    const __bf16* vp = V + ((size_t)(b * LL + lc * 512 + part * 32)) * DD + h * DKK + d4 * 4;
    float a[4][4] = {};
    for (int i = 0; i < 32; i++) {
        union { uint2 u; __bf16 bb[4]; } cv;
        cv.u = *(const uint2*)(vp + (size_t)i * DD);
        float v0 = (float)cv.bb[0], v1 = (float)cv.bb[1];
        float v2 = (float)cv.bb[2], v3 = (float)cv.bb[3];
        int l = part * 32 + i;
        #pragma unroll
        for (int u2 = 0; u2 < 4; u2++) {
            float p = (float)pls[u2][l];
            a[u2][0] += p * v0; a[u2][1] += p * v1;
            a[u2][2] += p * v2; a[u2][3] += p * v3;
        }
    }
    #pragma unroll
    for (int u2 = 0; u2 < 4; u2++)
        #pragma unroll
        for (int j = 0; j < 4; j++)
            osum[part][u2][d4 * 4 + j] = a[u2][j];
    __syncthreads();
    int d = tid & 63, u2 = tid >> 6;
    float s = 0.f;
    #pragma unroll
    for (int p = 0; p < 16; p++) s += osum[p][u2][d];
    atomicAdd(&upd[((size_t)bh * U + uc * 4 + u2) * DKK + d], s);
}

// ------------- base[b][n] = cmean[b] . Wo[:,n]  (fp32, tiny) ---------------
__global__ __launch_bounds__(256) void base_k(
    const float* __restrict__ Vm, const float* __restrict__ Wo,
    float* __restrict__ base)
{
    __shared__ float cm[DD];
    __shared__ float part[8][32];
    int b = blockIdx.y, n0 = blockIdx.x * 32, tid = threadIdx.x;
    cm[tid] = Vm[b * DD + tid];
    cm[tid + 256] = Vm[b * DD + 256 + tid];
    __syncthreads();
    int n = n0 + (tid & 31), kg = tid >> 5;      // 8 k-groups of 64
    float s = 0.f;
    for (int k = kg * 64; k < kg * 64 + 64; k++) s += cm[k] * Wo[(size_t)k * DD + n];
    part[kg][tid & 31] = s;
    __syncthreads();
    if (tid < 32) {
        float t = 0.f;
        #pragma unroll
        for (int g = 0; g < 8; g++) t += part[g][tid];
        base[b * DD + n0 + tid] = t;
    }
}

// ------------- aout init: every row of batch b <- base[b] ------------------
__global__ __launch_bounds__(256) void aout_init(
    const float* __restrict__ base, float* __restrict__ aout)
{
    int idx = blockIdx.x * 256 + threadIdx.x;    // over B*L*512
    aout[idx] = base[((idx >> 20) << 9) + (idx & 511)];
}

// ------------- aw[bh][u48][d] = bf16(upd - Vm) -----------------------------
__global__ __launch_bounds__(256) void aw_prep(
    const float* __restrict__ upd, const float* __restrict__ Vm,
    __bf16* __restrict__ aw, int U)
{
    int bh = blockIdx.x, tid = threadIdx.x;
    #pragma unroll
    for (int t = 0; t < 12; t++) {
        int e = tid + t * 256;                   // 0..3071
        int u = e >> 6, d = e & 63;
        float v = (u < U) ? upd[((size_t)bh * U + u) * DKK + d] - Vm[bh * DKK + d] : 0.f;
        aw[(size_t)bh * 48 * DKK + e] = (__bf16)v;
    }
}

// ------------- corr GEMM + scatter-add: aout[b, top[u]] += aw @ Wo_h -------
__global__ __launch_bounds__(256) void corr_gemm(
    const __bf16* __restrict__ aw, const __bf16* __restrict__ WoT,
    const int* __restrict__ top, float* __restrict__ aout, int U)
{
    __shared__ __bf16 Qs[2 * 48 * 32];    // aw panels (BK=32)
    __shared__ __bf16 Ks[2 * 128 * 32];   // WoT-slice panels
    int bh = blockIdx.y, nc = blockIdx.x;
    int b = bh >> 3, h = bh & 7, n0 = nc * 128;
    int tid = threadIdx.x;
    const unsigned int* qsrc = (const unsigned int*)(aw + (size_t)bh * 48 * DKK);
    unsigned int* qdst = (unsigned int*)Qs;
    #pragma unroll
    for (int t = 0; t < 6; t++) {
        int ui = tid + t * 256;            // 0..1535
        int u = ui >> 5, kp = ui & 31;
        int p = kp >> 4, kl2 = kp & 15;
        qdst[p * 768 + u * 16 + kl2] = qsrc[ui];
    }
    const unsigned int* wsrc = (const unsigned int*)WoT;
    unsigned int* kdst = (unsigned int*)Ks;
    #pragma unroll
    for (int t = 0; t < 16; t++) {
        int ui = tid + t * 256;            // 0..4095
        int row = ui >> 5, c2 = ui & 31;
        int p = c2 >> 4, col2 = c2 & 15;
        kdst[p * 2048 + row * 16 + col2] = wsrc[(size_t)(n0 + row) * (DD / 2) + h * 32 + c2];
    }
    __syncthreads();
    int wave = tid >> 6, lane = tid & 63, l15 = lane & 15, kq = lane >> 4;
    floatx4 acc[3][2] = {};
    #pragma unroll
    for (int p = 0; p < 2; p++) {
        bf16x8 bq[2];
        #pragma unroll
        for (int j = 0; j < 2; j++)
            bq[j] = *(const bf16x8*)(Ks + p * 4096 + (wave * 32 + j * 16 + l15) * 32 + kq * 8);
        #pragma unroll
        for (int i = 0; i < 3; i++) {
            bf16x8 aq = *(const bf16x8*)(Qs + p * 1536 + (i * 16 + l15) * 32 + kq * 8);
            #pragma unroll
            for (int j = 0; j < 2; j++)
                acc[i][j] = __builtin_amdgcn_mfma_f32_16x16x32_bf16(bq[j], aq, acc[i][j], 0, 0, 0);
        }
    }
    #pragma unroll
    for (int i = 0; i < 3; i++) {
        int u = i * 16 + l15;
        if (u < U) {
            int l = top[bh * U + u];
            float* dst = aout + ((size_t)(b * LL + l)) * DD;
            #pragma unroll
            for (int j = 0; j < 2; j++) {
                int n = n0 + wave * 32 + j * 16 + kq * 4;
                atomicAdd(dst + n,     acc[i][j][0]);
                atomicAdd(dst + n + 1, acc[i][j][1]);
                atomicAdd(dst + n + 2, acc[i][j][2]);
                atomicAdd(dst + n + 3, acc[i][j][3]);
            }
        }
    }
}

// ------------- LN1: x1 = LN(x + aout) -> bf16 ------------------------------
__global__ __launch_bounds__(256) void ln1_k(
    const float* __restrict__ x, const float* __restrict__ aout,
    const float* __restrict__ g, const float* __restrict__ bb,
    __bf16* __restrict__ x1h)
{
    __shared__ float red[256];
    int row = blockIdx.x, tid = threadIdx.x;
    size_t base = (size_t)row * DD;
    float h0 = x[base + tid] + aout[base + tid];
    float h1 = x[base + 256 + tid] + aout[base + 256 + tid];
    red[tid] = h0 + h1; __syncthreads();
    for (int s = 128; s > 0; s >>= 1) { if (tid < s) red[tid] += red[tid + s]; __syncthreads(); }
    float mean = red[0] * (1.0f / DD); __syncthreads();
    float d0 = h0 - mean, d1 = h1 - mean;
    red[tid] = d0 * d0 + d1 * d1; __syncthreads();
    for (int s = 128; s > 0; s >>= 1) { if (tid < s) red[tid] += red[tid + s]; __syncthreads(); }
    float rstd = rsqrtf(red[0] * (1.0f / DD) + 1e-5f);
    x1h[base + tid]       = (__bf16)(d0 * rstd * g[tid] + bb[tid]);
    x1h[base + 256 + tid] = (__bf16)(d1 * rstd * g[256 + tid] + bb[256 + tid]);
}

// ------------- LN2: out = LN(x1 + ffn2 + b2) -> fp32 -----------------------
__global__ __launch_bounds__(256) void ln2_k(
    const __bf16* __restrict__ x1h, const float* __restrict__ f2o,
    const float* __restrict__ c2b,
    const float* __restrict__ g, const float* __restrict__ bb,
    float* __restrict__ out)
{
    __shared__ float red[256];
    int row = blockIdx.x, tid = threadIdx.x;
    size_t base = (size_t)row * DD;
    float h0 = (float)x1h[base + tid] + f2o[base + tid] + c2b[tid];
    float h1 = (float)x1h[base + 256 + tid] + f2o[base + 256 + tid] + c2b[256 + tid];
    red[tid] = h0 + h1; __syncthreads();
    for (int s = 128; s > 0; s >>= 1) { if (tid < s) red[tid] += red[tid + s]; __syncthreads(); }
    float mean = red[0] * (1.0f / DD); __syncthreads();
    float d0 = h0 - mean, d1 = h1 - mean;
    red[tid] = d0 * d0 + d1 * d1; __syncthreads();
    for (int s = 128; s > 0; s >>= 1) { if (tid < s) red[tid] += red[tid + s]; __syncthreads(); }
    float rstd = rsqrtf(red[0] * (1.0f / DD) + 1e-5f);
    out[base + tid]       = d0 * rstd * g[tid] + bb[tid];
    out[base + 256 + tid] = d1 * rstd * g[256 + tid] + bb[256 + tid];
}

// ---------------------------------------------------------------------------
extern "C" void kernel_launch(void* const* d_in, const int* in_sizes, int n_in,
                              void* d_out, int out_size, void* d_ws, size_t ws_size,
                              hipStream_t stream)
{
    const float* x   = (const float*)d_in[0];
    const float* Wq  = (const float*)d_in[1];
    const float* Wk  = (const float*)d_in[2];
    const float* Wv  = (const float*)d_in[3];
    const float* Wo  = (const float*)d_in[4];
    const float* g1  = (const float*)d_in[5];
    const float* b1  = (const float*)d_in[6];
    const float* c1w = (const float*)d_in[7];
    const float* c1b = (const float*)d_in[8];
    const float* c2w = (const float*)d_in[9];
    const float* c2b = (const float*)d_in[10];
    const float* g2  = (const float*)d_in[11];
    const float* b2  = (const float*)d_in[12];
    const int* sidx  = (const int*)d_in[13];
    float* out       = (float*)d_out;

    const int U = in_sizes[13] / LL;            // 40
    const int M = BB * LL;                       // 8192

    char* ws = (char*)d_ws;
    const size_t MB = (size_t)1 << 20;
    float*  Q    = (float*)(ws + 0);
    float*  Kb   = (float*)(ws + 16 * MB);
    __bf16* V    = (__bf16*)(ws + 32 * MB);
    __bf16* xhi  = (__bf16*)(ws + 40 * MB);
    __bf16* xlo  = (__bf16*)(ws + 48 * MB);
    float*  S    = (float*)(ws + 40 * MB);          // 32*48*2048*4 = 12.6 MB
    __bf16* wb   = (__bf16*)(ws + 56 * MB);
    __bf16* c1wb = (__bf16*)(ws + 59 * MB);
    __bf16* c2wb = (__bf16*)(ws + 61 * MB);
    float*  Mo   = (float*)(ws + 63 * MB);
    float*  upd  = (float*)(ws + 63 * MB + 256 * 1024);
    float*  Vm   = (float*)(ws + 63 * MB + 576 * 1024);
    int*    top  = (int*)  (ws + 63 * MB + 584 * 1024);
    __bf16* qred = (__bf16*)(ws + 63 * MB + 592 * 1024);  // 192K
    __bf16* aw   = (__bf16*)(ws + 63 * MB + 784 * 1024);  // 192K
    float*  basep= (float*)(ws + 63 * MB + 976 * 1024);   // 8K
    float*  aout = Q;                               // alias: Q dead after gather_qred
    float*  f2o  = Q;                               // alias: aout dead after ln1
    __bf16* ych  = (__bf16*)(ws + 16 * MB);         // FFN intermediate (32 MB region)
    __bf16* x1h  = xlo;                             // alias: S/P dead by ln1
    (void)ws_size; (void)n_in; (void)out_size;

    const size_t SZ = (size_t)DD * DD;
    __bf16* WqThi = wb;          __bf16* WqTlo = wb + SZ;
    __bf16* WkThi = wb + 2 * SZ; __bf16* WkTlo = wb + 3 * SZ;
    __bf16* WvT   = wb + 4 * SZ; __bf16* WoT   = wb + 5 * SZ;

    // 1) weight prep + input split-cast
    prep_w<<<dim3(DD * DD / 256, 1, 4), 256, 0, stream>>>(Wq, Wk, Wv, Wo, wb);
    cast_cw<<<dim3(FF * DD / 256, 1, 2), 256, 0, stream>>>(c1w, c2w, c1wb, c2wb);
    split_cast_x<<<BB * LL * DD / 256, 256, 0, stream>>>(x, xhi, xlo);

    // 2) Q,K via split-precision MFMA (selection-faithful); V plain bf16
    dim3 gproj(DD / 128, M / 128);
    gemm_mfma_split<<<gproj, 256, 0, stream>>>(xhi, xlo, WqThi, WqTlo, Q,  M, DD, DD);
    gemm_mfma_split<<<gproj, 256, 0, stream>>>(xhi, xlo, WkThi, WkTlo, Kb, M, DD, DD);
    gemm_mfma<6, 0, false, true ><<<gproj, 256, 0, stream>>>(xhi, WvT, nullptr, V, M, DD, DD);

    // 3) sampled sparsity measure M, top-k, V mean (+ zero upd for pv atomics)
    calc_m<<<BB * LL, 256, 0, stream>>>(Q, Kb, sidx, Mo, U);
    zero_upd<<<(BB * HH * U * DKK + 255) / 256, 256, 0, stream>>>(upd, BB * HH * U * DKK);
    topk_k<<<BB * HH, 256, 0, stream>>>(Mo, top, U);
    vmean_k<<<BB * HH, 256, 0, stream>>>(V, Vm);

    // 4) attention: gather -> batched MFMA S -> softmax(in-place bf16 P) -> PV
    gather_qred<<<dim3(48 * DKK / 256, BB * HH), 256, 0, stream>>>(Q, top, qred, U);
    gemm_s<<<dim3(LL / 128, BB * HH), 256, 0, stream>>>(qred, Kb, S);
    softmax_p<<<BB * HH * U, 256, 0, stream>>>(S, U);
    pv_k<<<dim3(U / 4, 4, BB * HH), 256, 0, stream>>>(S, V, upd, U);

    // 5) out-projection via base + rank-U correction (Wo-GEMM eliminated)
    base_k<<<dim3(16, BB), 256, 0, stream>>>(Vm, Wo, basep);
    aw_prep<<<BB * HH, 256, 0, stream>>>(upd, Vm, aw, U);
    aout_init<<<M * DD / 256, 256, 0, stream>>>(basep, aout);
    corr_gemm<<<dim3(DD / 128, BB * HH), 256, 0, stream>>>(aw, WoT, top, aout, U);

    // 6) LN1 -> x1h bf16 (aliases xlo; S/P dead)
    ln1_k<<<M, 256, 0, stream>>>(x, aout, g1, b1, x1h);

    // 7) FFN: gelu(x1 @ c1w^T + c1b) -> ych bf16 (NB=3: 1024 blocks, 3/CU);
    //    ych @ c2w^T -> f2o (NB=6: 256 blocks grid-limited -> deep prefetch)
    gemm_mfma<3, 1, true,  true ><<<dim3(FF / 128, M / 128), 256, 0, stream>>>(x1h, c1wb, c1b, ych, M, FF, DD);
    gemm_mfma<6, 0, false, false><<<dim3(DD / 128, M / 128), 256, 0, stream>>>(ych, c2wb, nullptr, f2o, M, DD, FF);

    // 8) LN2 -> fp32 output
    ln2_k<<<M, 256, 0, stream>>>(x1h, f2o, c2b, g2, b2, out);
}

// Round 11
// 389.499 us; speedup vs baseline: 1.1029x; 1.0262x over previous
//
#include <hip/hip_runtime.h>
#include <hip/hip_bf16.h>

// Problem constants (B=4, L=2048, D=512, H=8, DK=64, FF=2048, U=40)
#define BB 4
#define LL 2048
#define DD 512
#define HH 8
#define DKK 64
#define FF 2048

typedef __bf16  bf16x8  __attribute__((ext_vector_type(8)));
typedef float   floatx4 __attribute__((ext_vector_type(4)));

// async 16B global->LDS copy (global_load_lds_dwordx4)
__device__ __forceinline__ void async_cp16(const void* g, void* l) {
    __builtin_amdgcn_global_load_lds(
        (const __attribute__((address_space(1))) unsigned int*)g,
        (__attribute__((address_space(3))) unsigned int*)l,
        16, 0, 0);
}

// exact-grade GELU: A&S 7.1.26 erf, |err| < 1.5e-7 (fp32-exact at our scale).
__device__ __forceinline__ float gelu_f(float v) {
    float z  = v * 0.70710678118654752f;
    float az = fabsf(z);
    float t  = __builtin_amdgcn_rcpf(1.0f + 0.3275911f * az);
    float p  = ((((1.061405429f * t - 1.453152027f) * t + 1.421413741f) * t
                 - 0.284496736f) * t + 0.254829592f) * t;
    float e  = __expf(-z * z);
    float er = 1.0f - p * e;
    er = (z < 0.0f) ? -er : er;
    return 0.5f * v * (1.0f + er);
}

// ---------- prep: transpose 512x512 fp32 -> bf16 (N,K); Wq/Wk also lo-part ----
__global__ __launch_bounds__(256) void prep_w(
    const float* __restrict__ Wq, const float* __restrict__ Wk,
    const float* __restrict__ Wv, const float* __restrict__ Wo,
    __bf16* __restrict__ wb)
{
    const size_t SZ = (size_t)DD * DD;
    int z = blockIdx.z;
    const float* s = (z == 0) ? Wq : (z == 1) ? Wk : (z == 2) ? Wv : Wo;
    __bf16* hi; __bf16* lo = nullptr;
    if (z == 0)      { hi = wb;          lo = wb + SZ; }
    else if (z == 1) { hi = wb + 2 * SZ; lo = wb + 3 * SZ; }
    else if (z == 2) { hi = wb + 4 * SZ; }
    else             { hi = wb + 5 * SZ; }
    int idx = blockIdx.x * 256 + threadIdx.x;   // 0..512*512-1
    int k = idx >> 9, n = idx & 511;
    float v = s[idx];
    __bf16 h = (__bf16)v;
    hi[(size_t)n * DD + k] = h;
    if (lo) lo[(size_t)n * DD + k] = (__bf16)(v - (float)h);
}

// ---------- cast conv weights fp32 (N,K) -> bf16 -----------------------------
__global__ __launch_bounds__(256) void cast_cw(
    const float* __restrict__ c1w, const float* __restrict__ c2w,
    __bf16* __restrict__ d1, __bf16* __restrict__ d2)
{
    const float* s = blockIdx.z ? c2w : c1w;
    __bf16* d = blockIdx.z ? d2 : d1;
    int idx = blockIdx.x * 256 + threadIdx.x;   // 0..FF*DD-1
    d[idx] = (__bf16)s[idx];
}

// ---------- split-cast x fp32 -> bf16 hi + lo --------------------------------
__global__ __launch_bounds__(256) void split_cast_x(
    const float* __restrict__ x, __bf16* __restrict__ xhi, __bf16* __restrict__ xlo)
{
    int idx = blockIdx.x * 256 + threadIdx.x;
    float v = x[idx];
    __bf16 h = (__bf16)v;
    xhi[idx] = h;
    xlo[idx] = (__bf16)(v - (float)h);
}

// ---------- MFMA GEMM, 128x128 tile (FFN1: 1024 blocks = 4/CU) ---------------
// NB-buffer pipeline, single barrier + counted vmcnt per k-step; bank swizzle
// (r8: conflicts -> 0); XCD swizzle; swapped-operand vector epilogue.
template<int NB, int ACT, bool BIAS, bool OUT_BF16>
__global__ __launch_bounds__(256) void gemm_mfma(
    const __bf16* __restrict__ A, const __bf16* __restrict__ B,
    const float* __restrict__ bias, void* __restrict__ Cv,
    int M, int N, int K)
{
    __shared__ __bf16 As[NB][128 * 32];
    __shared__ __bf16 Bs[NB][128 * 32];
    const int tid = threadIdx.x;
    const int wave = tid >> 6, lane = tid & 63;
    const int gx = gridDim.x;
    const int nwg = gx * gridDim.y;
    const int hw = blockIdx.y * gx + blockIdx.x;
    const int virt = ((nwg & 7) == 0) ? ((hw & 7) * (nwg >> 3) + (hw >> 3)) : hw;
    const int m0 = (virt / gx) * 128, n0 = (virt % gx) * 128;
    const int wm = (wave >> 1) * 64, wn = (wave & 1) * 64;
    const int l15 = lane & 15, kq = lane >> 4;

    auto stage = [&](int buf, int k0) {           // 4 vmem insts per thread
        #pragma unroll
        for (int p = 0; p < 2; p++) {
            int c = p * 256 + tid;                // 16B chunk id 0..511
            int row = c >> 2;
            int col = ((c & 3) ^ ((row >> 1) & 3)) * 8;   // inverse-swizzled src
            async_cp16(A + (size_t)(m0 + row) * K + k0 + col, &As[buf][c * 8]);
            async_cp16(B + (size_t)(n0 + row) * K + k0 + col, &Bs[buf][c * 8]);
        }
    };

    floatx4 acc[4][4] = {};

    const int nt = K >> 5;
    #pragma unroll
    for (int pt = 0; pt < NB - 1; pt++) stage(pt, pt << 5);
    if constexpr (NB == 6) asm volatile("s_waitcnt vmcnt(16)" ::: "memory");
    else                   asm volatile("s_waitcnt vmcnt(4)"  ::: "memory");
    __builtin_amdgcn_s_barrier();
    int bi = 0;                                   // buffer of current tile
    for (int t = 0; t < nt; t++) {
        if (t + NB - 1 < nt) {
            int b2 = bi + NB - 1; if (b2 >= NB) b2 -= NB;
            stage(b2, (t + NB - 1) << 5);
        }
        asm volatile("" ::: "memory");
        bf16x8 af[4], bfr[4];
        #pragma unroll
        for (int i = 0; i < 4; i++) {
            int ra = wm + i * 16 + l15;
            af[i] = *(const bf16x8*)(&As[bi][ra * 32 + ((kq ^ ((ra >> 1) & 3)) << 3)]);
        }
        #pragma unroll
        for (int j = 0; j < 4; j++) {
            int rb = wn + j * 16 + l15;
            bfr[j] = *(const bf16x8*)(&Bs[bi][rb * 32 + ((kq ^ ((rb >> 1) & 3)) << 3)]);
        }
        #pragma unroll
        for (int i = 0; i < 4; i++)
            #pragma unroll
            for (int j = 0; j < 4; j++)
                acc[i][j] = __builtin_amdgcn_mfma_f32_16x16x32_bf16(bfr[j], af[i], acc[i][j], 0, 0, 0);
        asm volatile("" ::: "memory");
        if (t + 1 < nt) {                         // wait: tile t+1 landed
            int c = nt - 2 - t; if (c > NB - 2) c = NB - 2;
            if (c >= 4)      asm volatile("s_waitcnt vmcnt(16)" ::: "memory");
            else if (c == 3) asm volatile("s_waitcnt vmcnt(12)" ::: "memory");
            else if (c == 2) asm volatile("s_waitcnt vmcnt(8)"  ::: "memory");
            else if (c == 1) asm volatile("s_waitcnt vmcnt(4)"  ::: "memory");
            else             asm volatile("s_waitcnt vmcnt(0)"  ::: "memory");
            __builtin_amdgcn_s_barrier();
        }
        if (++bi == NB) bi = 0;
    }
    #pragma unroll
    for (int i = 0; i < 4; i++) {
        int m = m0 + wm + i * 16 + l15;
        #pragma unroll
        for (int j = 0; j < 4; j++) {
            int n = n0 + wn + j * 16 + kq * 4;
            floatx4 v4 = acc[i][j];
            if (BIAS) {
                float4 bv = *(const float4*)&bias[n];
                v4[0] += bv.x; v4[1] += bv.y; v4[2] += bv.z; v4[3] += bv.w;
            }
            if (ACT == 1) {
                v4[0] = gelu_f(v4[0]); v4[1] = gelu_f(v4[1]);
                v4[2] = gelu_f(v4[2]); v4[3] = gelu_f(v4[3]);
            }
            if (OUT_BF16) {
                union { __bf16 b[4]; uint2 u; } pk;
                pk.b[0] = (__bf16)v4[0]; pk.b[1] = (__bf16)v4[1];
                pk.b[2] = (__bf16)v4[2]; pk.b[3] = (__bf16)v4[3];
                *(uint2*)((__bf16*)Cv + (size_t)m * N + n) = pk.u;
            } else {
                *(float4*)((float*)Cv + (size_t)m * N + n) = *(float4*)&v4;
            }
        }
    }
}

// ---------- MFMA GEMM, 64x128 tile for grid-limited N=512 GEMMs --------------
// V-proj / FFN2 previously ran 256 blocks = 1 block/CU = 1 wave/SIMD: zero TLP,
// LDS-read latency fully exposed (r10: MfmaUtil 13%, NB=6 neutral). BM=64
// doubles the grid -> 2 blocks/CU, 2 waves/SIMD. Wave-tile 32x64, acc[2][4],
// 3 loads/thread/stage, NB=6 -> 72 KB LDS (2 blocks fit).
template<int NB, int ACT, bool BIAS, bool OUT_BF16>
__global__ __launch_bounds__(256) void gemm_mfma64(
    const __bf16* __restrict__ A, const __bf16* __restrict__ B,
    const float* __restrict__ bias, void* __restrict__ Cv,
    int M, int N, int K)
{
    __shared__ __bf16 As[NB][64 * 32];
    __shared__ __bf16 Bs[NB][128 * 32];
    const int tid = threadIdx.x;
    const int wave = tid >> 6, lane = tid & 63;
    const int gx = gridDim.x;
    const int nwg = gx * gridDim.y;
    const int hw = blockIdx.y * gx + blockIdx.x;
    const int virt = ((nwg & 7) == 0) ? ((hw & 7) * (nwg >> 3) + (hw >> 3)) : hw;
    const int m0 = (virt / gx) * 64, n0 = (virt % gx) * 128;
    const int wm = (wave >> 1) * 32, wn = (wave & 1) * 64;
    const int l15 = lane & 15, kq = lane >> 4;

    auto stage = [&](int buf, int k0) {           // 3 vmem insts per thread
        {
            int c = tid;                          // A: 256 chunks (64 rows x 4)
            int row = c >> 2;
            int col = ((c & 3) ^ ((row >> 1) & 3)) * 8;
            async_cp16(A + (size_t)(m0 + row) * K + k0 + col, &As[buf][c * 8]);
        }
        #pragma unroll
        for (int p = 0; p < 2; p++) {
            int c = p * 256 + tid;                // B: 512 chunks
            int row = c >> 2;
            int col = ((c & 3) ^ ((row >> 1) & 3)) * 8;
            async_cp16(B + (size_t)(n0 + row) * K + k0 + col, &Bs[buf][c * 8]);
        }
    };

    floatx4 acc[2][4] = {};

    const int nt = K >> 5;
    #pragma unroll
    for (int pt = 0; pt < NB - 1; pt++) stage(pt, pt << 5);
    if constexpr (NB == 6) asm volatile("s_waitcnt vmcnt(12)" ::: "memory");
    else                   asm volatile("s_waitcnt vmcnt(3)"  ::: "memory");
    __builtin_amdgcn_s_barrier();
    int bi = 0;
    for (int t = 0; t < nt; t++) {
        if (t + NB - 1 < nt) {
            int b2 = bi + NB - 1; if (b2 >= NB) b2 -= NB;
            stage(b2, (t + NB - 1) << 5);
        }
        asm volatile("" ::: "memory");
        bf16x8 af[2], bfr[4];
        #pragma unroll
        for (int i = 0; i < 2; i++) {
            int ra = wm + i * 16 + l15;
            af[i] = *(const bf16x8*)(&As[bi][ra * 32 + ((kq ^ ((ra >> 1) & 3)) << 3)]);
        }
        #pragma unroll
        for (int j = 0; j < 4; j++) {
            int rb = wn + j * 16 + l15;
            bfr[j] = *(const bf16x8*)(&Bs[bi][rb * 32 + ((kq ^ ((rb >> 1) & 3)) << 3)]);
        }
        #pragma unroll
        for (int i = 0; i < 2; i++)
            #pragma unroll
            for (int j = 0; j < 4; j++)
                acc[i][j] = __builtin_amdgcn_mfma_f32_16x16x32_bf16(bfr[j], af[i], acc[i][j], 0, 0, 0);
        asm volatile("" ::: "memory");
        if (t + 1 < nt) {
            int c = nt - 2 - t; if (c > NB - 2) c = NB - 2;
            if (c >= 4)      asm volatile("s_waitcnt vmcnt(12)" ::: "memory");
            else if (c == 3) asm volatile("s_waitcnt vmcnt(9)"  ::: "memory");
            else if (c == 2) asm volatile("s_waitcnt vmcnt(6)"  ::: "memory");
            else if (c == 1) asm volatile("s_waitcnt vmcnt(3)"  ::: "memory");
            else             asm volatile("s_waitcnt vmcnt(0)"  ::: "memory");
            __builtin_amdgcn_s_barrier();
        }
        if (++bi == NB) bi = 0;
    }
    #pragma unroll
    for (int i = 0; i < 2; i++) {
        int m = m0 + wm + i * 16 + l15;
        #pragma unroll
        for (int j = 0; j < 4; j++) {
            int n = n0 + wn + j * 16 + kq * 4;
            floatx4 v4 = acc[i][j];
            if (BIAS) {
                float4 bv = *(const float4*)&bias[n];
                v4[0] += bv.x; v4[1] += bv.y; v4[2] += bv.z; v4[3] += bv.w;
            }
            if (ACT == 1) {
                v4[0] = gelu_f(v4[0]); v4[1] = gelu_f(v4[1]);
                v4[2] = gelu_f(v4[2]); v4[3] = gelu_f(v4[3]);
            }
            if (OUT_BF16) {
                union { __bf16 b[4]; uint2 u; } pk;
                pk.b[0] = (__bf16)v4[0]; pk.b[1] = (__bf16)v4[1];
                pk.b[2] = (__bf16)v4[2]; pk.b[3] = (__bf16)v4[3];
                *(uint2*)((__bf16*)Cv + (size_t)m * N + n) = pk.u;
            } else {
                *(float4*)((float*)Cv + (size_t)m * N + n) = *(float4*)&v4;
            }
        }
    }
}

// ---------- split-precision MFMA GEMM, 64x128 tile (Q/K projections) ---------
// C = (Ah+Al)(Bh+Bl)^T. Grid 512 = 2 blocks/CU (was 256 = 1/CU, 1 wave/SIMD).
// NB=3, 6 loads/thread/stage -> 72 KB LDS.
__global__ __launch_bounds__(256) void gemm_mfma_split64(
    const __bf16* __restrict__ Ah, const __bf16* __restrict__ Al,
    const __bf16* __restrict__ Bh, const __bf16* __restrict__ Bl,
    float* __restrict__ C, int M, int N, int K)
{
    __shared__ __bf16 Ahs[3][64 * 32];
    __shared__ __bf16 Als[3][64 * 32];
    __shared__ __bf16 Bhs[3][128 * 32];
    __shared__ __bf16 Bls[3][128 * 32];
    const int tid = threadIdx.x;
    const int wave = tid >> 6, lane = tid & 63;
    const int gx = gridDim.x;
    const int nwg = gx * gridDim.y;
    const int hw = blockIdx.y * gx + blockIdx.x;
    const int virt = ((nwg & 7) == 0) ? ((hw & 7) * (nwg >> 3) + (hw >> 3)) : hw;
    const int m0 = (virt / gx) * 64, n0 = (virt % gx) * 128;
    const int wm = (wave >> 1) * 32, wn = (wave & 1) * 64;
    const int l15 = lane & 15, kq = lane >> 4;

    auto stage = [&](int buf, int k0) {           // 6 vmem insts per thread
        {
            int c = tid;
            int row = c >> 2;
            int col = ((c & 3) ^ ((row >> 1) & 3)) * 8;
            size_t go = (size_t)(m0 + row) * K + k0 + col;
            async_cp16(Ah + go, &Ahs[buf][c * 8]);
            async_cp16(Al + go, &Als[buf][c * 8]);
        }
        #pragma unroll
        for (int p = 0; p < 2; p++) {
            int c = p * 256 + tid;
            int row = c >> 2;
            int col = ((c & 3) ^ ((row >> 1) & 3)) * 8;
            size_t go = (size_t)(n0 + row) * K + k0 + col;
            async_cp16(Bh + go, &Bhs[buf][c * 8]);
            async_cp16(Bl + go, &Bls[buf][c * 8]);
        }
    };

    floatx4 acc[2][4] = {};

    const int nt = K >> 5;
    stage(0, 0); stage(1, 32);
    asm volatile("s_waitcnt vmcnt(6)" ::: "memory");
    __builtin_amdgcn_s_barrier();
    int bi = 0;
    for (int t = 0; t < nt; t++) {
        if (t + 2 < nt) {
            int b2 = bi + 2; if (b2 >= 3) b2 -= 3;
            stage(b2, (t + 2) << 5);
        }
        asm volatile("" ::: "memory");
        bf16x8 ah[2], al[2], bh[4], bl[4];
        #pragma unroll
        for (int i = 0; i < 2; i++) {
            int ra = wm + i * 16 + l15;
            int off = ra * 32 + ((kq ^ ((ra >> 1) & 3)) << 3);
            ah[i] = *(const bf16x8*)(&Ahs[bi][off]);
            al[i] = *(const bf16x8*)(&Als[bi][off]);
        }
        #pragma unroll
        for (int j = 0; j < 4; j++) {
            int rb = wn + j * 16 + l15;
            int off = rb * 32 + ((kq ^ ((rb >> 1) & 3)) << 3);
            bh[j] = *(const bf16x8*)(&Bhs[bi][off]);
            bl[j] = *(const bf16x8*)(&Bls[bi][off]);
        }
        #pragma unroll
        for (int i = 0; i < 2; i++)
            #pragma unroll
            for (int j = 0; j < 4; j++) {
                acc[i][j] = __builtin_amdgcn_mfma_f32_16x16x32_bf16(bh[j], ah[i], acc[i][j], 0, 0, 0);
                acc[i][j] = __builtin_amdgcn_mfma_f32_16x16x32_bf16(bl[j], ah[i], acc[i][j], 0, 0, 0);
                acc[i][j] = __builtin_amdgcn_mfma_f32_16x16x32_bf16(bh[j], al[i], acc[i][j], 0, 0, 0);
            }
        asm volatile("" ::: "memory");
        if (t + 1 < nt) {
            if (t + 2 < nt) asm volatile("s_waitcnt vmcnt(6)" ::: "memory");
            else            asm volatile("s_waitcnt vmcnt(0)" ::: "memory");
            __builtin_amdgcn_s_barrier();
        }
        if (++bi == 3) bi = 0;
    }
    #pragma unroll
    for (int i = 0; i < 2; i++) {
        int m = m0 + wm + i * 16 + l15;
        #pragma unroll
        for (int j = 0; j < 4; j++) {
            int n = n0 + wn + j * 16 + kq * 4;
            *(float4*)(C + (size_t)m * N + n) = *(float4*)&acc[i][j];
        }
    }
}

// ------------- M[b,h,l] = max_s(q·k_s) - sum_s(q·k_s)/L  (sampled) ---------
// 16-lane sum via DPP-fused v_add_f32 (pure VALU; no LDS-pipe ds_swizzle).
__device__ __forceinline__ float dpp_sum16(float p) {
    int t;
    t = __builtin_amdgcn_update_dpp(0, __float_as_int(p), 0xB1,  0xF, 0xF, true); // quad_perm [1,0,3,2]
    p += __int_as_float(t);
    t = __builtin_amdgcn_update_dpp(0, __float_as_int(p), 0x4E,  0xF, 0xF, true); // quad_perm [2,3,0,1]
    p += __int_as_float(t);
    t = __builtin_amdgcn_update_dpp(0, __float_as_int(p), 0x141, 0xF, 0xF, true); // row_half_mirror
    p += __int_as_float(t);
    t = __builtin_amdgcn_update_dpp(0, __float_as_int(p), 0x140, 0xF, 0xF, true); // row_mirror
    p += __int_as_float(t);
    return p;
}

__global__ __launch_bounds__(256) void calc_m(
    const float* __restrict__ Q, const float* __restrict__ Kb,
    const int* __restrict__ sidx, float* __restrict__ Mo, int U)
{
    __shared__ int   js[64];
    __shared__ float red_mx[2][HH];
    __shared__ float red_sm[2][HH];
    int i = blockIdx.x;
    int b = i & 3, l = i >> 2;
    int tid = threadIdx.x;
    if (tid < U) js[tid] = sidx[l * U + tid];
    int e    = (tid & 127) * 4;          // element index within 512-wide row
    int slot = tid >> 7;                 // 0/1: even/odd samples
    const float* qr = Q + ((size_t)(b * LL + l) * DD);
    float4 q = *(const float4*)(qr + e);
    const float* kbase = Kb + ((size_t)b * LL) * DD + e;
    __syncthreads();
    float mx = -1e30f, sm = 0.f;
    for (int s = slot; s < U; s += 2) {
        int j = js[s];
        float4 kv = *(const float4*)(kbase + (size_t)j * DD);
        float p = q.x * kv.x + q.y * kv.y + q.z * kv.z + q.w * kv.w;
        p = dpp_sum16(p);
        mx = fmaxf(mx, p);
        sm += p;
    }
    if ((tid & 15) == 0) {
        int head = (tid >> 4) & 7;
        red_mx[slot][head] = mx;
        red_sm[slot][head] = sm;
    }
    __syncthreads();
    if (tid < HH) {
        float m2 = fmaxf(red_mx[0][tid], red_mx[1][tid]);
        float s2 = red_sm[0][tid] + red_sm[1][tid];
        Mo[((size_t)(b * HH + tid)) * LL + l] = m2 - s2 * (1.0f / (float)LL);
    }
}

// ------------- radix-select top-40 per (b,h) row of M ----------------------
__global__ __launch_bounds__(256) void topk_k(
    const float* __restrict__ Mo, int* __restrict__ top, int U)
{
    __shared__ unsigned int hist[256];
    __shared__ unsigned int wsum[4];
    __shared__ unsigned int bc[2];
    __shared__ int ties[LL];
    __shared__ int cnt2[2];
    int bh = blockIdx.x, tid = threadIdx.x;
    int lane = tid & 63, w = tid >> 6;

    unsigned int my[8];
    #pragma unroll
    for (int i = 0; i < 8; i++) {
        unsigned int u = __float_as_uint(Mo[(size_t)bh * LL + tid + i * 256]);
        my[i] = u ^ ((u >> 31) ? 0xFFFFFFFFu : 0x80000000u);  // order-preserving
    }

    unsigned int prefix = 0, pmask = 0;
    unsigned int need = (unsigned int)U;
    unsigned int above = 0;

    for (int pass = 0; pass < 4; pass++) {
        int shift = 24 - pass * 8;
        hist[tid] = 0;
        __syncthreads();
        #pragma unroll
        for (int i = 0; i < 8; i++) {
            unsigned int u = my[i];
            if ((u & pmask) == prefix)
                atomicAdd(&hist[(u >> shift) & 255u], 1u);
        }
        __syncthreads();
        unsigned int h = hist[tid];
        #pragma unroll
        for (int off = 1; off < 64; off <<= 1) {
            unsigned int o = __shfl_down(h, off);
            if (lane + off < 64) h += o;
        }
        if (lane == 0) wsum[w] = h;
        __syncthreads();
        unsigned int tail = 0;
        #pragma unroll
        for (int w2 = 1; w2 < 4; w2++) if (w2 > w) tail += wsum[w2];
        h += tail;
        hist[tid] = h;
        __syncthreads();
        unsigned int St = h;
        unsigned int St1 = (tid < 255) ? hist[tid + 1] : 0u;
        if (St >= need && St1 < need) { bc[0] = (unsigned int)tid; bc[1] = St1; }
        __syncthreads();
        unsigned int dig = bc[0], abv = bc[1];
        above += abv;
        need -= abv;
        prefix |= dig << shift;
        pmask |= 0xFFu << shift;
        __syncthreads();
    }

    if (tid == 0) { cnt2[0] = 0; cnt2[1] = 0; }
    __syncthreads();
    #pragma unroll
    for (int i = 0; i < 8; i++) {
        unsigned int u = my[i];
        int idx = tid + i * 256;
        if (u > prefix) {
            int pos = atomicAdd(&cnt2[0], 1);
            top[bh * U + pos] = idx;
        } else if (u == prefix) {
            int pos = atomicAdd(&cnt2[1], 1);
            ties[pos] = idx;
        }
    }
    __syncthreads();
    int tcnt = cnt2[1];
    #pragma unroll
    for (int i = 0; i < 8; i++) {
        unsigned int u = my[i];
        if (u == prefix) {
            int idx = tid + i * 256;
            int rank = 0;
            for (int j = 0; j < tcnt; j++) rank += (ties[j] < idx) ? 1 : 0;
            if (rank < (int)need) top[bh * U + (int)above + rank] = idx;
        }
    }
}

// ------------- Vmean[b,h,d] (V bf16), 256 threads/block --------------------
__global__ __launch_bounds__(256) void vmean_k(
    const __bf16* __restrict__ V, float* __restrict__ Vm)
{
    __shared__ float osum[4][DKK];
    int bh = blockIdx.x;
    int b = bh >> 3, h = bh & 7;
    int tid = threadIdx.x, d = tid & 63, part = tid >> 6;
    const __bf16* vp = V + ((size_t)(b * LL + part * 512) * DD + h * DKK + d);
    float s = 0.f;
    for (int i = 0; i < 512; i++) s += (float)vp[(size_t)i * DD];
    osum[part][d] = s;
    __syncthreads();
    if (tid < DKK)
        Vm[bh * DKK + tid] = (osum[0][tid] + osum[1][tid] + osum[2][tid] + osum[3][tid]) * (1.0f / (float)LL);
}

// ------------- gather Q[top] -> qred[32][48][64] bf16, scaled by 1/8 -------
__global__ __launch_bounds__(256) void gather_qred(
    const float* __restrict__ Q, const int* __restrict__ top,
    __bf16* __restrict__ qred, int U)
{
    int bh = blockIdx.y;
    int b = bh >> 3, h = bh & 7;
    int e = blockIdx.x * 256 + threadIdx.x;   // 0..48*64-1
    int u = e >> 6, d = e & 63;
    float v = 0.f;
    if (u < U) {
        int l = top[bh * U + u];
        v = Q[((size_t)(b * LL + l) * DD + h * DKK) + d] * 0.125f;
    }
    qred[(size_t)bh * 48 * DKK + e] = (__bf16)v;
}

// ------------- batched S[bh][48][2048] = qred[bh] @ K[bh]^T (MFMA) ---------
// Swapped-operand MFMA -> float4 stores of S.
__global__ __launch_bounds__(256) void gemm_s(
    const __bf16* __restrict__ qred, const float* __restrict__ Kb,
    float* __restrict__ S)
{
    __shared__ __bf16 Qs[2 * 48 * 32];    // 2 panels of BK=32
    __shared__ __bf16 Ks[2 * 128 * 32];
    int bh = blockIdx.y, nc = blockIdx.x;
    int b = bh >> 3, h = bh & 7, l0 = nc * 128;
    int tid = threadIdx.x;
    const unsigned int* qsrc = (const unsigned int*)(qred + (size_t)bh * 48 * DKK);
    unsigned int* qdst = (unsigned int*)Qs;
    #pragma unroll
    for (int t = 0; t < 6; t++) {
        int ui = tid + t * 256;            // 0..1535
        int u = ui >> 5, kp = ui & 31;
        int p = kp >> 4, kl2 = kp & 15;
        qdst[p * 768 + u * 16 + kl2] = qsrc[ui];
    }
    #pragma unroll
    for (int t = 0; t < 8; t++) {
        int fi = tid + t * 256;            // 0..2047
        int row = fi >> 4, k4 = fi & 15;
        int p = k4 >> 3, kl = (k4 & 7) * 4;
        float4 kv = *(const float4*)(Kb + ((size_t)(b * LL + l0 + row) * DD + h * DKK + k4 * 4));
        __bf16* dst = Ks + p * 128 * 32 + row * 32 + kl;
        dst[0] = (__bf16)kv.x; dst[1] = (__bf16)kv.y;
        dst[2] = (__bf16)kv.z; dst[3] = (__bf16)kv.w;
    }
    __syncthreads();
    int wave = tid >> 6, lane = tid & 63, l15 = lane & 15, kq = lane >> 4;
    floatx4 acc[3][2] = {};
    #pragma unroll
    for (int p = 0; p < 2; p++) {
        bf16x8 bq[2];
        #pragma unroll
        for (int j = 0; j < 2; j++)
            bq[j] = *(const bf16x8*)(Ks + p * 4096 + (wave * 32 + j * 16 + l15) * 32 + kq * 8);
        #pragma unroll
        for (int i = 0; i < 3; i++) {
            bf16x8 aq = *(const bf16x8*)(Qs + p * 1536 + (i * 16 + l15) * 32 + kq * 8);
            #pragma unroll
            for (int j = 0; j < 2; j++)
                acc[i][j] = __builtin_amdgcn_mfma_f32_16x16x32_bf16(bq[j], aq, acc[i][j], 0, 0, 0);
        }
    }
    // thread holds S[row][col..col+3]: row = i*16+l15, col = l0+wave*32+j*16+kq*4
    #pragma unroll
    for (int i = 0; i < 3; i++) {
        int row = i * 16 + l15;
        #pragma unroll
        for (int j = 0; j < 2; j++) {
            int col = l0 + wave * 32 + j * 16 + kq * 4;
            *(float4*)&S[((size_t)bh * 48 + row) * LL + col] = *(float4*)&acc[i][j];
        }
    }
}

// ------------- row softmax, in-place: S row fp32 -> P row bf16 -------------
__global__ __launch_bounds__(256) void softmax_p(float* __restrict__ S, int U)
{
    __shared__ float red[256];
    int row = blockIdx.x;              // 32*U rows
    int bh = row / U, u = row % U;
    float* sr = S + ((size_t)bh * 48 + u) * LL;
    int tid = threadIdx.x;
    float sc[8]; float mx = -1e30f;
    #pragma unroll
    for (int i = 0; i < 8; i++) { sc[i] = sr[tid + i * 256]; mx = fmaxf(mx, sc[i]); }
    red[tid] = mx; __syncthreads();
    for (int s = 128; s > 0; s >>= 1) { if (tid < s) red[tid] = fmaxf(red[tid], red[tid + s]); __syncthreads(); }
    mx = red[0]; __syncthreads();
    float se = 0.f;
    #pragma unroll
    for (int i = 0; i < 8; i++) { sc[i] = __expf(sc[i] - mx); se += sc[i]; }
    red[tid] = se; __syncthreads();
    for (int s = 128; s > 0; s >>= 1) { if (tid < s) red[tid] += red[tid + s]; __syncthreads(); }
    float inv = 1.0f / red[0];
    __bf16* pr = (__bf16*)sr;
    #pragma unroll
    for (int i = 0; i < 8; i++) pr[tid + i * 256] = (__bf16)(sc[i] * inv);
}

// ------------- zero upd (pv_k accumulates via atomicAdd) -------------------
__global__ __launch_bounds__(256) void zero_upd(float* __restrict__ upd, int n)
{
    int i = blockIdx.x * 256 + threadIdx.x;
    if (i < n) upd[i] = 0.f;
}

// ------------- upd[bh][u][d] += sum_{l in chunk} P[u][l] * V[b,h,l,d] ------
// L split 4-way (1280 blocks = 5/CU); uint2 V loads; LDS partials + atomicAdd.
__global__ __launch_bounds__(256) void pv_k(
    const float* __restrict__ S, const __bf16* __restrict__ V,
    float* __restrict__ upd, int U)
{
    __shared__ __bf16 pls[4][512];        // 4 KB
    __shared__ float osum[16][4][DKK];    // 16 KB
    int uc = blockIdx.x, lc = blockIdx.y, bh = blockIdx.z;
    int b = bh >> 3, h = bh & 7, tid = threadIdx.x;
    #pragma unroll
    for (int t = 0; t < 4; t++) {
        int ui = tid + t * 256;          // 0..1023
        int up = ui >> 8, lw = ui & 255;
        ((unsigned int*)pls)[up * 256 + lw] =
            ((const unsigned int*)(S + ((size_t)bh * 48 + uc * 4 + up) * LL))[lc * 256 + lw];
    }
    __syncthreads();
    int d4 = tid & 15, part = tid >> 4;   // 16 parts of 32 l; d4 covers 4 d's
    const __bf16* vp = V + ((size_t)(b * LL + lc * 512 + part * 32)) * DD + h * DKK + d4 * 4;
    float a[4][4] = {};
    for (int i = 0; i < 32; i++) {
        union { uint2 u; __bf16 bb[4]; } cv;
        cv.u = *(const uint2*)(vp + (size_t)i * DD);
        float v0 = (float)cv.bb[0], v1 = (float)cv.bb[1];
        float v2 = (float)cv.bb[2], v3 = (float)cv.bb[3];
        int l = part * 32 + i;
        #pragma unroll
        for (int u2 = 0; u2 < 4; u2++) {
            float p = (float)pls[u2][l];
            a[u2][0] += p * v0; a[u2][1] += p * v1;
            a[u2][2] += p * v2; a[u2][3] += p * v3;
        }
    }
    #pragma unroll
    for (int u2 = 0; u2 < 4; u2++)
        #pragma unroll
        for (int j = 0; j < 4; j++)
            osum[part][u2][d4 * 4 + j] = a[u2][j];
    __syncthreads();
    int d = tid & 63, u2 = tid >> 6;
    float s = 0.f;
    #pragma unroll
    for (int p = 0; p < 16; p++) s += osum[p][u2][d];
    atomicAdd(&upd[((size_t)bh * U + uc * 4 + u2) * DKK + d], s);
}

// ------------- base[b][n] = cmean[b] . Wo[:,n]  (fp32, tiny) ---------------
__global__ __launch_bounds__(256) void base_k(
    const float* __restrict__ Vm, const float* __restrict__ Wo,
    float* __restrict__ base)
{
    __shared__ float cm[DD];
    __shared__ float part[8][32];
    int b = blockIdx.y, n0 = blockIdx.x * 32, tid = threadIdx.x;
    cm[tid] = Vm[b * DD + tid];
    cm[tid + 256] = Vm[b * DD + 256 + tid];
    __syncthreads();
    int n = n0 + (tid & 31), kg = tid >> 5;      // 8 k-groups of 64
    float s = 0.f;
    for (int k = kg * 64; k < kg * 64 + 64; k++) s += cm[k] * Wo[(size_t)k * DD + n];
    part[kg][tid & 31] = s;
    __syncthreads();
    if (tid < 32) {
        float t = 0.f;
        #pragma unroll
        for (int g = 0; g < 8; g++) t += part[g][tid];
        base[b * DD + n0 + tid] = t;
    }
}

// ------------- aout init: every row of batch b <- base[b] ------------------
__global__ __launch_bounds__(256) void aout_init(
    const float* __restrict__ base, float* __restrict__ aout)
{
    int idx = blockIdx.x * 256 + threadIdx.x;    // over B*L*512
    aout[idx] = base[((idx >> 20) << 9) + (idx & 511)];
}

// ------------- aw[bh][u48][d] = bf16(upd - Vm) -----------------------------
__global__ __launch_bounds__(256) void aw_prep(
    const float* __restrict__ upd, const float* __restrict__ Vm,
    __bf16* __restrict__ aw, int U)
{
    int bh = blockIdx.x, tid = threadIdx.x;
    #pragma unroll
    for (int t = 0; t < 12; t++) {
        int e = tid + t * 256;                   // 0..3071
        int u = e >> 6, d = e & 63;
        float v = (u < U) ? upd[((size_t)bh * U + u) * DKK + d] - Vm[bh * DKK + d] : 0.f;
        aw[(size_t)bh * 48 * DKK + e] = (__bf16)v;
    }
}

// ------------- corr GEMM + scatter-add: aout[b, top[u]] += aw @ Wo_h -------
__global__ __launch_bounds__(256) void corr_gemm(
    const __bf16* __restrict__ aw, const __bf16* __restrict__ WoT,
    const int* __restrict__ top, float* __restrict__ aout, int U)
{
    __shared__ __bf16 Qs[2 * 48 * 32];    // aw panels (BK=32)
    __shared__ __bf16 Ks[2 * 128 * 32];   // WoT-slice panels
    int bh = blockIdx.y, nc = blockIdx.x;
    int b = bh >> 3, h = bh & 7, n0 = nc * 128;
    int tid = threadIdx.x;
    const unsigned int* qsrc = (const unsigned int*)(aw + (size_t)bh * 48 * DKK);
    unsigned int* qdst = (unsigned int*)Qs;
    #pragma unroll
    for (int t = 0; t < 6; t++) {
        int ui = tid + t * 256;            // 0..1535
        int u = ui >> 5, kp = ui & 31;
        int p = kp >> 4, kl2 = kp & 15;
        qdst[p * 768 + u * 16 + kl2] = qsrc[ui];
    }
    const unsigned int* wsrc = (const unsigned int*)WoT;
    unsigned int* kdst = (unsigned int*)Ks;
    #pragma unroll
    for (int t = 0; t < 16; t++) {
        int ui = tid + t * 256;            // 0..4095
        int row = ui >> 5, c2 = ui & 31;
        int p = c2 >> 4, col2 = c2 & 15;
        kdst[p * 2048 + row * 16 + col2] = wsrc[(size_t)(n0 + row) * (DD / 2) + h * 32 + c2];
    }
    __syncthreads();
    int wave = tid >> 6, lane = tid & 63, l15 = lane & 15, kq = lane >> 4;
    floatx4 acc[3][2] = {};
    #pragma unroll
    for (int p = 0; p < 2; p++) {
        bf16x8 bq[2];
        #pragma unroll
        for (int j = 0; j < 2; j++)
            bq[j] = *(const bf16x8*)(Ks + p * 4096 + (wave * 32 + j * 16 + l15) * 32 + kq * 8);
        #pragma unroll
        for (int i = 0; i < 3; i++) {
            bf16x8 aq = *(const bf16x8*)(Qs + p * 1536 + (i * 16 + l15) * 32 + kq * 8);
            #pragma unroll
            for (int j = 0; j < 2; j++)
                acc[i][j] = __builtin_amdgcn_mfma_f32_16x16x32_bf16(bq[j], aq, acc[i][j], 0, 0, 0);
        }
    }
    #pragma unroll
    for (int i = 0; i < 3; i++) {
        int u = i * 16 + l15;
        if (u < U) {
            int l = top[bh * U + u];
            float* dst = aout + ((size_t)(b * LL + l)) * DD;
            #pragma unroll
            for (int j = 0; j < 2; j++) {
                int n = n0 + wave * 32 + j * 16 + kq * 4;
                atomicAdd(dst + n,     acc[i][j][0]);
                atomicAdd(dst + n + 1, acc[i][j][1]);
                atomicAdd(dst + n + 2, acc[i][j][2]);
                atomicAdd(dst + n + 3, acc[i][j][3]);
            }
        }
    }
}

// ------------- LN1: x1 = LN(x + aout) -> bf16 ------------------------------
__global__ __launch_bounds__(256) void ln1_k(
    const float* __restrict__ x, const float* __restrict__ aout,
    const float* __restrict__ g, const float* __restrict__ bb,
    __bf16* __restrict__ x1h)
{
    __shared__ float red[256];
    int row = blockIdx.x, tid = threadIdx.x;
    size_t base = (size_t)row * DD;
    float h0 = x[base + tid] + aout[base + tid];
    float h1 = x[base + 256 + tid] + aout[base + 256 + tid];
    red[tid] = h0 + h1; __syncthreads();
    for (int s = 128; s > 0; s >>= 1) { if (tid < s) red[tid] += red[tid + s]; __syncthreads(); }
    float mean = red[0] * (1.0f / DD); __syncthreads();
    float d0 = h0 - mean, d1 = h1 - mean;
    red[tid] = d0 * d0 + d1 * d1; __syncthreads();
    for (int s = 128; s > 0; s >>= 1) { if (tid < s) red[tid] += red[tid + s]; __syncthreads(); }
    float rstd = rsqrtf(red[0] * (1.0f / DD) + 1e-5f);
    x1h[base + tid]       = (__bf16)(d0 * rstd * g[tid] + bb[tid]);
    x1h[base + 256 + tid] = (__bf16)(d1 * rstd * g[256 + tid] + bb[256 + tid]);
}

// ------------- LN2: out = LN(x1 + ffn2 + b2) -> fp32 -----------------------
__global__ __launch_bounds__(256) void ln2_k(
    const __bf16* __restrict__ x1h, const float* __restrict__ f2o,
    const float* __restrict__ c2b,
    const float* __restrict__ g, const float* __restrict__ bb,
    float* __restrict__ out)
{
    __shared__ float red[256];
    int row = blockIdx.x, tid = threadIdx.x;
    size_t base = (size_t)row * DD;
    float h0 = (float)x1h[base + tid] + f2o[base + tid] + c2b[tid];
    float h1 = (float)x1h[base + 256 + tid] + f2o[base + 256 + tid] + c2b[256 + tid];
    red[tid] = h0 + h1; __syncthreads();
    for (int s = 128; s > 0; s >>= 1) { if (tid < s) red[tid] += red[tid + s]; __syncthreads(); }
    float mean = red[0] * (1.0f / DD); __syncthreads();
    float d0 = h0 - mean, d1 = h1 - mean;
    red[tid] = d0 * d0 + d1 * d1; __syncthreads();
    for (int s = 128; s > 0; s >>= 1) { if (tid < s) red[tid] += red[tid + s]; __syncthreads(); }
    float rstd = rsqrtf(red[0] * (1.0f / DD) + 1e-5f);
    out[base + tid]       = d0 * rstd * g[tid] + bb[tid];
    out[base + 256 + tid] = d1 * rstd * g[256 + tid] + bb[256 + tid];
}

// ---------------------------------------------------------------------------
extern "C" void kernel_launch(void* const* d_in, const int* in_sizes, int n_in,
                              void* d_out, int out_size, void* d_ws, size_t ws_size,
                              hipStream_t stream)
{
    const float* x   = (const float*)d_in[0];
    const float* Wq  = (const float*)d_in[1];
    const float* Wk  = (const float*)d_in[2];
    const float* Wv  = (const float*)d_in[3];
    const float* Wo  = (const float*)d_in[4];
    const float* g1  = (const float*)d_in[5];
    const float* b1  = (const float*)d_in[6];
    const float* c1w = (const float*)d_in[7];
    const float* c1b = (const float*)d_in[8];
    const float* c2w = (const float*)d_in[9];
    const float* c2b = (const float*)d_in[10];
    const float* g2  = (const float*)d_in[11];
    const float* b2  = (const float*)d_in[12];
    const int* sidx  = (const int*)d_in[13];
    float* out       = (float*)d_out;

    const int U = in_sizes[13] / LL;            // 40
    const int M = BB * LL;                       // 8192

    char* ws = (char*)d_ws;
    const size_t MB = (size_t)1 << 20;
    float*  Q    = (float*)(ws + 0);
    float*  Kb   = (float*)(ws + 16 * MB);
    __bf16* V    = (__bf16*)(ws + 32 * MB);
    __bf16* xhi  = (__bf16*)(ws + 40 * MB);
    __bf16* xlo  = (__bf16*)(ws + 48 * MB);
    float*  S    = (float*)(ws + 40 * MB);          // 32*48*2048*4 = 12.6 MB
    __bf16* wb   = (__bf16*)(ws + 56 * MB);
    __bf16* c1wb = (__bf16*)(ws + 59 * MB);
    __bf16* c2wb = (__bf16*)(ws + 61 * MB);
    float*  Mo   = (float*)(ws + 63 * MB);
    float*  upd  = (float*)(ws + 63 * MB + 256 * 1024);
    float*  Vm   = (float*)(ws + 63 * MB + 576 * 1024);
    int*    top  = (int*)  (ws + 63 * MB + 584 * 1024);
    __bf16* qred = (__bf16*)(ws + 63 * MB + 592 * 1024);  // 192K
    __bf16* aw   = (__bf16*)(ws + 63 * MB + 784 * 1024);  // 192K
    float*  basep= (float*)(ws + 63 * MB + 976 * 1024);   // 8K
    float*  aout = Q;                               // alias: Q dead after gather_qred
    float*  f2o  = Q;                               // alias: aout dead after ln1
    __bf16* ych  = (__bf16*)(ws + 16 * MB);         // FFN intermediate (32 MB region)
    __bf16* x1h  = xlo;                             // alias: S/P dead by ln1
    (void)ws_size; (void)n_in; (void)out_size;

    const size_t SZ = (size_t)DD * DD;
    __bf16* WqThi = wb;          __bf16* WqTlo = wb + SZ;
    __bf16* WkThi = wb + 2 * SZ; __bf16* WkTlo = wb + 3 * SZ;
    __bf16* WvT   = wb + 4 * SZ; __bf16* WoT   = wb + 5 * SZ;

    // 1) weight prep + input split-cast
    prep_w<<<dim3(DD * DD / 256, 1, 4), 256, 0, stream>>>(Wq, Wk, Wv, Wo, wb);
    cast_cw<<<dim3(FF * DD / 256, 1, 2), 256, 0, stream>>>(c1w, c2w, c1wb, c2wb);
    split_cast_x<<<BB * LL * DD / 256, 256, 0, stream>>>(x, xhi, xlo);

    // 2) Q,K via split-precision MFMA (BM=64: 512 blocks = 2/CU); V bf16 (same)
    dim3 gproj64(DD / 128, M / 64);
    gemm_mfma_split64<<<gproj64, 256, 0, stream>>>(xhi, xlo, WqThi, WqTlo, Q,  M, DD, DD);
    gemm_mfma_split64<<<gproj64, 256, 0, stream>>>(xhi, xlo, WkThi, WkTlo, Kb, M, DD, DD);
    gemm_mfma64<6, 0, false, true ><<<gproj64, 256, 0, stream>>>(xhi, WvT, nullptr, V, M, DD, DD);

    // 3) sampled sparsity measure M, top-k, V mean (+ zero upd for pv atomics)
    calc_m<<<BB * LL, 256, 0, stream>>>(Q, Kb, sidx, Mo, U);
    zero_upd<<<(BB * HH * U * DKK + 255) / 256, 256, 0, stream>>>(upd, BB * HH * U * DKK);
    topk_k<<<BB * HH, 256, 0, stream>>>(Mo, top, U);
    vmean_k<<<BB * HH, 256, 0, stream>>>(V, Vm);

    // 4) attention: gather -> batched MFMA S -> softmax(in-place bf16 P) -> PV
    gather_qred<<<dim3(48 * DKK / 256, BB * HH), 256, 0, stream>>>(Q, top, qred, U);
    gemm_s<<<dim3(LL / 128, BB * HH), 256, 0, stream>>>(qred, Kb, S);
    softmax_p<<<BB * HH * U, 256, 0, stream>>>(S, U);
    pv_k<<<dim3(U / 4, 4, BB * HH), 256, 0, stream>>>(S, V, upd, U);

    // 5) out-projection via base + rank-U correction (Wo-GEMM eliminated)
    base_k<<<dim3(16, BB), 256, 0, stream>>>(Vm, Wo, basep);
    aw_prep<<<BB * HH, 256, 0, stream>>>(upd, Vm, aw, U);
    aout_init<<<M * DD / 256, 256, 0, stream>>>(basep, aout);
    corr_gemm<<<dim3(DD / 128, BB * HH), 256, 0, stream>>>(aw, WoT, top, aout, U);

    // 6) LN1 -> x1h bf16 (aliases xlo; S/P dead)
    ln1_k<<<M, 256, 0, stream>>>(x, aout, g1, b1, x1h);

    // 7) FFN: gelu(x1 @ c1w^T + c1b) -> ych bf16 (BM=128, 1024 blocks = 4/CU);
    //    ych @ c2w^T -> f2o (BM=64: 512 blocks = 2/CU, NB=6 deep prefetch)
    gemm_mfma<3, 1, true,  true ><<<dim3(FF / 128, M / 128), 256, 0, stream>>>(x1h, c1wb, c1b, ych, M, FF, DD);
    gemm_mfma64<6, 0, false, false><<<dim3(DD / 128, M / 64), 256, 0, stream>>>(ych, c2wb, nullptr, f2o, M, DD, FF);

    // 8) LN2 -> fp32 output
    ln2_k<<<M, 256, 0, stream>>>(x1h, f2o, c2b, g2, b2, out);
}

// Round 12
// 388.447 us; speedup vs baseline: 1.1059x; 1.0027x over previous
//
#include <hip/hip_runtime.h>
#include <hip/hip_bf16.h>

// Problem constants (B=4, L=2048, D=512, H=8, DK=64, FF=2048, U=40)
#define BB 4
#define LL 2048
#define DD 512
#define HH 8
#define DKK 64
#define FF 2048

typedef __bf16  bf16x8  __attribute__((ext_vector_type(8)));
typedef float   floatx4 __attribute__((ext_vector_type(4)));

// async 16B global->LDS copy (global_load_lds_dwordx4)
__device__ __forceinline__ void async_cp16(const void* g, void* l) {
    __builtin_amdgcn_global_load_lds(
        (const __attribute__((address_space(1))) unsigned int*)g,
        (__attribute__((address_space(3))) unsigned int*)l,
        16, 0, 0);
}

// exact-grade GELU: A&S 7.1.26 erf, |err| < 1.5e-7 (fp32-exact at our scale).
__device__ __forceinline__ float gelu_f(float v) {
    float z  = v * 0.70710678118654752f;
    float az = fabsf(z);
    float t  = __builtin_amdgcn_rcpf(1.0f + 0.3275911f * az);
    float p  = ((((1.061405429f * t - 1.453152027f) * t + 1.421413741f) * t
                 - 0.284496736f) * t + 0.254829592f) * t;
    float e  = __expf(-z * z);
    float er = 1.0f - p * e;
    er = (z < 0.0f) ? -er : er;
    return 0.5f * v * (1.0f + er);
}

// ---------- prep: transpose 512x512 fp32 -> bf16 (N,K); Wq/Wk also lo-part ----
__global__ __launch_bounds__(256) void prep_w(
    const float* __restrict__ Wq, const float* __restrict__ Wk,
    const float* __restrict__ Wv, const float* __restrict__ Wo,
    __bf16* __restrict__ wb)
{
    const size_t SZ = (size_t)DD * DD;
    int z = blockIdx.z;
    const float* s = (z == 0) ? Wq : (z == 1) ? Wk : (z == 2) ? Wv : Wo;
    __bf16* hi; __bf16* lo = nullptr;
    if (z == 0)      { hi = wb;          lo = wb + SZ; }
    else if (z == 1) { hi = wb + 2 * SZ; lo = wb + 3 * SZ; }
    else if (z == 2) { hi = wb + 4 * SZ; }
    else             { hi = wb + 5 * SZ; }
    int idx = blockIdx.x * 256 + threadIdx.x;   // 0..512*512-1
    int k = idx >> 9, n = idx & 511;
    float v = s[idx];
    __bf16 h = (__bf16)v;
    hi[(size_t)n * DD + k] = h;
    if (lo) lo[(size_t)n * DD + k] = (__bf16)(v - (float)h);
}

// ---------- cast conv weights fp32 (N,K) -> bf16 -----------------------------
__global__ __launch_bounds__(256) void cast_cw(
    const float* __restrict__ c1w, const float* __restrict__ c2w,
    __bf16* __restrict__ d1, __bf16* __restrict__ d2)
{
    const float* s = blockIdx.z ? c2w : c1w;
    __bf16* d = blockIdx.z ? d2 : d1;
    int idx = blockIdx.x * 256 + threadIdx.x;   // 0..FF*DD-1
    d[idx] = (__bf16)s[idx];
}

// ---------- split-cast x fp32 -> bf16 hi + lo --------------------------------
__global__ __launch_bounds__(256) void split_cast_x(
    const float* __restrict__ x, __bf16* __restrict__ xhi, __bf16* __restrict__ xlo)
{
    int idx = blockIdx.x * 256 + threadIdx.x;
    float v = x[idx];
    __bf16 h = (__bf16)v;
    xhi[idx] = h;
    xlo[idx] = (__bf16)(v - (float)h);
}

// ---------- MFMA GEMM, 128x128 tile (FFN1: 1024 blocks = 4/CU) ---------------
// NB-buffer pipeline, single barrier + counted vmcnt per k-step; bank swizzle
// (r8: conflicts -> 0); XCD swizzle; swapped-operand vector epilogue.
template<int NB, int ACT, bool BIAS, bool OUT_BF16>
__global__ __launch_bounds__(256) void gemm_mfma(
    const __bf16* __restrict__ A, const __bf16* __restrict__ B,
    const float* __restrict__ bias, void* __restrict__ Cv,
    int M, int N, int K)
{
    __shared__ __bf16 As[NB][128 * 32];
    __shared__ __bf16 Bs[NB][128 * 32];
    const int tid = threadIdx.x;
    const int wave = tid >> 6, lane = tid & 63;
    const int gx = gridDim.x;
    const int nwg = gx * gridDim.y;
    const int hw = blockIdx.y * gx + blockIdx.x;
    const int virt = ((nwg & 7) == 0) ? ((hw & 7) * (nwg >> 3) + (hw >> 3)) : hw;
    const int m0 = (virt / gx) * 128, n0 = (virt % gx) * 128;
    const int wm = (wave >> 1) * 64, wn = (wave & 1) * 64;
    const int l15 = lane & 15, kq = lane >> 4;

    auto stage = [&](int buf, int k0) {           // 4 vmem insts per thread
        #pragma unroll
        for (int p = 0; p < 2; p++) {
            int c = p * 256 + tid;                // 16B chunk id 0..511
            int row = c >> 2;
            int col = ((c & 3) ^ ((row >> 1) & 3)) * 8;   // inverse-swizzled src
            async_cp16(A + (size_t)(m0 + row) * K + k0 + col, &As[buf][c * 8]);
            async_cp16(B + (size_t)(n0 + row) * K + k0 + col, &Bs[buf][c * 8]);
        }
    };

    floatx4 acc[4][4] = {};

    const int nt = K >> 5;
    #pragma unroll
    for (int pt = 0; pt < NB - 1; pt++) stage(pt, pt << 5);
    if constexpr (NB == 6) asm volatile("s_waitcnt vmcnt(16)" ::: "memory");
    else                   asm volatile("s_waitcnt vmcnt(4)"  ::: "memory");
    __builtin_amdgcn_s_barrier();
    int bi = 0;                                   // buffer of current tile
    for (int t = 0; t < nt; t++) {
        if (t + NB - 1 < nt) {
            int b2 = bi + NB - 1; if (b2 >= NB) b2 -= NB;
            stage(b2, (t + NB - 1) << 5);
        }
        asm volatile("" ::: "memory");
        bf16x8 af[4], bfr[4];
        #pragma unroll
        for (int i = 0; i < 4; i++) {
            int ra = wm + i * 16 + l15;
            af[i] = *(const bf16x8*)(&As[bi][ra * 32 + ((kq ^ ((ra >> 1) & 3)) << 3)]);
        }
        #pragma unroll
        for (int j = 0; j < 4; j++) {
            int rb = wn + j * 16 + l15;
            bfr[j] = *(const bf16x8*)(&Bs[bi][rb * 32 + ((kq ^ ((rb >> 1) & 3)) << 3)]);
        }
        #pragma unroll
        for (int i = 0; i < 4; i++)
            #pragma unroll
            for (int j = 0; j < 4; j++)
                acc[i][j] = __builtin_amdgcn_mfma_f32_16x16x32_bf16(bfr[j], af[i], acc[i][j], 0, 0, 0);
        asm volatile("" ::: "memory");
        if (t + 1 < nt) {                         // wait: tile t+1 landed
            int c = nt - 2 - t; if (c > NB - 2) c = NB - 2;
            if (c >= 4)      asm volatile("s_waitcnt vmcnt(16)" ::: "memory");
            else if (c == 3) asm volatile("s_waitcnt vmcnt(12)" ::: "memory");
            else if (c == 2) asm volatile("s_waitcnt vmcnt(8)"  ::: "memory");
            else if (c == 1) asm volatile("s_waitcnt vmcnt(4)"  ::: "memory");
            else             asm volatile("s_waitcnt vmcnt(0)"  ::: "memory");
            __builtin_amdgcn_s_barrier();
        }
        if (++bi == NB) bi = 0;
    }
    #pragma unroll
    for (int i = 0; i < 4; i++) {
        int m = m0 + wm + i * 16 + l15;
        #pragma unroll
        for (int j = 0; j < 4; j++) {
            int n = n0 + wn + j * 16 + kq * 4;
            floatx4 v4 = acc[i][j];
            if (BIAS) {
                float4 bv = *(const float4*)&bias[n];
                v4[0] += bv.x; v4[1] += bv.y; v4[2] += bv.z; v4[3] += bv.w;
            }
            if (ACT == 1) {
                v4[0] = gelu_f(v4[0]); v4[1] = gelu_f(v4[1]);
                v4[2] = gelu_f(v4[2]); v4[3] = gelu_f(v4[3]);
            }
            if (OUT_BF16) {
                union { __bf16 b[4]; uint2 u; } pk;
                pk.b[0] = (__bf16)v4[0]; pk.b[1] = (__bf16)v4[1];
                pk.b[2] = (__bf16)v4[2]; pk.b[3] = (__bf16)v4[3];
                *(uint2*)((__bf16*)Cv + (size_t)m * N + n) = pk.u;
            } else {
                *(float4*)((float*)Cv + (size_t)m * N + n) = *(float4*)&v4;
            }
        }
    }
}

// ---------- MFMA GEMM, 64x128 tile for grid-limited N=512 GEMMs --------------
// r10/r11 A/B isolated the lever: TLP (blocks/CU), not prefetch depth.
// NB=3 -> 36 KB LDS -> 4 blocks/CU = 4 waves/SIMD (was NB=6 = 72 KB = 2/CU).
// 88 VGPR x 4 waves = 352 <= 512 per SIMD. Wave-tile 32x64, acc[2][4].
template<int NB, int ACT, bool BIAS, bool OUT_BF16>
__global__ __launch_bounds__(256) void gemm_mfma64(
    const __bf16* __restrict__ A, const __bf16* __restrict__ B,
    const float* __restrict__ bias, void* __restrict__ Cv,
    int M, int N, int K)
{
    __shared__ __bf16 As[NB][64 * 32];
    __shared__ __bf16 Bs[NB][128 * 32];
    const int tid = threadIdx.x;
    const int wave = tid >> 6, lane = tid & 63;
    const int gx = gridDim.x;
    const int nwg = gx * gridDim.y;
    const int hw = blockIdx.y * gx + blockIdx.x;
    const int virt = ((nwg & 7) == 0) ? ((hw & 7) * (nwg >> 3) + (hw >> 3)) : hw;
    const int m0 = (virt / gx) * 64, n0 = (virt % gx) * 128;
    const int wm = (wave >> 1) * 32, wn = (wave & 1) * 64;
    const int l15 = lane & 15, kq = lane >> 4;

    auto stage = [&](int buf, int k0) {           // 3 vmem insts per thread
        {
            int c = tid;                          // A: 256 chunks (64 rows x 4)
            int row = c >> 2;
            int col = ((c & 3) ^ ((row >> 1) & 3)) * 8;
            async_cp16(A + (size_t)(m0 + row) * K + k0 + col, &As[buf][c * 8]);
        }
        #pragma unroll
        for (int p = 0; p < 2; p++) {
            int c = p * 256 + tid;                // B: 512 chunks
            int row = c >> 2;
            int col = ((c & 3) ^ ((row >> 1) & 3)) * 8;
            async_cp16(B + (size_t)(n0 + row) * K + k0 + col, &Bs[buf][c * 8]);
        }
    };

    floatx4 acc[2][4] = {};

    const int nt = K >> 5;
    #pragma unroll
    for (int pt = 0; pt < NB - 1; pt++) stage(pt, pt << 5);
    if constexpr (NB == 6) asm volatile("s_waitcnt vmcnt(12)" ::: "memory");
    else                   asm volatile("s_waitcnt vmcnt(3)"  ::: "memory");
    __builtin_amdgcn_s_barrier();
    int bi = 0;
    for (int t = 0; t < nt; t++) {
        if (t + NB - 1 < nt) {
            int b2 = bi + NB - 1; if (b2 >= NB) b2 -= NB;
            stage(b2, (t + NB - 1) << 5);
        }
        asm volatile("" ::: "memory");
        bf16x8 af[2], bfr[4];
        #pragma unroll
        for (int i = 0; i < 2; i++) {
            int ra = wm + i * 16 + l15;
            af[i] = *(const bf16x8*)(&As[bi][ra * 32 + ((kq ^ ((ra >> 1) & 3)) << 3)]);
        }
        #pragma unroll
        for (int j = 0; j < 4; j++) {
            int rb = wn + j * 16 + l15;
            bfr[j] = *(const bf16x8*)(&Bs[bi][rb * 32 + ((kq ^ ((rb >> 1) & 3)) << 3)]);
        }
        #pragma unroll
        for (int i = 0; i < 2; i++)
            #pragma unroll
            for (int j = 0; j < 4; j++)
                acc[i][j] = __builtin_amdgcn_mfma_f32_16x16x32_bf16(bfr[j], af[i], acc[i][j], 0, 0, 0);
        asm volatile("" ::: "memory");
        if (t + 1 < nt) {
            int c = nt - 2 - t; if (c > NB - 2) c = NB - 2;
            if (c >= 4)      asm volatile("s_waitcnt vmcnt(12)" ::: "memory");
            else if (c == 3) asm volatile("s_waitcnt vmcnt(9)"  ::: "memory");
            else if (c == 2) asm volatile("s_waitcnt vmcnt(6)"  ::: "memory");
            else if (c == 1) asm volatile("s_waitcnt vmcnt(3)"  ::: "memory");
            else             asm volatile("s_waitcnt vmcnt(0)"  ::: "memory");
            __builtin_amdgcn_s_barrier();
        }
        if (++bi == NB) bi = 0;
    }
    #pragma unroll
    for (int i = 0; i < 2; i++) {
        int m = m0 + wm + i * 16 + l15;
        #pragma unroll
        for (int j = 0; j < 4; j++) {
            int n = n0 + wn + j * 16 + kq * 4;
            floatx4 v4 = acc[i][j];
            if (BIAS) {
                float4 bv = *(const float4*)&bias[n];
                v4[0] += bv.x; v4[1] += bv.y; v4[2] += bv.z; v4[3] += bv.w;
            }
            if (ACT == 1) {
                v4[0] = gelu_f(v4[0]); v4[1] = gelu_f(v4[1]);
                v4[2] = gelu_f(v4[2]); v4[3] = gelu_f(v4[3]);
            }
            if (OUT_BF16) {
                union { __bf16 b[4]; uint2 u; } pk;
                pk.b[0] = (__bf16)v4[0]; pk.b[1] = (__bf16)v4[1];
                pk.b[2] = (__bf16)v4[2]; pk.b[3] = (__bf16)v4[3];
                *(uint2*)((__bf16*)Cv + (size_t)m * N + n) = pk.u;
            } else {
                *(float4*)((float*)Cv + (size_t)m * N + n) = *(float4*)&v4;
            }
        }
    }
}

// ---------- split-precision MFMA GEMM, 64x128 tile (Q/K projections) ---------
// C = (Ah+Al)(Bh+Bl)^T. Grid 512 = 2 blocks/CU. NB=3, 72 KB LDS.
__global__ __launch_bounds__(256) void gemm_mfma_split64(
    const __bf16* __restrict__ Ah, const __bf16* __restrict__ Al,
    const __bf16* __restrict__ Bh, const __bf16* __restrict__ Bl,
    float* __restrict__ C, int M, int N, int K)
{
    __shared__ __bf16 Ahs[3][64 * 32];
    __shared__ __bf16 Als[3][64 * 32];
    __shared__ __bf16 Bhs[3][128 * 32];
    __shared__ __bf16 Bls[3][128 * 32];
    const int tid = threadIdx.x;
    const int wave = tid >> 6, lane = tid & 63;
    const int gx = gridDim.x;
    const int nwg = gx * gridDim.y;
    const int hw = blockIdx.y * gx + blockIdx.x;
    const int virt = ((nwg & 7) == 0) ? ((hw & 7) * (nwg >> 3) + (hw >> 3)) : hw;
    const int m0 = (virt / gx) * 64, n0 = (virt % gx) * 128;
    const int wm = (wave >> 1) * 32, wn = (wave & 1) * 64;
    const int l15 = lane & 15, kq = lane >> 4;

    auto stage = [&](int buf, int k0) {           // 6 vmem insts per thread
        {
            int c = tid;
            int row = c >> 2;
            int col = ((c & 3) ^ ((row >> 1) & 3)) * 8;
            size_t go = (size_t)(m0 + row) * K + k0 + col;
            async_cp16(Ah + go, &Ahs[buf][c * 8]);
            async_cp16(Al + go, &Als[buf][c * 8]);
        }
        #pragma unroll
        for (int p = 0; p < 2; p++) {
            int c = p * 256 + tid;
            int row = c >> 2;
            int col = ((c & 3) ^ ((row >> 1) & 3)) * 8;
            size_t go = (size_t)(n0 + row) * K + k0 + col;
            async_cp16(Bh + go, &Bhs[buf][c * 8]);
            async_cp16(Bl + go, &Bls[buf][c * 8]);
        }
    };

    floatx4 acc[2][4] = {};

    const int nt = K >> 5;
    stage(0, 0); stage(1, 32);
    asm volatile("s_waitcnt vmcnt(6)" ::: "memory");
    __builtin_amdgcn_s_barrier();
    int bi = 0;
    for (int t = 0; t < nt; t++) {
        if (t + 2 < nt) {
            int b2 = bi + 2; if (b2 >= 3) b2 -= 3;
            stage(b2, (t + 2) << 5);
        }
        asm volatile("" ::: "memory");
        bf16x8 ah[2], al[2], bh[4], bl[4];
        #pragma unroll
        for (int i = 0; i < 2; i++) {
            int ra = wm + i * 16 + l15;
            int off = ra * 32 + ((kq ^ ((ra >> 1) & 3)) << 3);
            ah[i] = *(const bf16x8*)(&Ahs[bi][off]);
            al[i] = *(const bf16x8*)(&Als[bi][off]);
        }
        #pragma unroll
        for (int j = 0; j < 4; j++) {
            int rb = wn + j * 16 + l15;
            int off = rb * 32 + ((kq ^ ((rb >> 1) & 3)) << 3);
            bh[j] = *(const bf16x8*)(&Bhs[bi][off]);
            bl[j] = *(const bf16x8*)(&Bls[bi][off]);
        }
        #pragma unroll
        for (int i = 0; i < 2; i++)
            #pragma unroll
            for (int j = 0; j < 4; j++) {
                acc[i][j] = __builtin_amdgcn_mfma_f32_16x16x32_bf16(bh[j], ah[i], acc[i][j], 0, 0, 0);
                acc[i][j] = __builtin_amdgcn_mfma_f32_16x16x32_bf16(bl[j], ah[i], acc[i][j], 0, 0, 0);
                acc[i][j] = __builtin_amdgcn_mfma_f32_16x16x32_bf16(bh[j], al[i], acc[i][j], 0, 0, 0);
            }
        asm volatile("" ::: "memory");
        if (t + 1 < nt) {
            if (t + 2 < nt) asm volatile("s_waitcnt vmcnt(6)" ::: "memory");
            else            asm volatile("s_waitcnt vmcnt(0)" ::: "memory");
            __builtin_amdgcn_s_barrier();
        }
        if (++bi == 3) bi = 0;
    }
    #pragma unroll
    for (int i = 0; i < 2; i++) {
        int m = m0 + wm + i * 16 + l15;
        #pragma unroll
        for (int j = 0; j < 4; j++) {
            int n = n0 + wn + j * 16 + kq * 4;
            *(float4*)(C + (size_t)m * N + n) = *(float4*)&acc[i][j];
        }
    }
}

// ------------- M[b,h,l] = max_s(q·k_s) - sum_s(q·k_s)/L  (sampled) ---------
// 16-lane sum via DPP-fused v_add_f32 (pure VALU; no LDS-pipe ds_swizzle).
__device__ __forceinline__ float dpp_sum16(float p) {
    int t;
    t = __builtin_amdgcn_update_dpp(0, __float_as_int(p), 0xB1,  0xF, 0xF, true); // quad_perm [1,0,3,2]
    p += __int_as_float(t);
    t = __builtin_amdgcn_update_dpp(0, __float_as_int(p), 0x4E,  0xF, 0xF, true); // quad_perm [2,3,0,1]
    p += __int_as_float(t);
    t = __builtin_amdgcn_update_dpp(0, __float_as_int(p), 0x141, 0xF, 0xF, true); // row_half_mirror
    p += __int_as_float(t);
    t = __builtin_amdgcn_update_dpp(0, __float_as_int(p), 0x140, 0xF, 0xF, true); // row_mirror
    p += __int_as_float(t);
    return p;
}

__global__ __launch_bounds__(256) void calc_m(
    const float* __restrict__ Q, const float* __restrict__ Kb,
    const int* __restrict__ sidx, float* __restrict__ Mo, int U)
{
    __shared__ int   js[64];
    __shared__ float red_mx[2][HH];
    __shared__ float red_sm[2][HH];
    int i = blockIdx.x;
    int b = i & 3, l = i >> 2;
    int tid = threadIdx.x;
    if (tid < U) js[tid] = sidx[l * U + tid];
    int e    = (tid & 127) * 4;          // element index within 512-wide row
    int slot = tid >> 7;                 // 0/1: even/odd samples
    const float* qr = Q + ((size_t)(b * LL + l) * DD);
    float4 q = *(const float4*)(qr + e);
    const float* kbase = Kb + ((size_t)b * LL) * DD + e;
    __syncthreads();
    float mx = -1e30f, sm = 0.f;
    for (int s = slot; s < U; s += 2) {
        int j = js[s];
        float4 kv = *(const float4*)(kbase + (size_t)j * DD);
        float p = q.x * kv.x + q.y * kv.y + q.z * kv.z + q.w * kv.w;
        p = dpp_sum16(p);
        mx = fmaxf(mx, p);
        sm += p;
    }
    if ((tid & 15) == 0) {
        int head = (tid >> 4) & 7;
        red_mx[slot][head] = mx;
        red_sm[slot][head] = sm;
    }
    __syncthreads();
    if (tid < HH) {
        float m2 = fmaxf(red_mx[0][tid], red_mx[1][tid]);
        float s2 = red_sm[0][tid] + red_sm[1][tid];
        Mo[((size_t)(b * HH + tid)) * LL + l] = m2 - s2 * (1.0f / (float)LL);
    }
}

// ------------- radix-select top-40 per (b,h) row of M ----------------------
__global__ __launch_bounds__(256) void topk_k(
    const float* __restrict__ Mo, int* __restrict__ top, int U)
{
    __shared__ unsigned int hist[256];
    __shared__ unsigned int wsum[4];
    __shared__ unsigned int bc[2];
    __shared__ int ties[LL];
    __shared__ int cnt2[2];
    int bh = blockIdx.x, tid = threadIdx.x;
    int lane = tid & 63, w = tid >> 6;

    unsigned int my[8];
    #pragma unroll
    for (int i = 0; i < 8; i++) {
        unsigned int u = __float_as_uint(Mo[(size_t)bh * LL + tid + i * 256]);
        my[i] = u ^ ((u >> 31) ? 0xFFFFFFFFu : 0x80000000u);  // order-preserving
    }

    unsigned int prefix = 0, pmask = 0;
    unsigned int need = (unsigned int)U;
    unsigned int above = 0;

    for (int pass = 0; pass < 4; pass++) {
        int shift = 24 - pass * 8;
        hist[tid] = 0;
        __syncthreads();
        #pragma unroll
        for (int i = 0; i < 8; i++) {
            unsigned int u = my[i];
            if ((u & pmask) == prefix)
                atomicAdd(&hist[(u >> shift) & 255u], 1u);
        }
        __syncthreads();
        unsigned int h = hist[tid];
        #pragma unroll
        for (int off = 1; off < 64; off <<= 1) {
            unsigned int o = __shfl_down(h, off);
            if (lane + off < 64) h += o;
        }
        if (lane == 0) wsum[w] = h;
        __syncthreads();
        unsigned int tail = 0;
        #pragma unroll
        for (int w2 = 1; w2 < 4; w2++) if (w2 > w) tail += wsum[w2];
        h += tail;
        hist[tid] = h;
        __syncthreads();
        unsigned int St = h;
        unsigned int St1 = (tid < 255) ? hist[tid + 1] : 0u;
        if (St >= need && St1 < need) { bc[0] = (unsigned int)tid; bc[1] = St1; }
        __syncthreads();
        unsigned int dig = bc[0], abv = bc[1];
        above += abv;
        need -= abv;
        prefix |= dig << shift;
        pmask |= 0xFFu << shift;
        __syncthreads();
    }

    if (tid == 0) { cnt2[0] = 0; cnt2[1] = 0; }
    __syncthreads();
    #pragma unroll
    for (int i = 0; i < 8; i++) {
        unsigned int u = my[i];
        int idx = tid + i * 256;
        if (u > prefix) {
            int pos = atomicAdd(&cnt2[0], 1);
            top[bh * U + pos] = idx;
        } else if (u == prefix) {
            int pos = atomicAdd(&cnt2[1], 1);
            ties[pos] = idx;
        }
    }
    __syncthreads();
    int tcnt = cnt2[1];
    #pragma unroll
    for (int i = 0; i < 8; i++) {
        unsigned int u = my[i];
        if (u == prefix) {
            int idx = tid + i * 256;
            int rank = 0;
            for (int j = 0; j < tcnt; j++) rank += (ties[j] < idx) ? 1 : 0;
            if (rank < (int)need) top[bh * U + (int)above + rank] = idx;
        }
    }
}

// ------------- Vmean[b,h,d] (V bf16), 256 threads/block --------------------
__global__ __launch_bounds__(256) void vmean_k(
    const __bf16* __restrict__ V, float* __restrict__ Vm)
{
    __shared__ float osum[4][DKK];
    int bh = blockIdx.x;
    int b = bh >> 3, h = bh & 7;
    int tid = threadIdx.x, d = tid & 63, part = tid >> 6;
    const __bf16* vp = V + ((size_t)(b * LL + part * 512) * DD + h * DKK + d);
    float s = 0.f;
    for (int i = 0; i < 512; i++) s += (float)vp[(size_t)i * DD];
    osum[part][d] = s;
    __syncthreads();
    if (tid < DKK)
        Vm[bh * DKK + tid] = (osum[0][tid] + osum[1][tid] + osum[2][tid] + osum[3][tid]) * (1.0f / (float)LL);
}

// ------------- gather Q[top] -> qred[32][48][64] bf16, scaled by 1/8 -------
__global__ __launch_bounds__(256) void gather_qred(
    const float* __restrict__ Q, const int* __restrict__ top,
    __bf16* __restrict__ qred, int U)
{
    int bh = blockIdx.y;
    int b = bh >> 3, h = bh & 7;
    int e = blockIdx.x * 256 + threadIdx.x;   // 0..48*64-1
    int u = e >> 6, d = e & 63;
    float v = 0.f;
    if (u < U) {
        int l = top[bh * U + u];
        v = Q[((size_t)(b * LL + l) * DD + h * DKK) + d] * 0.125f;
    }
    qred[(size_t)bh * 48 * DKK + e] = (__bf16)v;
}

// ------------- batched S[bh][48][2048] = qred[bh] @ K[bh]^T (MFMA) ---------
// Swapped-operand MFMA -> float4 stores of S.
__global__ __launch_bounds__(256) void gemm_s(
    const __bf16* __restrict__ qred, const float* __restrict__ Kb,
    float* __restrict__ S)
{
    __shared__ __bf16 Qs[2 * 48 * 32];    // 2 panels of BK=32
    __shared__ __bf16 Ks[2 * 128 * 32];
    int bh = blockIdx.y, nc = blockIdx.x;
    int b = bh >> 3, h = bh & 7, l0 = nc * 128;
    int tid = threadIdx.x;
    const unsigned int* qsrc = (const unsigned int*)(qred + (size_t)bh * 48 * DKK);
    unsigned int* qdst = (unsigned int*)Qs;
    #pragma unroll
    for (int t = 0; t < 6; t++) {
        int ui = tid + t * 256;            // 0..1535
        int u = ui >> 5, kp = ui & 31;
        int p = kp >> 4, kl2 = kp & 15;
        qdst[p * 768 + u * 16 + kl2] = qsrc[ui];
    }
    #pragma unroll
    for (int t = 0; t < 8; t++) {
        int fi = tid + t * 256;            // 0..2047
        int row = fi >> 4, k4 = fi & 15;
        int p = k4 >> 3, kl = (k4 & 7) * 4;
        float4 kv = *(const float4*)(Kb + ((size_t)(b * LL + l0 + row) * DD + h * DKK + k4 * 4));
        __bf16* dst = Ks + p * 128 * 32 + row * 32 + kl;
        dst[0] = (__bf16)kv.x; dst[1] = (__bf16)kv.y;
        dst[2] = (__bf16)kv.z; dst[3] = (__bf16)kv.w;
    }
    __syncthreads();
    int wave = tid >> 6, lane = tid & 63, l15 = lane & 15, kq = lane >> 4;
    floatx4 acc[3][2] = {};
    #pragma unroll
    for (int p = 0; p < 2; p++) {
        bf16x8 bq[2];
        #pragma unroll
        for (int j = 0; j < 2; j++)
            bq[j] = *(const bf16x8*)(Ks + p * 4096 + (wave * 32 + j * 16 + l15) * 32 + kq * 8);
        #pragma unroll
        for (int i = 0; i < 3; i++) {
            bf16x8 aq = *(const bf16x8*)(Qs + p * 1536 + (i * 16 + l15) * 32 + kq * 8);
            #pragma unroll
            for (int j = 0; j < 2; j++)
                acc[i][j] = __builtin_amdgcn_mfma_f32_16x16x32_bf16(bq[j], aq, acc[i][j], 0, 0, 0);
        }
    }
    // thread holds S[row][col..col+3]: row = i*16+l15, col = l0+wave*32+j*16+kq*4
    #pragma unroll
    for (int i = 0; i < 3; i++) {
        int row = i * 16 + l15;
        #pragma unroll
        for (int j = 0; j < 2; j++) {
            int col = l0 + wave * 32 + j * 16 + kq * 4;
            *(float4*)&S[((size_t)bh * 48 + row) * LL + col] = *(float4*)&acc[i][j];
        }
    }
}

// ------------- row softmax, in-place: S row fp32 -> P row bf16 -------------
__global__ __launch_bounds__(256) void softmax_p(float* __restrict__ S, int U)
{
    __shared__ float red[256];
    int row = blockIdx.x;              // 32*U rows
    int bh = row / U, u = row % U;
    float* sr = S + ((size_t)bh * 48 + u) * LL;
    int tid = threadIdx.x;
    float sc[8]; float mx = -1e30f;
    #pragma unroll
    for (int i = 0; i < 8; i++) { sc[i] = sr[tid + i * 256]; mx = fmaxf(mx, sc[i]); }
    red[tid] = mx; __syncthreads();
    for (int s = 128; s > 0; s >>= 1) { if (tid < s) red[tid] = fmaxf(red[tid], red[tid + s]); __syncthreads(); }
    mx = red[0]; __syncthreads();
    float se = 0.f;
    #pragma unroll
    for (int i = 0; i < 8; i++) { sc[i] = __expf(sc[i] - mx); se += sc[i]; }
    red[tid] = se; __syncthreads();
    for (int s = 128; s > 0; s >>= 1) { if (tid < s) red[tid] += red[tid + s]; __syncthreads(); }
    float inv = 1.0f / red[0];
    __bf16* pr = (__bf16*)sr;
    #pragma unroll
    for (int i = 0; i < 8; i++) pr[tid + i * 256] = (__bf16)(sc[i] * inv);
}

// ------------- zero upd (pv_k accumulates via atomicAdd) -------------------
__global__ __launch_bounds__(256) void zero_upd(float* __restrict__ upd, int n)
{
    int i = blockIdx.x * 256 + threadIdx.x;
    if (i < n) upd[i] = 0.f;
}

// ------------- upd[bh][u][d] += sum_{l in chunk} P[u][l] * V[b,h,l,d] ------
// L split 4-way (1280 blocks = 5/CU); uint2 V loads; LDS partials + atomicAdd.
__global__ __launch_bounds__(256) void pv_k(
    const float* __restrict__ S, const __bf16* __restrict__ V,
    float* __restrict__ upd, int U)
{
    __shared__ __bf16 pls[4][512];        // 4 KB
    __shared__ float osum[16][4][DKK];    // 16 KB
    int uc = blockIdx.x, lc = blockIdx.y, bh = blockIdx.z;
    int b = bh >> 3, h = bh & 7, tid = threadIdx.x;
    #pragma unroll
    for (int t = 0; t < 4; t++) {
        int ui = tid + t * 256;          // 0..1023
        int up = ui >> 8, lw = ui & 255;
        ((unsigned int*)pls)[up * 256 + lw] =
            ((const unsigned int*)(S + ((size_t)bh * 48 + uc * 4 + up) * LL))[lc * 256 + lw];
    }
    __syncthreads();
    int d4 = tid & 15, part = tid >> 4;   // 16 parts of 32 l; d4 covers 4 d's
    const __bf16* vp = V + ((size_t)(b * LL + lc * 512 + part * 32)) * DD + h * DKK + d4 * 4;
    float a[4][4] = {};
    for (int i = 0; i < 32; i++) {
        union { uint2 u; __bf16 bb[4]; } cv;
        cv.u = *(const uint2*)(vp + (size_t)i * DD);
        float v0 = (float)cv.bb[0], v1 = (float)cv.bb[1];
        float v2 = (float)cv.bb[2], v3 = (float)cv.bb[3];
        int l = part * 32 + i;
        #pragma unroll
        for (int u2 = 0; u2 < 4; u2++) {
            float p = (float)pls[u2][l];
            a[u2][0] += p * v0; a[u2][1] += p * v1;
            a[u2][2] += p * v2; a[u2][3] += p * v3;
        }
    }
    #pragma unroll
    for (int u2 = 0; u2 < 4; u2++)
        #pragma unroll
        for (int j = 0; j < 4; j++)
            osum[part][u2][d4 * 4 + j] = a[u2][j];
    __syncthreads();
    int d = tid & 63, u2 = tid >> 6;
    float s = 0.f;
    #pragma unroll
    for (int p = 0; p < 16; p++) s += osum[p][u2][d];
    atomicAdd(&upd[((size_t)bh * U + uc * 4 + u2) * DKK + d], s);
}

// ------------- base[b][n] = cmean[b] . Wo[:,n]  (fp32, tiny) ---------------
__global__ __launch_bounds__(256) void base_k(
    const float* __restrict__ Vm, const float* __restrict__ Wo,
    float* __restrict__ base)
{
    __shared__ float cm[DD];
    __shared__ float part[8][32];
    int b = blockIdx.y, n0 = blockIdx.x * 32, tid = threadIdx.x;
    cm[tid] = Vm[b * DD + tid];
    cm[tid + 256] = Vm[b * DD + 256 + tid];
    __syncthreads();
    int n = n0 + (tid & 31), kg = tid >> 5;      // 8 k-groups of 64
    float s = 0.f;
    for (int k = kg * 64; k < kg * 64 + 64; k++) s += cm[k] * Wo[(size_t)k * DD + n];
    part[kg][tid & 31] = s;
    __syncthreads();
    if (tid < 32) {
        float t = 0.f;
        #pragma unroll
        for (int g = 0; g < 8; g++) t += part[g][tid];
        base[b * DD + n0 + tid] = t;
    }
}

// ------------- aout init: every row of batch b <- base[b] ------------------
__global__ __launch_bounds__(256) void aout_init(
    const float* __restrict__ base, float* __restrict__ aout)
{
    int idx = blockIdx.x * 256 + threadIdx.x;    // over B*L*512
    aout[idx] = base[((idx >> 20) << 9) + (idx & 511)];
}

// ------------- aw[bh][u48][d] = bf16(upd - Vm) -----------------------------
__global__ __launch_bounds__(256) void aw_prep(
    const float* __restrict__ upd, const float* __restrict__ Vm,
    __bf16* __restrict__ aw, int U)
{
    int bh = blockIdx.x, tid = threadIdx.x;
    #pragma unroll
    for (int t = 0; t < 12; t++) {
        int e = tid + t * 256;                   // 0..3071
        int u = e >> 6, d = e & 63;
        float v = (u < U) ? upd[((size_t)bh * U + u) * DKK + d] - Vm[bh * DKK + d] : 0.f;
        aw[(size_t)bh * 48 * DKK + e] = (__bf16)v;
    }
}

// ------------- corr GEMM + scatter-add: aout[b, top[u]] += aw @ Wo_h -------
__global__ __launch_bounds__(256) void corr_gemm(
    const __bf16* __restrict__ aw, const __bf16* __restrict__ WoT,
    const int* __restrict__ top, float* __restrict__ aout, int U)
{
    __shared__ __bf16 Qs[2 * 48 * 32];    // aw panels (BK=32)
    __shared__ __bf16 Ks[2 * 128 * 32];   // WoT-slice panels
    int bh = blockIdx.y, nc = blockIdx.x;
    int b = bh >> 3, h = bh & 7, n0 = nc * 128;
    int tid = threadIdx.x;
    const unsigned int* qsrc = (const unsigned int*)(aw + (size_t)bh * 48 * DKK);
    unsigned int* qdst = (unsigned int*)Qs;
    #pragma unroll
    for (int t = 0; t < 6; t++) {
        int ui = tid + t * 256;            // 0..1535
        int u = ui >> 5, kp = ui & 31;
        int p = kp >> 4, kl2 = kp & 15;
        qdst[p * 768 + u * 16 + kl2] = qsrc[ui];
    }
    const unsigned int* wsrc = (const unsigned int*)WoT;
    unsigned int* kdst = (unsigned int*)Ks;
    #pragma unroll
    for (int t = 0; t < 16; t++) {
        int ui = tid + t * 256;            // 0..4095
        int row = ui >> 5, c2 = ui & 31;
        int p = c2 >> 4, col2 = c2 & 15;
        kdst[p * 2048 + row * 16 + col2] = wsrc[(size_t)(n0 + row) * (DD / 2) + h * 32 + c2];
    }
    __syncthreads();
    int wave = tid >> 6, lane = tid & 63, l15 = lane & 15, kq = lane >> 4;
    floatx4 acc[3][2] = {};
    #pragma unroll
    for (int p = 0; p < 2; p++) {
        bf16x8 bq[2];
        #pragma unroll
        for (int j = 0; j < 2; j++)
            bq[j] = *(const bf16x8*)(Ks + p * 4096 + (wave * 32 + j * 16 + l15) * 32 + kq * 8);
        #pragma unroll
        for (int i = 0; i < 3; i++) {
            bf16x8 aq = *(const bf16x8*)(Qs + p * 1536 + (i * 16 + l15) * 32 + kq * 8);
            #pragma unroll
            for (int j = 0; j < 2; j++)
                acc[i][j] = __builtin_amdgcn_mfma_f32_16x16x32_bf16(bq[j], aq, acc[i][j], 0, 0, 0);
        }
    }
    #pragma unroll
    for (int i = 0; i < 3; i++) {
        int u = i * 16 + l15;
        if (u < U) {
            int l = top[bh * U + u];
            float* dst = aout + ((size_t)(b * LL + l)) * DD;
            #pragma unroll
            for (int j = 0; j < 2; j++) {
                int n = n0 + wave * 32 + j * 16 + kq * 4;
                atomicAdd(dst + n,     acc[i][j][0]);
                atomicAdd(dst + n + 1, acc[i][j][1]);
                atomicAdd(dst + n + 2, acc[i][j][2]);
                atomicAdd(dst + n + 3, acc[i][j][3]);
            }
        }
    }
}

// ------------- LN1: x1 = LN(x + aout) -> bf16 ------------------------------
__global__ __launch_bounds__(256) void ln1_k(
    const float* __restrict__ x, const float* __restrict__ aout,
    const float* __restrict__ g, const float* __restrict__ bb,
    __bf16* __restrict__ x1h)
{
    __shared__ float red[256];
    int row = blockIdx.x, tid = threadIdx.x;
    size_t base = (size_t)row * DD;
    float h0 = x[base + tid] + aout[base + tid];
    float h1 = x[base + 256 + tid] + aout[base + 256 + tid];
    red[tid] = h0 + h1; __syncthreads();
    for (int s = 128; s > 0; s >>= 1) { if (tid < s) red[tid] += red[tid + s]; __syncthreads(); }
    float mean = red[0] * (1.0f / DD); __syncthreads();
    float d0 = h0 - mean, d1 = h1 - mean;
    red[tid] = d0 * d0 + d1 * d1; __syncthreads();
    for (int s = 128; s > 0; s >>= 1) { if (tid < s) red[tid] += red[tid + s]; __syncthreads(); }
    float rstd = rsqrtf(red[0] * (1.0f / DD) + 1e-5f);
    x1h[base + tid]       = (__bf16)(d0 * rstd * g[tid] + bb[tid]);
    x1h[base + 256 + tid] = (__bf16)(d1 * rstd * g[256 + tid] + bb[256 + tid]);
}

// ------------- LN2: out = LN(x1 + ffn2 + b2) -> fp32 -----------------------
__global__ __launch_bounds__(256) void ln2_k(
    const __bf16* __restrict__ x1h, const float* __restrict__ f2o,
    const float* __restrict__ c2b,
    const float* __restrict__ g, const float* __restrict__ bb,
    float* __restrict__ out)
{
    __shared__ float red[256];
    int row = blockIdx.x, tid = threadIdx.x;
    size_t base = (size_t)row * DD;
    float h0 = (float)x1h[base + tid] + f2o[base + tid] + c2b[tid];
    float h1 = (float)x1h[base + 256 + tid] + f2o[base + 256 + tid] + c2b[256 + tid];
    red[tid] = h0 + h1; __syncthreads();
    for (int s = 128; s > 0; s >>= 1) { if (tid < s) red[tid] += red[tid + s]; __syncthreads(); }
    float mean = red[0] * (1.0f / DD); __syncthreads();
    float d0 = h0 - mean, d1 = h1 - mean;
    red[tid] = d0 * d0 + d1 * d1; __syncthreads();
    for (int s = 128; s > 0; s >>= 1) { if (tid < s) red[tid] += red[tid + s]; __syncthreads(); }
    float rstd = rsqrtf(red[0] * (1.0f / DD) + 1e-5f);
    out[base + tid]       = d0 * rstd * g[tid] + bb[tid];
    out[base + 256 + tid] = d1 * rstd * g[256 + tid] + bb[256 + tid];
}

// ---------------------------------------------------------------------------
extern "C" void kernel_launch(void* const* d_in, const int* in_sizes, int n_in,
                              void* d_out, int out_size, void* d_ws, size_t ws_size,
                              hipStream_t stream)
{
    const float* x   = (const float*)d_in[0];
    const float* Wq  = (const float*)d_in[1];
    const float* Wk  = (const float*)d_in[2];
    const float* Wv  = (const float*)d_in[3];
    const float* Wo  = (const float*)d_in[4];
    const float* g1  = (const float*)d_in[5];
    const float* b1  = (const float*)d_in[6];
    const float* c1w = (const float*)d_in[7];
    const float* c1b = (const float*)d_in[8];
    const float* c2w = (const float*)d_in[9];
    const float* c2b = (const float*)d_in[10];
    const float* g2  = (const float*)d_in[11];
    const float* b2  = (const float*)d_in[12];
    const int* sidx  = (const int*)d_in[13];
    float* out       = (float*)d_out;

    const int U = in_sizes[13] / LL;            // 40
    const int M = BB * LL;                       // 8192

    char* ws = (char*)d_ws;
    const size_t MB = (size_t)1 << 20;
    float*  Q    = (float*)(ws + 0);
    float*  Kb   = (float*)(ws + 16 * MB);
    __bf16* V    = (__bf16*)(ws + 32 * MB);
    __bf16* xhi  = (__bf16*)(ws + 40 * MB);
    __bf16* xlo  = (__bf16*)(ws + 48 * MB);
    float*  S    = (float*)(ws + 40 * MB);          // 32*48*2048*4 = 12.6 MB
    __bf16* wb   = (__bf16*)(ws + 56 * MB);
    __bf16* c1wb = (__bf16*)(ws + 59 * MB);
    __bf16* c2wb = (__bf16*)(ws + 61 * MB);
    float*  Mo   = (float*)(ws + 63 * MB);
    float*  upd  = (float*)(ws + 63 * MB + 256 * 1024);
    float*  Vm   = (float*)(ws + 63 * MB + 576 * 1024);
    int*    top  = (int*)  (ws + 63 * MB + 584 * 1024);
    __bf16* qred = (__bf16*)(ws + 63 * MB + 592 * 1024);  // 192K
    __bf16* aw   = (__bf16*)(ws + 63 * MB + 784 * 1024);  // 192K
    float*  basep= (float*)(ws + 63 * MB + 976 * 1024);   // 8K
    float*  aout = Q;                               // alias: Q dead after gather_qred
    float*  f2o  = Q;                               // alias: aout dead after ln1
    __bf16* ych  = (__bf16*)(ws + 16 * MB);         // FFN intermediate (32 MB region)
    __bf16* x1h  = xlo;                             // alias: S/P dead by ln1
    (void)ws_size; (void)n_in; (void)out_size;

    const size_t SZ = (size_t)DD * DD;
    __bf16* WqThi = wb;          __bf16* WqTlo = wb + SZ;
    __bf16* WkThi = wb + 2 * SZ; __bf16* WkTlo = wb + 3 * SZ;
    __bf16* WvT   = wb + 4 * SZ; __bf16* WoT   = wb + 5 * SZ;

    // 1) weight prep + input split-cast
    prep_w<<<dim3(DD * DD / 256, 1, 4), 256, 0, stream>>>(Wq, Wk, Wv, Wo, wb);
    cast_cw<<<dim3(FF * DD / 256, 1, 2), 256, 0, stream>>>(c1w, c2w, c1wb, c2wb);
    split_cast_x<<<BB * LL * DD / 256, 256, 0, stream>>>(x, xhi, xlo);

    // 2) Q,K via split-precision MFMA (BM=64: 512 blocks = 2/CU);
    //    V bf16 (BM=64, NB=3 -> 36 KB LDS -> 4 blocks/CU)
    dim3 gproj64(DD / 128, M / 64);
    gemm_mfma_split64<<<gproj64, 256, 0, stream>>>(xhi, xlo, WqThi, WqTlo, Q,  M, DD, DD);
    gemm_mfma_split64<<<gproj64, 256, 0, stream>>>(xhi, xlo, WkThi, WkTlo, Kb, M, DD, DD);
    gemm_mfma64<3, 0, false, true ><<<gproj64, 256, 0, stream>>>(xhi, WvT, nullptr, V, M, DD, DD);

    // 3) sampled sparsity measure M, top-k, V mean (+ zero upd for pv atomics)
    calc_m<<<BB * LL, 256, 0, stream>>>(Q, Kb, sidx, Mo, U);
    zero_upd<<<(BB * HH * U * DKK + 255) / 256, 256, 0, stream>>>(upd, BB * HH * U * DKK);
    topk_k<<<BB * HH, 256, 0, stream>>>(Mo, top, U);
    vmean_k<<<BB * HH, 256, 0, stream>>>(V, Vm);

    // 4) attention: gather -> batched MFMA S -> softmax(in-place bf16 P) -> PV
    gather_qred<<<dim3(48 * DKK / 256, BB * HH), 256, 0, stream>>>(Q, top, qred, U);
    gemm_s<<<dim3(LL / 128, BB * HH), 256, 0, stream>>>(qred, Kb, S);
    softmax_p<<<BB * HH * U, 256, 0, stream>>>(S, U);
    pv_k<<<dim3(U / 4, 4, BB * HH), 256, 0, stream>>>(S, V, upd, U);

    // 5) out-projection via base + rank-U correction (Wo-GEMM eliminated)
    base_k<<<dim3(16, BB), 256, 0, stream>>>(Vm, Wo, basep);
    aw_prep<<<BB * HH, 256, 0, stream>>>(upd, Vm, aw, U);
    aout_init<<<M * DD / 256, 256, 0, stream>>>(basep, aout);
    corr_gemm<<<dim3(DD / 128, BB * HH), 256, 0, stream>>>(aw, WoT, top, aout, U);

    // 6) LN1 -> x1h bf16 (aliases xlo; S/P dead)
    ln1_k<<<M, 256, 0, stream>>>(x, aout, g1, b1, x1h);

    // 7) FFN: gelu(x1 @ c1w^T + c1b) -> ych bf16 (BM=128, 1024 blocks = 4/CU);
    //    ych @ c2w^T -> f2o (BM=64, NB=3: 512 blocks = 4 blocks/CU)
    gemm_mfma<3, 1, true,  true ><<<dim3(FF / 128, M / 128), 256, 0, stream>>>(x1h, c1wb, c1b, ych, M, FF, DD);
    gemm_mfma64<3, 0, false, false><<<dim3(DD / 128, M / 64), 256, 0, stream>>>(ych, c2wb, nullptr, f2o, M, DD, FF);

    // 8) LN2 -> fp32 output
    ln2_k<<<M, 256, 0, stream>>>(x1h, f2o, c2b, g2, b2, out);
}

// Round 13
// 384.643 us; speedup vs baseline: 1.1169x; 1.0099x over previous
//
#include <hip/hip_runtime.h>
#include <hip/hip_bf16.h>

// Problem constants (B=4, L=2048, D=512, H=8, DK=64, FF=2048, U=40)
#define BB 4
#define LL 2048
#define DD 512
#define HH 8
#define DKK 64
#define FF 2048

typedef __bf16  bf16x8  __attribute__((ext_vector_type(8)));
typedef float   floatx4 __attribute__((ext_vector_type(4)));

// async 16B global->LDS copy (global_load_lds_dwordx4)
__device__ __forceinline__ void async_cp16(const void* g, void* l) {
    __builtin_amdgcn_global_load_lds(
        (const __attribute__((address_space(1))) unsigned int*)g,
        (__attribute__((address_space(3))) unsigned int*)l,
        16, 0, 0);
}

// exact-grade GELU: A&S 7.1.26 erf, |err| < 1.5e-7 (fp32-exact at our scale).
__device__ __forceinline__ float gelu_f(float v) {
    float z  = v * 0.70710678118654752f;
    float az = fabsf(z);
    float t  = __builtin_amdgcn_rcpf(1.0f + 0.3275911f * az);
    float p  = ((((1.061405429f * t - 1.453152027f) * t + 1.421413741f) * t
                 - 0.284496736f) * t + 0.254829592f) * t;
    float e  = __expf(-z * z);
    float er = 1.0f - p * e;
    er = (z < 0.0f) ? -er : er;
    return 0.5f * v * (1.0f + er);
}

// ---------- prep: transpose 512x512 fp32 -> bf16 (N,K); Wq/Wk also lo-part ----
__global__ __launch_bounds__(256) void prep_w(
    const float* __restrict__ Wq, const float* __restrict__ Wk,
    const float* __restrict__ Wv, const float* __restrict__ Wo,
    __bf16* __restrict__ wb)
{
    const size_t SZ = (size_t)DD * DD;
    int z = blockIdx.z;
    const float* s = (z == 0) ? Wq : (z == 1) ? Wk : (z == 2) ? Wv : Wo;
    __bf16* hi; __bf16* lo = nullptr;
    if (z == 0)      { hi = wb;          lo = wb + SZ; }
    else if (z == 1) { hi = wb + 2 * SZ; lo = wb + 3 * SZ; }
    else if (z == 2) { hi = wb + 4 * SZ; }
    else             { hi = wb + 5 * SZ; }
    int idx = blockIdx.x * 256 + threadIdx.x;   // 0..512*512-1
    int k = idx >> 9, n = idx & 511;
    float v = s[idx];
    __bf16 h = (__bf16)v;
    hi[(size_t)n * DD + k] = h;
    if (lo) lo[(size_t)n * DD + k] = (__bf16)(v - (float)h);
}

// ---------- cast conv weights fp32 (N,K) -> bf16 -----------------------------
__global__ __launch_bounds__(256) void cast_cw(
    const float* __restrict__ c1w, const float* __restrict__ c2w,
    __bf16* __restrict__ d1, __bf16* __restrict__ d2)
{
    const float* s = blockIdx.z ? c2w : c1w;
    __bf16* d = blockIdx.z ? d2 : d1;
    int idx = blockIdx.x * 256 + threadIdx.x;   // 0..FF*DD-1
    d[idx] = (__bf16)s[idx];
}

// ---------- split-cast x fp32 -> bf16 hi + lo --------------------------------
__global__ __launch_bounds__(256) void split_cast_x(
    const float* __restrict__ x, __bf16* __restrict__ xhi, __bf16* __restrict__ xlo)
{
    int idx = blockIdx.x * 256 + threadIdx.x;
    float v = x[idx];
    __bf16 h = (__bf16)v;
    xhi[idx] = h;
    xlo[idx] = (__bf16)(v - (float)h);
}

// ---------- MFMA GEMM, 128x128 tile (FFN1: 1024 blocks = 4/CU) ---------------
// NB-buffer pipeline, single barrier + counted vmcnt per k-step; bank swizzle
// (r8: conflicts -> 0); XCD swizzle; swapped-operand vector epilogue.
template<int NB, int ACT, bool BIAS, bool OUT_BF16>
__global__ __launch_bounds__(256) void gemm_mfma(
    const __bf16* __restrict__ A, const __bf16* __restrict__ B,
    const float* __restrict__ bias, void* __restrict__ Cv,
    int M, int N, int K)
{
    __shared__ __bf16 As[NB][128 * 32];
    __shared__ __bf16 Bs[NB][128 * 32];
    const int tid = threadIdx.x;
    const int wave = tid >> 6, lane = tid & 63;
    const int gx = gridDim.x;
    const int nwg = gx * gridDim.y;
    const int hw = blockIdx.y * gx + blockIdx.x;
    const int virt = ((nwg & 7) == 0) ? ((hw & 7) * (nwg >> 3) + (hw >> 3)) : hw;
    const int m0 = (virt / gx) * 128, n0 = (virt % gx) * 128;
    const int wm = (wave >> 1) * 64, wn = (wave & 1) * 64;
    const int l15 = lane & 15, kq = lane >> 4;

    auto stage = [&](int buf, int k0) {           // 4 vmem insts per thread
        #pragma unroll
        for (int p = 0; p < 2; p++) {
            int c = p * 256 + tid;                // 16B chunk id 0..511
            int row = c >> 2;
            int col = ((c & 3) ^ ((row >> 1) & 3)) * 8;   // inverse-swizzled src
            async_cp16(A + (size_t)(m0 + row) * K + k0 + col, &As[buf][c * 8]);
            async_cp16(B + (size_t)(n0 + row) * K + k0 + col, &Bs[buf][c * 8]);
        }
    };

    floatx4 acc[4][4] = {};

    const int nt = K >> 5;
    #pragma unroll
    for (int pt = 0; pt < NB - 1; pt++) stage(pt, pt << 5);
    if constexpr (NB == 6) asm volatile("s_waitcnt vmcnt(16)" ::: "memory");
    else                   asm volatile("s_waitcnt vmcnt(4)"  ::: "memory");
    __builtin_amdgcn_s_barrier();
    int bi = 0;                                   // buffer of current tile
    for (int t = 0; t < nt; t++) {
        if (t + NB - 1 < nt) {
            int b2 = bi + NB - 1; if (b2 >= NB) b2 -= NB;
            stage(b2, (t + NB - 1) << 5);
        }
        asm volatile("" ::: "memory");
        bf16x8 af[4], bfr[4];
        #pragma unroll
        for (int i = 0; i < 4; i++) {
            int ra = wm + i * 16 + l15;
            af[i] = *(const bf16x8*)(&As[bi][ra * 32 + ((kq ^ ((ra >> 1) & 3)) << 3)]);
        }
        #pragma unroll
        for (int j = 0; j < 4; j++) {
            int rb = wn + j * 16 + l15;
            bfr[j] = *(const bf16x8*)(&Bs[bi][rb * 32 + ((kq ^ ((rb >> 1) & 3)) << 3)]);
        }
        #pragma unroll
        for (int i = 0; i < 4; i++)
            #pragma unroll
            for (int j = 0; j < 4; j++)
                acc[i][j] = __builtin_amdgcn_mfma_f32_16x16x32_bf16(bfr[j], af[i], acc[i][j], 0, 0, 0);
        asm volatile("" ::: "memory");
        if (t + 1 < nt) {                         // wait: tile t+1 landed
            int c = nt - 2 - t; if (c > NB - 2) c = NB - 2;
            if (c >= 4)      asm volatile("s_waitcnt vmcnt(16)" ::: "memory");
            else if (c == 3) asm volatile("s_waitcnt vmcnt(12)" ::: "memory");
            else if (c == 2) asm volatile("s_waitcnt vmcnt(8)"  ::: "memory");
            else if (c == 1) asm volatile("s_waitcnt vmcnt(4)"  ::: "memory");
            else             asm volatile("s_waitcnt vmcnt(0)"  ::: "memory");
            __builtin_amdgcn_s_barrier();
        }
        if (++bi == NB) bi = 0;
    }
    #pragma unroll
    for (int i = 0; i < 4; i++) {
        int m = m0 + wm + i * 16 + l15;
        #pragma unroll
        for (int j = 0; j < 4; j++) {
            int n = n0 + wn + j * 16 + kq * 4;
            floatx4 v4 = acc[i][j];
            if (BIAS) {
                float4 bv = *(const float4*)&bias[n];
                v4[0] += bv.x; v4[1] += bv.y; v4[2] += bv.z; v4[3] += bv.w;
            }
            if (ACT == 1) {
                v4[0] = gelu_f(v4[0]); v4[1] = gelu_f(v4[1]);
                v4[2] = gelu_f(v4[2]); v4[3] = gelu_f(v4[3]);
            }
            if (OUT_BF16) {
                union { __bf16 b[4]; uint2 u; } pk;
                pk.b[0] = (__bf16)v4[0]; pk.b[1] = (__bf16)v4[1];
                pk.b[2] = (__bf16)v4[2]; pk.b[3] = (__bf16)v4[3];
                *(uint2*)((__bf16*)Cv + (size_t)m * N + n) = pk.u;
            } else {
                *(float4*)((float*)Cv + (size_t)m * N + n) = *(float4*)&v4;
            }
        }
    }
}

// ---------- MFMA GEMM, 64x64 tile for grid-limited N=512 GEMMs ---------------
// r10-r12 A/B chain: the ONLY lever at these shapes is resident waves/SIMD,
// and the grid caps blocks/CU (512 blocks = 2/CU regardless of LDS). 64x64
// tile -> grid (N/64)x(M/64) = 8x128 = 1024 blocks = 4 blocks/CU = 4 waves/
// SIMD. 4 waves x 32x32 wave-tiles, acc[2][2], 2 staging loads/thread
// (uniform vmcnt), NB=4 -> 32 KB LDS (5 fit; grid gives 4).
template<int NB, int ACT, bool BIAS, bool OUT_BF16>
__global__ __launch_bounds__(256) void gemm_sq64(
    const __bf16* __restrict__ A, const __bf16* __restrict__ B,
    const float* __restrict__ bias, void* __restrict__ Cv,
    int M, int N, int K)
{
    __shared__ __bf16 As[NB][64 * 32];
    __shared__ __bf16 Bs[NB][64 * 32];
    const int tid = threadIdx.x;
    const int wave = tid >> 6, lane = tid & 63;
    const int gx = gridDim.x;
    const int nwg = gx * gridDim.y;
    const int hw = blockIdx.y * gx + blockIdx.x;
    const int virt = ((nwg & 7) == 0) ? ((hw & 7) * (nwg >> 3) + (hw >> 3)) : hw;
    const int m0 = (virt / gx) * 64, n0 = (virt % gx) * 64;
    const int wm = (wave >> 1) * 32, wn = (wave & 1) * 32;
    const int l15 = lane & 15, kq = lane >> 4;

    auto stage = [&](int buf, int k0) {           // 2 vmem insts per thread
        int c = tid;                              // 256 chunks = 64 rows x 4
        int row = c >> 2;
        int col = ((c & 3) ^ ((row >> 1) & 3)) * 8;
        async_cp16(A + (size_t)(m0 + row) * K + k0 + col, &As[buf][c * 8]);
        async_cp16(B + (size_t)(n0 + row) * K + k0 + col, &Bs[buf][c * 8]);
    };

    floatx4 acc[2][2] = {};

    const int nt = K >> 5;
    #pragma unroll
    for (int pt = 0; pt < NB - 1; pt++) stage(pt, pt << 5);
    asm volatile("s_waitcnt vmcnt(%0)" :: "i"(2 * (NB - 2)) : "memory");
    __builtin_amdgcn_s_barrier();
    int bi = 0;
    for (int t = 0; t < nt; t++) {
        if (t + NB - 1 < nt) {
            int b2 = bi + NB - 1; if (b2 >= NB) b2 -= NB;
            stage(b2, (t + NB - 1) << 5);
        }
        asm volatile("" ::: "memory");
        bf16x8 af[2], bfr[2];
        #pragma unroll
        for (int i = 0; i < 2; i++) {
            int ra = wm + i * 16 + l15;
            af[i] = *(const bf16x8*)(&As[bi][ra * 32 + ((kq ^ ((ra >> 1) & 3)) << 3)]);
        }
        #pragma unroll
        for (int j = 0; j < 2; j++) {
            int rb = wn + j * 16 + l15;
            bfr[j] = *(const bf16x8*)(&Bs[bi][rb * 32 + ((kq ^ ((rb >> 1) & 3)) << 3)]);
        }
        #pragma unroll
        for (int i = 0; i < 2; i++)
            #pragma unroll
            for (int j = 0; j < 2; j++)
                acc[i][j] = __builtin_amdgcn_mfma_f32_16x16x32_bf16(bfr[j], af[i], acc[i][j], 0, 0, 0);
        asm volatile("" ::: "memory");
        if (t + 1 < nt) {
            int c = nt - 2 - t; if (c > NB - 2) c = NB - 2;
            if (c >= 3)      asm volatile("s_waitcnt vmcnt(6)" ::: "memory");
            else if (c == 2) asm volatile("s_waitcnt vmcnt(4)" ::: "memory");
            else if (c == 1) asm volatile("s_waitcnt vmcnt(2)" ::: "memory");
            else             asm volatile("s_waitcnt vmcnt(0)" ::: "memory");
            __builtin_amdgcn_s_barrier();
        }
        if (++bi == NB) bi = 0;
    }
    #pragma unroll
    for (int i = 0; i < 2; i++) {
        int m = m0 + wm + i * 16 + l15;
        #pragma unroll
        for (int j = 0; j < 2; j++) {
            int n = n0 + wn + j * 16 + kq * 4;
            floatx4 v4 = acc[i][j];
            if (BIAS) {
                float4 bv = *(const float4*)&bias[n];
                v4[0] += bv.x; v4[1] += bv.y; v4[2] += bv.z; v4[3] += bv.w;
            }
            if (ACT == 1) {
                v4[0] = gelu_f(v4[0]); v4[1] = gelu_f(v4[1]);
                v4[2] = gelu_f(v4[2]); v4[3] = gelu_f(v4[3]);
            }
            if (OUT_BF16) {
                union { __bf16 b[4]; uint2 u; } pk;
                pk.b[0] = (__bf16)v4[0]; pk.b[1] = (__bf16)v4[1];
                pk.b[2] = (__bf16)v4[2]; pk.b[3] = (__bf16)v4[3];
                *(uint2*)((__bf16*)Cv + (size_t)m * N + n) = pk.u;
            } else {
                *(float4*)((float*)Cv + (size_t)m * N + n) = *(float4*)&v4;
            }
        }
    }
}

// ---------- split-precision MFMA GEMM, 64x128 tile (Q/K projections) ---------
// C = (Ah+Al)(Bh+Bl)^T. Grid 512 = 2 blocks/CU. NB=3, 72 KB LDS.
__global__ __launch_bounds__(256) void gemm_mfma_split64(
    const __bf16* __restrict__ Ah, const __bf16* __restrict__ Al,
    const __bf16* __restrict__ Bh, const __bf16* __restrict__ Bl,
    float* __restrict__ C, int M, int N, int K)
{
    __shared__ __bf16 Ahs[3][64 * 32];
    __shared__ __bf16 Als[3][64 * 32];
    __shared__ __bf16 Bhs[3][128 * 32];
    __shared__ __bf16 Bls[3][128 * 32];
    const int tid = threadIdx.x;
    const int wave = tid >> 6, lane = tid & 63;
    const int gx = gridDim.x;
    const int nwg = gx * gridDim.y;
    const int hw = blockIdx.y * gx + blockIdx.x;
    const int virt = ((nwg & 7) == 0) ? ((hw & 7) * (nwg >> 3) + (hw >> 3)) : hw;
    const int m0 = (virt / gx) * 64, n0 = (virt % gx) * 128;
    const int wm = (wave >> 1) * 32, wn = (wave & 1) * 64;
    const int l15 = lane & 15, kq = lane >> 4;

    auto stage = [&](int buf, int k0) {           // 6 vmem insts per thread
        {
            int c = tid;
            int row = c >> 2;
            int col = ((c & 3) ^ ((row >> 1) & 3)) * 8;
            size_t go = (size_t)(m0 + row) * K + k0 + col;
            async_cp16(Ah + go, &Ahs[buf][c * 8]);
            async_cp16(Al + go, &Als[buf][c * 8]);
        }
        #pragma unroll
        for (int p = 0; p < 2; p++) {
            int c = p * 256 + tid;
            int row = c >> 2;
            int col = ((c & 3) ^ ((row >> 1) & 3)) * 8;
            size_t go = (size_t)(n0 + row) * K + k0 + col;
            async_cp16(Bh + go, &Bhs[buf][c * 8]);
            async_cp16(Bl + go, &Bls[buf][c * 8]);
        }
    };

    floatx4 acc[2][4] = {};

    const int nt = K >> 5;
    stage(0, 0); stage(1, 32);
    asm volatile("s_waitcnt vmcnt(6)" ::: "memory");
    __builtin_amdgcn_s_barrier();
    int bi = 0;
    for (int t = 0; t < nt; t++) {
        if (t + 2 < nt) {
            int b2 = bi + 2; if (b2 >= 3) b2 -= 3;
            stage(b2, (t + 2) << 5);
        }
        asm volatile("" ::: "memory");
        bf16x8 ah[2], al[2], bh[4], bl[4];
        #pragma unroll
        for (int i = 0; i < 2; i++) {
            int ra = wm + i * 16 + l15;
            int off = ra * 32 + ((kq ^ ((ra >> 1) & 3)) << 3);
            ah[i] = *(const bf16x8*)(&Ahs[bi][off]);
            al[i] = *(const bf16x8*)(&Als[bi][off]);
        }
        #pragma unroll
        for (int j = 0; j < 4; j++) {
            int rb = wn + j * 16 + l15;
            int off = rb * 32 + ((kq ^ ((rb >> 1) & 3)) << 3);
            bh[j] = *(const bf16x8*)(&Bhs[bi][off]);
            bl[j] = *(const bf16x8*)(&Bls[bi][off]);
        }
        #pragma unroll
        for (int i = 0; i < 2; i++)
            #pragma unroll
            for (int j = 0; j < 4; j++) {
                acc[i][j] = __builtin_amdgcn_mfma_f32_16x16x32_bf16(bh[j], ah[i], acc[i][j], 0, 0, 0);
                acc[i][j] = __builtin_amdgcn_mfma_f32_16x16x32_bf16(bl[j], ah[i], acc[i][j], 0, 0, 0);
                acc[i][j] = __builtin_amdgcn_mfma_f32_16x16x32_bf16(bh[j], al[i], acc[i][j], 0, 0, 0);
            }
        asm volatile("" ::: "memory");
        if (t + 1 < nt) {
            if (t + 2 < nt) asm volatile("s_waitcnt vmcnt(6)" ::: "memory");
            else            asm volatile("s_waitcnt vmcnt(0)" ::: "memory");
            __builtin_amdgcn_s_barrier();
        }
        if (++bi == 3) bi = 0;
    }
    #pragma unroll
    for (int i = 0; i < 2; i++) {
        int m = m0 + wm + i * 16 + l15;
        #pragma unroll
        for (int j = 0; j < 4; j++) {
            int n = n0 + wn + j * 16 + kq * 4;
            *(float4*)(C + (size_t)m * N + n) = *(float4*)&acc[i][j];
        }
    }
}

// ------------- M[b,h,l] = max_s(q·k_s) - sum_s(q·k_s)/L  (sampled) ---------
// 16-lane sum via DPP-fused v_add_f32 (pure VALU; no LDS-pipe ds_swizzle).
__device__ __forceinline__ float dpp_sum16(float p) {
    int t;
    t = __builtin_amdgcn_update_dpp(0, __float_as_int(p), 0xB1,  0xF, 0xF, true); // quad_perm [1,0,3,2]
    p += __int_as_float(t);
    t = __builtin_amdgcn_update_dpp(0, __float_as_int(p), 0x4E,  0xF, 0xF, true); // quad_perm [2,3,0,1]
    p += __int_as_float(t);
    t = __builtin_amdgcn_update_dpp(0, __float_as_int(p), 0x141, 0xF, 0xF, true); // row_half_mirror
    p += __int_as_float(t);
    t = __builtin_amdgcn_update_dpp(0, __float_as_int(p), 0x140, 0xF, 0xF, true); // row_mirror
    p += __int_as_float(t);
    return p;
}

__global__ __launch_bounds__(256) void calc_m(
    const float* __restrict__ Q, const float* __restrict__ Kb,
    const int* __restrict__ sidx, float* __restrict__ Mo, int U)
{
    __shared__ int   js[64];
    __shared__ float red_mx[2][HH];
    __shared__ float red_sm[2][HH];
    int i = blockIdx.x;
    int b = i & 3, l = i >> 2;
    int tid = threadIdx.x;
    if (tid < U) js[tid] = sidx[l * U + tid];
    int e    = (tid & 127) * 4;          // element index within 512-wide row
    int slot = tid >> 7;                 // 0/1: even/odd samples
    const float* qr = Q + ((size_t)(b * LL + l) * DD);
    float4 q = *(const float4*)(qr + e);
    const float* kbase = Kb + ((size_t)b * LL) * DD + e;
    __syncthreads();
    float mx = -1e30f, sm = 0.f;
    for (int s = slot; s < U; s += 2) {
        int j = js[s];
        float4 kv = *(const float4*)(kbase + (size_t)j * DD);
        float p = q.x * kv.x + q.y * kv.y + q.z * kv.z + q.w * kv.w;
        p = dpp_sum16(p);
        mx = fmaxf(mx, p);
        sm += p;
    }
    if ((tid & 15) == 0) {
        int head = (tid >> 4) & 7;
        red_mx[slot][head] = mx;
        red_sm[slot][head] = sm;
    }
    __syncthreads();
    if (tid < HH) {
        float m2 = fmaxf(red_mx[0][tid], red_mx[1][tid]);
        float s2 = red_sm[0][tid] + red_sm[1][tid];
        Mo[((size_t)(b * HH + tid)) * LL + l] = m2 - s2 * (1.0f / (float)LL);
    }
}

// ------------- radix-select top-40 per (b,h) row of M ----------------------
__global__ __launch_bounds__(256) void topk_k(
    const float* __restrict__ Mo, int* __restrict__ top, int U)
{
    __shared__ unsigned int hist[256];
    __shared__ unsigned int wsum[4];
    __shared__ unsigned int bc[2];
    __shared__ int ties[LL];
    __shared__ int cnt2[2];
    int bh = blockIdx.x, tid = threadIdx.x;
    int lane = tid & 63, w = tid >> 6;

    unsigned int my[8];
    #pragma unroll
    for (int i = 0; i < 8; i++) {
        unsigned int u = __float_as_uint(Mo[(size_t)bh * LL + tid + i * 256]);
        my[i] = u ^ ((u >> 31) ? 0xFFFFFFFFu : 0x80000000u);  // order-preserving
    }

    unsigned int prefix = 0, pmask = 0;
    unsigned int need = (unsigned int)U;
    unsigned int above = 0;

    for (int pass = 0; pass < 4; pass++) {
        int shift = 24 - pass * 8;
        hist[tid] = 0;
        __syncthreads();
        #pragma unroll
        for (int i = 0; i < 8; i++) {
            unsigned int u = my[i];
            if ((u & pmask) == prefix)
                atomicAdd(&hist[(u >> shift) & 255u], 1u);
        }
        __syncthreads();
        unsigned int h = hist[tid];
        #pragma unroll
        for (int off = 1; off < 64; off <<= 1) {
            unsigned int o = __shfl_down(h, off);
            if (lane + off < 64) h += o;
        }
        if (lane == 0) wsum[w] = h;
        __syncthreads();
        unsigned int tail = 0;
        #pragma unroll
        for (int w2 = 1; w2 < 4; w2++) if (w2 > w) tail += wsum[w2];
        h += tail;
        hist[tid] = h;
        __syncthreads();
        unsigned int St = h;
        unsigned int St1 = (tid < 255) ? hist[tid + 1] : 0u;
        if (St >= need && St1 < need) { bc[0] = (unsigned int)tid; bc[1] = St1; }
        __syncthreads();
        unsigned int dig = bc[0], abv = bc[1];
        above += abv;
        need -= abv;
        prefix |= dig << shift;
        pmask |= 0xFFu << shift;
        __syncthreads();
    }

    if (tid == 0) { cnt2[0] = 0; cnt2[1] = 0; }
    __syncthreads();
    #pragma unroll
    for (int i = 0; i < 8; i++) {
        unsigned int u = my[i];
        int idx = tid + i * 256;
        if (u > prefix) {
            int pos = atomicAdd(&cnt2[0], 1);
            top[bh * U + pos] = idx;
        } else if (u == prefix) {
            int pos = atomicAdd(&cnt2[1], 1);
            ties[pos] = idx;
        }
    }
    __syncthreads();
    int tcnt = cnt2[1];
    #pragma unroll
    for (int i = 0; i < 8; i++) {
        unsigned int u = my[i];
        if (u == prefix) {
            int idx = tid + i * 256;
            int rank = 0;
            for (int j = 0; j < tcnt; j++) rank += (ties[j] < idx) ? 1 : 0;
            if (rank < (int)need) top[bh * U + (int)above + rank] = idx;
        }
    }
}

// ------------- Vmean[b,h,d] (V bf16), 256 threads/block --------------------
__global__ __launch_bounds__(256) void vmean_k(
    const __bf16* __restrict__ V, float* __restrict__ Vm)
{
    __shared__ float osum[4][DKK];
    int bh = blockIdx.x;
    int b = bh >> 3, h = bh & 7;
    int tid = threadIdx.x, d = tid & 63, part = tid >> 6;
    const __bf16* vp = V + ((size_t)(b * LL + part * 512) * DD + h * DKK + d);
    float s = 0.f;
    for (int i = 0; i < 512; i++) s += (float)vp[(size_t)i * DD];
    osum[part][d] = s;
    __syncthreads();
    if (tid < DKK)
        Vm[bh * DKK + tid] = (osum[0][tid] + osum[1][tid] + osum[2][tid] + osum[3][tid]) * (1.0f / (float)LL);
}

// ------------- gather Q[top] -> qred[32][48][64] bf16, scaled by 1/8 -------
__global__ __launch_bounds__(256) void gather_qred(
    const float* __restrict__ Q, const int* __restrict__ top,
    __bf16* __restrict__ qred, int U)
{
    int bh = blockIdx.y;
    int b = bh >> 3, h = bh & 7;
    int e = blockIdx.x * 256 + threadIdx.x;   // 0..48*64-1
    int u = e >> 6, d = e & 63;
    float v = 0.f;
    if (u < U) {
        int l = top[bh * U + u];
        v = Q[((size_t)(b * LL + l) * DD + h * DKK) + d] * 0.125f;
    }
    qred[(size_t)bh * 48 * DKK + e] = (__bf16)v;
}

// ------------- batched S[bh][48][2048] = qred[bh] @ K[bh]^T (MFMA) ---------
// Swapped-operand MFMA -> float4 stores of S.
__global__ __launch_bounds__(256) void gemm_s(
    const __bf16* __restrict__ qred, const float* __restrict__ Kb,
    float* __restrict__ S)
{
    __shared__ __bf16 Qs[2 * 48 * 32];    // 2 panels of BK=32
    __shared__ __bf16 Ks[2 * 128 * 32];
    int bh = blockIdx.y, nc = blockIdx.x;
    int b = bh >> 3, h = bh & 7, l0 = nc * 128;
    int tid = threadIdx.x;
    const unsigned int* qsrc = (const unsigned int*)(qred + (size_t)bh * 48 * DKK);
    unsigned int* qdst = (unsigned int*)Qs;
    #pragma unroll
    for (int t = 0; t < 6; t++) {
        int ui = tid + t * 256;            // 0..1535
        int u = ui >> 5, kp = ui & 31;
        int p = kp >> 4, kl2 = kp & 15;
        qdst[p * 768 + u * 16 + kl2] = qsrc[ui];
    }
    #pragma unroll
    for (int t = 0; t < 8; t++) {
        int fi = tid + t * 256;            // 0..2047
        int row = fi >> 4, k4 = fi & 15;
        int p = k4 >> 3, kl = (k4 & 7) * 4;
        float4 kv = *(const float4*)(Kb + ((size_t)(b * LL + l0 + row) * DD + h * DKK + k4 * 4));
        __bf16* dst = Ks + p * 128 * 32 + row * 32 + kl;
        dst[0] = (__bf16)kv.x; dst[1] = (__bf16)kv.y;
        dst[2] = (__bf16)kv.z; dst[3] = (__bf16)kv.w;
    }
    __syncthreads();
    int wave = tid >> 6, lane = tid & 63, l15 = lane & 15, kq = lane >> 4;
    floatx4 acc[3][2] = {};
    #pragma unroll
    for (int p = 0; p < 2; p++) {
        bf16x8 bq[2];
        #pragma unroll
        for (int j = 0; j < 2; j++)
            bq[j] = *(const bf16x8*)(Ks + p * 4096 + (wave * 32 + j * 16 + l15) * 32 + kq * 8);
        #pragma unroll
        for (int i = 0; i < 3; i++) {
            bf16x8 aq = *(const bf16x8*)(Qs + p * 1536 + (i * 16 + l15) * 32 + kq * 8);
            #pragma unroll
            for (int j = 0; j < 2; j++)
                acc[i][j] = __builtin_amdgcn_mfma_f32_16x16x32_bf16(bq[j], aq, acc[i][j], 0, 0, 0);
        }
    }
    // thread holds S[row][col..col+3]: row = i*16+l15, col = l0+wave*32+j*16+kq*4
    #pragma unroll
    for (int i = 0; i < 3; i++) {
        int row = i * 16 + l15;
        #pragma unroll
        for (int j = 0; j < 2; j++) {
            int col = l0 + wave * 32 + j * 16 + kq * 4;
            *(float4*)&S[((size_t)bh * 48 + row) * LL + col] = *(float4*)&acc[i][j];
        }
    }
}

// ------------- row softmax, in-place: S row fp32 -> P row bf16 -------------
__global__ __launch_bounds__(256) void softmax_p(float* __restrict__ S, int U)
{
    __shared__ float red[256];
    int row = blockIdx.x;              // 32*U rows
    int bh = row / U, u = row % U;
    float* sr = S + ((size_t)bh * 48 + u) * LL;
    int tid = threadIdx.x;
    float sc[8]; float mx = -1e30f;
    #pragma unroll
    for (int i = 0; i < 8; i++) { sc[i] = sr[tid + i * 256]; mx = fmaxf(mx, sc[i]); }
    red[tid] = mx; __syncthreads();
    for (int s = 128; s > 0; s >>= 1) { if (tid < s) red[tid] = fmaxf(red[tid], red[tid + s]); __syncthreads(); }
    mx = red[0]; __syncthreads();
    float se = 0.f;
    #pragma unroll
    for (int i = 0; i < 8; i++) { sc[i] = __expf(sc[i] - mx); se += sc[i]; }
    red[tid] = se; __syncthreads();
    for (int s = 128; s > 0; s >>= 1) { if (tid < s) red[tid] += red[tid + s]; __syncthreads(); }
    float inv = 1.0f / red[0];
    __bf16* pr = (__bf16*)sr;
    #pragma unroll
    for (int i = 0; i < 8; i++) pr[tid + i * 256] = (__bf16)(sc[i] * inv);
}

// ------------- zero upd (pv_k accumulates via atomicAdd) -------------------
__global__ __launch_bounds__(256) void zero_upd(float* __restrict__ upd, int n)
{
    int i = blockIdx.x * 256 + threadIdx.x;
    if (i < n) upd[i] = 0.f;
}

// ------------- upd[bh][u][d] += sum_{l in chunk} P[u][l] * V[b,h,l,d] ------
// L split 4-way (1280 blocks = 5/CU); uint2 V loads; LDS partials + atomicAdd.
__global__ __launch_bounds__(256) void pv_k(
    const float* __restrict__ S, const __bf16* __restrict__ V,
    float* __restrict__ upd, int U)
{
    __shared__ __bf16 pls[4][512];        // 4 KB
    __shared__ float osum[16][4][DKK];    // 16 KB
    int uc = blockIdx.x, lc = blockIdx.y, bh = blockIdx.z;
    int b = bh >> 3, h = bh & 7, tid = threadIdx.x;
    #pragma unroll
    for (int t = 0; t < 4; t++) {
        int ui = tid + t * 256;          // 0..1023
        int up = ui >> 8, lw = ui & 255;
        ((unsigned int*)pls)[up * 256 + lw] =
            ((const unsigned int*)(S + ((size_t)bh * 48 + uc * 4 + up) * LL))[lc * 256 + lw];
    }
    __syncthreads();
    int d4 = tid & 15, part = tid >> 4;   // 16 parts of 32 l; d4 covers 4 d's
    const __bf16* vp = V + ((size_t)(b * LL + lc * 512 + part * 32)) * DD + h * DKK + d4 * 4;
    float a[4][4] = {};
    for (int i = 0; i < 32; i++) {
        union { uint2 u; __bf16 bb[4]; } cv;
        cv.u = *(const uint2*)(vp + (size_t)i * DD);
        float v0 = (float)cv.bb[0], v1 = (float)cv.bb[1];
        float v2 = (float)cv.bb[2], v3 = (float)cv.bb[3];
        int l = part * 32 + i;
        #pragma unroll
        for (int u2 = 0; u2 < 4; u2++) {
            float p = (float)pls[u2][l];
            a[u2][0] += p * v0; a[u2][1] += p * v1;
            a[u2][2] += p * v2; a[u2][3] += p * v3;
        }
    }
    #pragma unroll
    for (int u2 = 0; u2 < 4; u2++)
        #pragma unroll
        for (int j = 0; j < 4; j++)
            osum[part][u2][d4 * 4 + j] = a[u2][j];
    __syncthreads();
    int d = tid & 63, u2 = tid >> 6;
    float s = 0.f;
    #pragma unroll
    for (int p = 0; p < 16; p++) s += osum[p][u2][d];
    atomicAdd(&upd[((size_t)bh * U + uc * 4 + u2) * DKK + d], s);
}

// ------------- base[b][n] = cmean[b] . Wo[:,n]  (fp32, tiny) ---------------
__global__ __launch_bounds__(256) void base_k(
    const float* __restrict__ Vm, const float* __restrict__ Wo,
    float* __restrict__ base)
{
    __shared__ float cm[DD];
    __shared__ float part[8][32];
    int b = blockIdx.y, n0 = blockIdx.x * 32, tid = threadIdx.x;
    cm[tid] = Vm[b * DD + tid];
    cm[tid + 256] = Vm[b * DD + 256 + tid];
    __syncthreads();
    int n = n0 + (tid & 31), kg = tid >> 5;      // 8 k-groups of 64
    float s = 0.f;
    for (int k = kg * 64; k < kg * 64 + 64; k++) s += cm[k] * Wo[(size_t)k * DD + n];
    part[kg][tid & 31] = s;
    __syncthreads();
    if (tid < 32) {
        float t = 0.f;
        #pragma unroll
        for (int g = 0; g < 8; g++) t += part[g][tid];
        base[b * DD + n0 + tid] = t;
    }
}

// ------------- aout init: every row of batch b <- base[b] ------------------
__global__ __launch_bounds__(256) void aout_init(
    const float* __restrict__ base, float* __restrict__ aout)
{
    int idx = blockIdx.x * 256 + threadIdx.x;    // over B*L*512
    aout[idx] = base[((idx >> 20) << 9) + (idx & 511)];
}

// ------------- aw[bh][u48][d] = bf16(upd - Vm) -----------------------------
__global__ __launch_bounds__(256) void aw_prep(
    const float* __restrict__ upd, const float* __restrict__ Vm,
    __bf16* __restrict__ aw, int U)
{
    int bh = blockIdx.x, tid = threadIdx.x;
    #pragma unroll
    for (int t = 0; t < 12; t++) {
        int e = tid + t * 256;                   // 0..3071
        int u = e >> 6, d = e & 63;
        float v = (u < U) ? upd[((size_t)bh * U + u) * DKK + d] - Vm[bh * DKK + d] : 0.f;
        aw[(size_t)bh * 48 * DKK + e] = (__bf16)v;
    }
}

// ------------- corr GEMM + scatter-add: aout[b, top[u]] += aw @ Wo_h -------
__global__ __launch_bounds__(256) void corr_gemm(
    const __bf16* __restrict__ aw, const __bf16* __restrict__ WoT,
    const int* __restrict__ top, float* __restrict__ aout, int U)
{
    __shared__ __bf16 Qs[2 * 48 * 32];    // aw panels (BK=32)
    __shared__ __bf16 Ks[2 * 128 * 32];   // WoT-slice panels
    int bh = blockIdx.y, nc = blockIdx.x;
    int b = bh >> 3, h = bh & 7, n0 = nc * 128;
    int tid = threadIdx.x;
    const unsigned int* qsrc = (const unsigned int*)(aw + (size_t)bh * 48 * DKK);
    unsigned int* qdst = (unsigned int*)Qs;
    #pragma unroll
    for (int t = 0; t < 6; t++) {
        int ui = tid + t * 256;            // 0..1535
        int u = ui >> 5, kp = ui & 31;
        int p = kp >> 4, kl2 = kp & 15;
        qdst[p * 768 + u * 16 + kl2] = qsrc[ui];
    }
    const unsigned int* wsrc = (const unsigned int*)WoT;
    unsigned int* kdst = (unsigned int*)Ks;
    #pragma unroll
    for (int t = 0; t < 16; t++) {
        int ui = tid + t * 256;            // 0..4095
        int row = ui >> 5, c2 = ui & 31;
        int p = c2 >> 4, col2 = c2 & 15;
        kdst[p * 2048 + row * 16 + col2] = wsrc[(size_t)(n0 + row) * (DD / 2) + h * 32 + c2];
    }
    __syncthreads();
    int wave = tid >> 6, lane = tid & 63, l15 = lane & 15, kq = lane >> 4;
    floatx4 acc[3][2] = {};
    #pragma unroll
    for (int p = 0; p < 2; p++) {
        bf16x8 bq[2];
        #pragma unroll
        for (int j = 0; j < 2; j++)
            bq[j] = *(const bf16x8*)(Ks + p * 4096 + (wave * 32 + j * 16 + l15) * 32 + kq * 8);
        #pragma unroll
        for (int i = 0; i < 3; i++) {
            bf16x8 aq = *(const bf16x8*)(Qs + p * 1536 + (i * 16 + l15) * 32 + kq * 8);
            #pragma unroll
            for (int j = 0; j < 2; j++)
                acc[i][j] = __builtin_amdgcn_mfma_f32_16x16x32_bf16(bq[j], aq, acc[i][j], 0, 0, 0);
        }
    }
    #pragma unroll
    for (int i = 0; i < 3; i++) {
        int u = i * 16 + l15;
        if (u < U) {
            int l = top[bh * U + u];
            float* dst = aout + ((size_t)(b * LL + l)) * DD;
            #pragma unroll
            for (int j = 0; j < 2; j++) {
                int n = n0 + wave * 32 + j * 16 + kq * 4;
                atomicAdd(dst + n,     acc[i][j][0]);
                atomicAdd(dst + n + 1, acc[i][j][1]);
                atomicAdd(dst + n + 2, acc[i][j][2]);
                atomicAdd(dst + n + 3, acc[i][j][3]);
            }
        }
    }
}

// ------------- LN1: x1 = LN(x + aout) -> bf16 ------------------------------
__global__ __launch_bounds__(256) void ln1_k(
    const float* __restrict__ x, const float* __restrict__ aout,
    const float* __restrict__ g, const float* __restrict__ bb,
    __bf16* __restrict__ x1h)
{
    __shared__ float red[256];
    int row = blockIdx.x, tid = threadIdx.x;
    size_t base = (size_t)row * DD;
    float h0 = x[base + tid] + aout[base + tid];
    float h1 = x[base + 256 + tid] + aout[base + 256 + tid];
    red[tid] = h0 + h1; __syncthreads();
    for (int s = 128; s > 0; s >>= 1) { if (tid < s) red[tid] += red[tid + s]; __syncthreads(); }
    float mean = red[0] * (1.0f / DD); __syncthreads();
    float d0 = h0 - mean, d1 = h1 - mean;
    red[tid] = d0 * d0 + d1 * d1; __syncthreads();
    for (int s = 128; s > 0; s >>= 1) { if (tid < s) red[tid] += red[tid + s]; __syncthreads(); }
    float rstd = rsqrtf(red[0] * (1.0f / DD) + 1e-5f);
    x1h[base + tid]       = (__bf16)(d0 * rstd * g[tid] + bb[tid]);
    x1h[base + 256 + tid] = (__bf16)(d1 * rstd * g[256 + tid] + bb[256 + tid]);
}

// ------------- LN2: out = LN(x1 + ffn2 + b2) -> fp32 -----------------------
__global__ __launch_bounds__(256) void ln2_k(
    const __bf16* __restrict__ x1h, const float* __restrict__ f2o,
    const float* __restrict__ c2b,
    const float* __restrict__ g, const float* __restrict__ bb,
    float* __restrict__ out)
{
    __shared__ float red[256];
    int row = blockIdx.x, tid = threadIdx.x;
    size_t base = (size_t)row * DD;
    float h0 = (float)x1h[base + tid] + f2o[base + tid] + c2b[tid];
    float h1 = (float)x1h[base + 256 + tid] + f2o[base + 256 + tid] + c2b[256 + tid];
    red[tid] = h0 + h1; __syncthreads();
    for (int s = 128; s > 0; s >>= 1) { if (tid < s) red[tid] += red[tid + s]; __syncthreads(); }
    float mean = red[0] * (1.0f / DD); __syncthreads();
    float d0 = h0 - mean, d1 = h1 - mean;
    red[tid] = d0 * d0 + d1 * d1; __syncthreads();
    for (int s = 128; s > 0; s >>= 1) { if (tid < s) red[tid] += red[tid + s]; __syncthreads(); }
    float rstd = rsqrtf(red[0] * (1.0f / DD) + 1e-5f);
    out[base + tid]       = d0 * rstd * g[tid] + bb[tid];
    out[base + 256 + tid] = d1 * rstd * g[256 + tid] + bb[256 + tid];
}

// ---------------------------------------------------------------------------
extern "C" void kernel_launch(void* const* d_in, const int* in_sizes, int n_in,
                              void* d_out, int out_size, void* d_ws, size_t ws_size,
                              hipStream_t stream)
{
    const float* x   = (const float*)d_in[0];
    const float* Wq  = (const float*)d_in[1];
    const float* Wk  = (const float*)d_in[2];
    const float* Wv  = (const float*)d_in[3];
    const float* Wo  = (const float*)d_in[4];
    const float* g1  = (const float*)d_in[5];
    const float* b1  = (const float*)d_in[6];
    const float* c1w = (const float*)d_in[7];
    const float* c1b = (const float*)d_in[8];
    const float* c2w = (const float*)d_in[9];
    const float* c2b = (const float*)d_in[10];
    const float* g2  = (const float*)d_in[11];
    const float* b2  = (const float*)d_in[12];
    const int* sidx  = (const int*)d_in[13];
    float* out       = (float*)d_out;

    const int U = in_sizes[13] / LL;            // 40
    const int M = BB * LL;                       // 8192

    char* ws = (char*)d_ws;
    const size_t MB = (size_t)1 << 20;
    float*  Q    = (float*)(ws + 0);
    float*  Kb   = (float*)(ws + 16 * MB);
    __bf16* V    = (__bf16*)(ws + 32 * MB);
    __bf16* xhi  = (__bf16*)(ws + 40 * MB);
    __bf16* xlo  = (__bf16*)(ws + 48 * MB);
    float*  S    = (float*)(ws + 40 * MB);          // 32*48*2048*4 = 12.6 MB
    __bf16* wb   = (__bf16*)(ws + 56 * MB);
    __bf16* c1wb = (__bf16*)(ws + 59 * MB);
    __bf16* c2wb = (__bf16*)(ws + 61 * MB);
    float*  Mo   = (float*)(ws + 63 * MB);
    float*  upd  = (float*)(ws + 63 * MB + 256 * 1024);
    float*  Vm   = (float*)(ws + 63 * MB + 576 * 1024);
    int*    top  = (int*)  (ws + 63 * MB + 584 * 1024);
    __bf16* qred = (__bf16*)(ws + 63 * MB + 592 * 1024);  // 192K
    __bf16* aw   = (__bf16*)(ws + 63 * MB + 784 * 1024);  // 192K
    float*  basep= (float*)(ws + 63 * MB + 976 * 1024);   // 8K
    float*  aout = Q;                               // alias: Q dead after gather_qred
    float*  f2o  = Q;                               // alias: aout dead after ln1
    __bf16* ych  = (__bf16*)(ws + 16 * MB);         // FFN intermediate (32 MB region)
    __bf16* x1h  = xlo;                             // alias: S/P dead by ln1
    (void)ws_size; (void)n_in; (void)out_size;

    const size_t SZ = (size_t)DD * DD;
    __bf16* WqThi = wb;          __bf16* WqTlo = wb + SZ;
    __bf16* WkThi = wb + 2 * SZ; __bf16* WkTlo = wb + 3 * SZ;
    __bf16* WvT   = wb + 4 * SZ; __bf16* WoT   = wb + 5 * SZ;

    // 1) weight prep + input split-cast
    prep_w<<<dim3(DD * DD / 256, 1, 4), 256, 0, stream>>>(Wq, Wk, Wv, Wo, wb);
    cast_cw<<<dim3(FF * DD / 256, 1, 2), 256, 0, stream>>>(c1w, c2w, c1wb, c2wb);
    split_cast_x<<<BB * LL * DD / 256, 256, 0, stream>>>(x, xhi, xlo);

    // 2) Q,K via split-precision MFMA (BM=64: 512 blocks = 2/CU);
    //    V bf16 via 64x64 tile (1024 blocks = 4/CU)
    dim3 gproj64(DD / 128, M / 64);
    gemm_mfma_split64<<<gproj64, 256, 0, stream>>>(xhi, xlo, WqThi, WqTlo, Q,  M, DD, DD);
    gemm_mfma_split64<<<gproj64, 256, 0, stream>>>(xhi, xlo, WkThi, WkTlo, Kb, M, DD, DD);
    dim3 gsq(DD / 64, M / 64);
    gemm_sq64<4, 0, false, true ><<<gsq, 256, 0, stream>>>(xhi, WvT, nullptr, V, M, DD, DD);

    // 3) sampled sparsity measure M, top-k, V mean (+ zero upd for pv atomics)
    calc_m<<<BB * LL, 256, 0, stream>>>(Q, Kb, sidx, Mo, U);
    zero_upd<<<(BB * HH * U * DKK + 255) / 256, 256, 0, stream>>>(upd, BB * HH * U * DKK);
    topk_k<<<BB * HH, 256, 0, stream>>>(Mo, top, U);
    vmean_k<<<BB * HH, 256, 0, stream>>>(V, Vm);

    // 4) attention: gather -> batched MFMA S -> softmax(in-place bf16 P) -> PV
    gather_qred<<<dim3(48 * DKK / 256, BB * HH), 256, 0, stream>>>(Q, top, qred, U);
    gemm_s<<<dim3(LL / 128, BB * HH), 256, 0, stream>>>(qred, Kb, S);
    softmax_p<<<BB * HH * U, 256, 0, stream>>>(S, U);
    pv_k<<<dim3(U / 4, 4, BB * HH), 256, 0, stream>>>(S, V, upd, U);

    // 5) out-projection via base + rank-U correction (Wo-GEMM eliminated)
    base_k<<<dim3(16, BB), 256, 0, stream>>>(Vm, Wo, basep);
    aw_prep<<<BB * HH, 256, 0, stream>>>(upd, Vm, aw, U);
    aout_init<<<M * DD / 256, 256, 0, stream>>>(basep, aout);
    corr_gemm<<<dim3(DD / 128, BB * HH), 256, 0, stream>>>(aw, WoT, top, aout, U);

    // 6) LN1 -> x1h bf16 (aliases xlo; S/P dead)
    ln1_k<<<M, 256, 0, stream>>>(x, aout, g1, b1, x1h);

    // 7) FFN: gelu(x1 @ c1w^T + c1b) -> ych bf16 (BM=128, 1024 blocks = 4/CU);
    //    ych @ c2w^T -> f2o (64x64 tile: 1024 blocks = 4 blocks/CU)
    gemm_mfma<3, 1, true,  true ><<<dim3(FF / 128, M / 128), 256, 0, stream>>>(x1h, c1wb, c1b, ych, M, FF, DD);
    gemm_sq64<4, 0, false, false><<<gsq, 256, 0, stream>>>(ych, c2wb, nullptr, f2o, M, DD, FF);

    // 8) LN2 -> fp32 output
    ln2_k<<<M, 256, 0, stream>>>(x1h, f2o, c2b, g2, b2, out);
}

// Round 14
// 380.433 us; speedup vs baseline: 1.1292x; 1.0111x over previous
//
#include <hip/hip_runtime.h>
#include <hip/hip_bf16.h>

// Problem constants (B=4, L=2048, D=512, H=8, DK=64, FF=2048, U=40)
#define BB 4
#define LL 2048
#define DD 512
#define HH 8
#define DKK 64
#define FF 2048

typedef __bf16  bf16x8  __attribute__((ext_vector_type(8)));
typedef float   floatx4 __attribute__((ext_vector_type(4)));

// async 16B global->LDS copy (global_load_lds_dwordx4)
__device__ __forceinline__ void async_cp16(const void* g, void* l) {
    __builtin_amdgcn_global_load_lds(
        (const __attribute__((address_space(1))) unsigned int*)g,
        (__attribute__((address_space(3))) unsigned int*)l,
        16, 0, 0);
}

// exact-grade GELU: A&S 7.1.26 erf, |err| < 1.5e-7 (fp32-exact at our scale).
__device__ __forceinline__ float gelu_f(float v) {
    float z  = v * 0.70710678118654752f;
    float az = fabsf(z);
    float t  = __builtin_amdgcn_rcpf(1.0f + 0.3275911f * az);
    float p  = ((((1.061405429f * t - 1.453152027f) * t + 1.421413741f) * t
                 - 0.284496736f) * t + 0.254829592f) * t;
    float e  = __expf(-z * z);
    float er = 1.0f - p * e;
    er = (z < 0.0f) ? -er : er;
    return 0.5f * v * (1.0f + er);
}

// ---------- prep: transpose 512x512 fp32 -> bf16 (N,K) -----------------------
// Layout: [0,SZ) WqThi | [SZ,2SZ) WkThi | [2SZ,3SZ) WqTlo | [3SZ,4SZ) WkTlo |
//         [4SZ,5SZ) WvT | [5SZ,6SZ) WoT  -- Q/K hi (and lo) contiguous so the
// fused QK projection sees a single 1024-row B.
__global__ __launch_bounds__(256) void prep_w(
    const float* __restrict__ Wq, const float* __restrict__ Wk,
    const float* __restrict__ Wv, const float* __restrict__ Wo,
    __bf16* __restrict__ wb)
{
    const size_t SZ = (size_t)DD * DD;
    int z = blockIdx.z;
    const float* s = (z == 0) ? Wq : (z == 1) ? Wk : (z == 2) ? Wv : Wo;
    __bf16* hi; __bf16* lo = nullptr;
    if (z == 0)      { hi = wb;          lo = wb + 2 * SZ; }
    else if (z == 1) { hi = wb + SZ;     lo = wb + 3 * SZ; }
    else if (z == 2) { hi = wb + 4 * SZ; }
    else             { hi = wb + 5 * SZ; }
    int idx = blockIdx.x * 256 + threadIdx.x;   // 0..512*512-1
    int k = idx >> 9, n = idx & 511;
    float v = s[idx];
    __bf16 h = (__bf16)v;
    hi[(size_t)n * DD + k] = h;
    if (lo) lo[(size_t)n * DD + k] = (__bf16)(v - (float)h);
}

// ---------- cast conv weights fp32 (N,K) -> bf16 -----------------------------
__global__ __launch_bounds__(256) void cast_cw(
    const float* __restrict__ c1w, const float* __restrict__ c2w,
    __bf16* __restrict__ d1, __bf16* __restrict__ d2)
{
    const float* s = blockIdx.z ? c2w : c1w;
    __bf16* d = blockIdx.z ? d2 : d1;
    int idx = blockIdx.x * 256 + threadIdx.x;   // 0..FF*DD-1
    d[idx] = (__bf16)s[idx];
}

// ---------- split-cast x fp32 -> bf16 hi + lo --------------------------------
__global__ __launch_bounds__(256) void split_cast_x(
    const float* __restrict__ x, __bf16* __restrict__ xhi, __bf16* __restrict__ xlo)
{
    int idx = blockIdx.x * 256 + threadIdx.x;
    float v = x[idx];
    __bf16 h = (__bf16)v;
    xhi[idx] = h;
    xlo[idx] = (__bf16)(v - (float)h);
}

// ---------- MFMA GEMM, 128x128 tile (FFN1: 1024 blocks = 4/CU) ---------------
template<int NB, int ACT, bool BIAS, bool OUT_BF16>
__global__ __launch_bounds__(256) void gemm_mfma(
    const __bf16* __restrict__ A, const __bf16* __restrict__ B,
    const float* __restrict__ bias, void* __restrict__ Cv,
    int M, int N, int K)
{
    __shared__ __bf16 As[NB][128 * 32];
    __shared__ __bf16 Bs[NB][128 * 32];
    const int tid = threadIdx.x;
    const int wave = tid >> 6, lane = tid & 63;
    const int gx = gridDim.x;
    const int nwg = gx * gridDim.y;
    const int hw = blockIdx.y * gx + blockIdx.x;
    const int virt = ((nwg & 7) == 0) ? ((hw & 7) * (nwg >> 3) + (hw >> 3)) : hw;
    const int m0 = (virt / gx) * 128, n0 = (virt % gx) * 128;
    const int wm = (wave >> 1) * 64, wn = (wave & 1) * 64;
    const int l15 = lane & 15, kq = lane >> 4;

    auto stage = [&](int buf, int k0) {           // 4 vmem insts per thread
        #pragma unroll
        for (int p = 0; p < 2; p++) {
            int c = p * 256 + tid;                // 16B chunk id 0..511
            int row = c >> 2;
            int col = ((c & 3) ^ ((row >> 1) & 3)) * 8;   // inverse-swizzled src
            async_cp16(A + (size_t)(m0 + row) * K + k0 + col, &As[buf][c * 8]);
            async_cp16(B + (size_t)(n0 + row) * K + k0 + col, &Bs[buf][c * 8]);
        }
    };

    floatx4 acc[4][4] = {};

    const int nt = K >> 5;
    #pragma unroll
    for (int pt = 0; pt < NB - 1; pt++) stage(pt, pt << 5);
    asm volatile("s_waitcnt vmcnt(4)"  ::: "memory");
    __builtin_amdgcn_s_barrier();
    int bi = 0;                                   // buffer of current tile
    for (int t = 0; t < nt; t++) {
        if (t + NB - 1 < nt) {
            int b2 = bi + NB - 1; if (b2 >= NB) b2 -= NB;
            stage(b2, (t + NB - 1) << 5);
        }
        asm volatile("" ::: "memory");
        bf16x8 af[4], bfr[4];
        #pragma unroll
        for (int i = 0; i < 4; i++) {
            int ra = wm + i * 16 + l15;
            af[i] = *(const bf16x8*)(&As[bi][ra * 32 + ((kq ^ ((ra >> 1) & 3)) << 3)]);
        }
        #pragma unroll
        for (int j = 0; j < 4; j++) {
            int rb = wn + j * 16 + l15;
            bfr[j] = *(const bf16x8*)(&Bs[bi][rb * 32 + ((kq ^ ((rb >> 1) & 3)) << 3)]);
        }
        #pragma unroll
        for (int i = 0; i < 4; i++)
            #pragma unroll
            for (int j = 0; j < 4; j++)
                acc[i][j] = __builtin_amdgcn_mfma_f32_16x16x32_bf16(bfr[j], af[i], acc[i][j], 0, 0, 0);
        asm volatile("" ::: "memory");
        if (t + 1 < nt) {                         // wait: tile t+1 landed
            int c = nt - 2 - t; if (c > NB - 2) c = NB - 2;
            if (c >= 2)      asm volatile("s_waitcnt vmcnt(8)"  ::: "memory");
            else if (c == 1) asm volatile("s_waitcnt vmcnt(4)"  ::: "memory");
            else             asm volatile("s_waitcnt vmcnt(0)"  ::: "memory");
            __builtin_amdgcn_s_barrier();
        }
        if (++bi == NB) bi = 0;
    }
    #pragma unroll
    for (int i = 0; i < 4; i++) {
        int m = m0 + wm + i * 16 + l15;
        #pragma unroll
        for (int j = 0; j < 4; j++) {
            int n = n0 + wn + j * 16 + kq * 4;
            floatx4 v4 = acc[i][j];
            if (BIAS) {
                float4 bv = *(const float4*)&bias[n];
                v4[0] += bv.x; v4[1] += bv.y; v4[2] += bv.z; v4[3] += bv.w;
            }
            if (ACT == 1) {
                v4[0] = gelu_f(v4[0]); v4[1] = gelu_f(v4[1]);
                v4[2] = gelu_f(v4[2]); v4[3] = gelu_f(v4[3]);
            }
            if (OUT_BF16) {
                union { __bf16 b[4]; uint2 u; } pk;
                pk.b[0] = (__bf16)v4[0]; pk.b[1] = (__bf16)v4[1];
                pk.b[2] = (__bf16)v4[2]; pk.b[3] = (__bf16)v4[3];
                *(uint2*)((__bf16*)Cv + (size_t)m * N + n) = pk.u;
            } else {
                *(float4*)((float*)Cv + (size_t)m * N + n) = *(float4*)&v4;
            }
        }
    }
}

// ---------- MFMA GEMM, 64x64 tile for grid-limited N=512 GEMMs ---------------
// 1024 blocks = 4 blocks/CU = 4 waves/SIMD. acc[2][2], NB=4 -> 32 KB LDS.
template<int NB, int ACT, bool BIAS, bool OUT_BF16>
__global__ __launch_bounds__(256) void gemm_sq64(
    const __bf16* __restrict__ A, const __bf16* __restrict__ B,
    const float* __restrict__ bias, void* __restrict__ Cv,
    int M, int N, int K)
{
    __shared__ __bf16 As[NB][64 * 32];
    __shared__ __bf16 Bs[NB][64 * 32];
    const int tid = threadIdx.x;
    const int wave = tid >> 6, lane = tid & 63;
    const int gx = gridDim.x;
    const int nwg = gx * gridDim.y;
    const int hw = blockIdx.y * gx + blockIdx.x;
    const int virt = ((nwg & 7) == 0) ? ((hw & 7) * (nwg >> 3) + (hw >> 3)) : hw;
    const int m0 = (virt / gx) * 64, n0 = (virt % gx) * 64;
    const int wm = (wave >> 1) * 32, wn = (wave & 1) * 32;
    const int l15 = lane & 15, kq = lane >> 4;

    auto stage = [&](int buf, int k0) {           // 2 vmem insts per thread
        int c = tid;                              // 256 chunks = 64 rows x 4
        int row = c >> 2;
        int col = ((c & 3) ^ ((row >> 1) & 3)) * 8;
        async_cp16(A + (size_t)(m0 + row) * K + k0 + col, &As[buf][c * 8]);
        async_cp16(B + (size_t)(n0 + row) * K + k0 + col, &Bs[buf][c * 8]);
    };

    floatx4 acc[2][2] = {};

    const int nt = K >> 5;
    #pragma unroll
    for (int pt = 0; pt < NB - 1; pt++) stage(pt, pt << 5);
    asm volatile("s_waitcnt vmcnt(%0)" :: "i"(2 * (NB - 2)) : "memory");
    __builtin_amdgcn_s_barrier();
    int bi = 0;
    for (int t = 0; t < nt; t++) {
        if (t + NB - 1 < nt) {
            int b2 = bi + NB - 1; if (b2 >= NB) b2 -= NB;
            stage(b2, (t + NB - 1) << 5);
        }
        asm volatile("" ::: "memory");
        bf16x8 af[2], bfr[2];
        #pragma unroll
        for (int i = 0; i < 2; i++) {
            int ra = wm + i * 16 + l15;
            af[i] = *(const bf16x8*)(&As[bi][ra * 32 + ((kq ^ ((ra >> 1) & 3)) << 3)]);
        }
        #pragma unroll
        for (int j = 0; j < 2; j++) {
            int rb = wn + j * 16 + l15;
            bfr[j] = *(const bf16x8*)(&Bs[bi][rb * 32 + ((kq ^ ((rb >> 1) & 3)) << 3)]);
        }
        #pragma unroll
        for (int i = 0; i < 2; i++)
            #pragma unroll
            for (int j = 0; j < 2; j++)
                acc[i][j] = __builtin_amdgcn_mfma_f32_16x16x32_bf16(bfr[j], af[i], acc[i][j], 0, 0, 0);
        asm volatile("" ::: "memory");
        if (t + 1 < nt) {
            int c = nt - 2 - t; if (c > NB - 2) c = NB - 2;
            if (c >= 3)      asm volatile("s_waitcnt vmcnt(6)" ::: "memory");
            else if (c == 2) asm volatile("s_waitcnt vmcnt(4)" ::: "memory");
            else if (c == 1) asm volatile("s_waitcnt vmcnt(2)" ::: "memory");
            else             asm volatile("s_waitcnt vmcnt(0)" ::: "memory");
            __builtin_amdgcn_s_barrier();
        }
        if (++bi == NB) bi = 0;
    }
    #pragma unroll
    for (int i = 0; i < 2; i++) {
        int m = m0 + wm + i * 16 + l15;
        #pragma unroll
        for (int j = 0; j < 2; j++) {
            int n = n0 + wn + j * 16 + kq * 4;
            floatx4 v4 = acc[i][j];
            if (BIAS) {
                float4 bv = *(const float4*)&bias[n];
                v4[0] += bv.x; v4[1] += bv.y; v4[2] += bv.z; v4[3] += bv.w;
            }
            if (ACT == 1) {
                v4[0] = gelu_f(v4[0]); v4[1] = gelu_f(v4[1]);
                v4[2] = gelu_f(v4[2]); v4[3] = gelu_f(v4[3]);
            }
            if (OUT_BF16) {
                union { __bf16 b[4]; uint2 u; } pk;
                pk.b[0] = (__bf16)v4[0]; pk.b[1] = (__bf16)v4[1];
                pk.b[2] = (__bf16)v4[2]; pk.b[3] = (__bf16)v4[3];
                *(uint2*)((__bf16*)Cv + (size_t)m * N + n) = pk.u;
            } else {
                *(float4*)((float*)Cv + (size_t)m * N + n) = *(float4*)&v4;
            }
        }
    }
}

// ---------- fused split-precision QK projection, 64x64 tile ------------------
// C = (Ah+Al)(Bh+Bl)^T with B = [WqT; WkT] (1024 rows). Shares the A staging
// between Q and K (was two kernels, each re-fetching A) and lifts TLP: grid
// 16x128 = 2048 blocks; NB=2 -> 32 KB LDS -> 5 blocks/CU (was 2). Each
// block's 64-col range lies wholly in the Q- or K-half (n0 is 64-aligned,
// halves 512-aligned) -> one branch per block selects the output buffer.
// Per-output math identical to the separate kernels -> bit-identical Q/K.
__global__ __launch_bounds__(256) void gemm_split_qk(
    const __bf16* __restrict__ Ah, const __bf16* __restrict__ Al,
    const __bf16* __restrict__ Bh, const __bf16* __restrict__ Bl,
    float* __restrict__ Cq, float* __restrict__ Ck, int M, int K)
{
    __shared__ __bf16 Ahs[2][64 * 32];
    __shared__ __bf16 Als[2][64 * 32];
    __shared__ __bf16 Bhs[2][64 * 32];
    __shared__ __bf16 Bls[2][64 * 32];
    const int tid = threadIdx.x;
    const int wave = tid >> 6, lane = tid & 63;
    const int gx = gridDim.x;                     // 16
    const int nwg = gx * gridDim.y;
    const int hw = blockIdx.y * gx + blockIdx.x;
    const int virt = ((nwg & 7) == 0) ? ((hw & 7) * (nwg >> 3) + (hw >> 3)) : hw;
    const int m0 = (virt / gx) * 64, n0 = (virt % gx) * 64;
    const int wm = (wave >> 1) * 32, wn = (wave & 1) * 32;
    const int l15 = lane & 15, kq = lane >> 4;

    auto stage = [&](int buf, int k0) {           // 4 vmem insts per thread
        int c = tid;                              // 256 chunks = 64 rows x 4
        int row = c >> 2;
        int col = ((c & 3) ^ ((row >> 1) & 3)) * 8;
        size_t goA = (size_t)(m0 + row) * K + k0 + col;
        size_t goB = (size_t)(n0 + row) * K + k0 + col;
        async_cp16(Ah + goA, &Ahs[buf][c * 8]);
        async_cp16(Al + goA, &Als[buf][c * 8]);
        async_cp16(Bh + goB, &Bhs[buf][c * 8]);
        async_cp16(Bl + goB, &Bls[buf][c * 8]);
    };

    floatx4 acc[2][2] = {};

    const int nt = K >> 5;
    stage(0, 0);
    asm volatile("s_waitcnt vmcnt(0)" ::: "memory");
    __builtin_amdgcn_s_barrier();
    int bi = 0;
    for (int t = 0; t < nt; t++) {
        if (t + 1 < nt) stage(bi ^ 1, (t + 1) << 5);
        asm volatile("" ::: "memory");
        bf16x8 ah[2], al[2], bh[2], bl[2];
        #pragma unroll
        for (int i = 0; i < 2; i++) {
            int ra = wm + i * 16 + l15;
            int off = ra * 32 + ((kq ^ ((ra >> 1) & 3)) << 3);
            ah[i] = *(const bf16x8*)(&Ahs[bi][off]);
            al[i] = *(const bf16x8*)(&Als[bi][off]);
        }
        #pragma unroll
        for (int j = 0; j < 2; j++) {
            int rb = wn + j * 16 + l15;
            int off = rb * 32 + ((kq ^ ((rb >> 1) & 3)) << 3);
            bh[j] = *(const bf16x8*)(&Bhs[bi][off]);
            bl[j] = *(const bf16x8*)(&Bls[bi][off]);
        }
        #pragma unroll
        for (int i = 0; i < 2; i++)
            #pragma unroll
            for (int j = 0; j < 2; j++) {
                acc[i][j] = __builtin_amdgcn_mfma_f32_16x16x32_bf16(bh[j], ah[i], acc[i][j], 0, 0, 0);
                acc[i][j] = __builtin_amdgcn_mfma_f32_16x16x32_bf16(bl[j], ah[i], acc[i][j], 0, 0, 0);
                acc[i][j] = __builtin_amdgcn_mfma_f32_16x16x32_bf16(bh[j], al[i], acc[i][j], 0, 0, 0);
            }
        asm volatile("" ::: "memory");
        if (t + 1 < nt) {
            asm volatile("s_waitcnt vmcnt(0)" ::: "memory");
            __builtin_amdgcn_s_barrier();
        }
        bi ^= 1;
    }
    float* C = (n0 < DD) ? Cq : Ck;
    const int nc0 = n0 & (DD - 1);
    #pragma unroll
    for (int i = 0; i < 2; i++) {
        int m = m0 + wm + i * 16 + l15;
        #pragma unroll
        for (int j = 0; j < 2; j++) {
            int n = nc0 + wn + j * 16 + kq * 4;
            *(float4*)(C + (size_t)m * DD + n) = *(float4*)&acc[i][j];
        }
    }
}

// ------------- M[b,h,l] = max_s(q·k_s) - sum_s(q·k_s)/L  (sampled) ---------
// 16-lane sum via DPP-fused v_add_f32 (pure VALU; no LDS-pipe ds_swizzle).
__device__ __forceinline__ float dpp_sum16(float p) {
    int t;
    t = __builtin_amdgcn_update_dpp(0, __float_as_int(p), 0xB1,  0xF, 0xF, true); // quad_perm [1,0,3,2]
    p += __int_as_float(t);
    t = __builtin_amdgcn_update_dpp(0, __float_as_int(p), 0x4E,  0xF, 0xF, true); // quad_perm [2,3,0,1]
    p += __int_as_float(t);
    t = __builtin_amdgcn_update_dpp(0, __float_as_int(p), 0x141, 0xF, 0xF, true); // row_half_mirror
    p += __int_as_float(t);
    t = __builtin_amdgcn_update_dpp(0, __float_as_int(p), 0x140, 0xF, 0xF, true); // row_mirror
    p += __int_as_float(t);
    return p;
}

__global__ __launch_bounds__(256) void calc_m(
    const float* __restrict__ Q, const float* __restrict__ Kb,
    const int* __restrict__ sidx, float* __restrict__ Mo, int U)
{
    __shared__ int   js[64];
    __shared__ float red_mx[2][HH];
    __shared__ float red_sm[2][HH];
    int i = blockIdx.x;
    int b = i & 3, l = i >> 2;
    int tid = threadIdx.x;
    if (tid < U) js[tid] = sidx[l * U + tid];
    int e    = (tid & 127) * 4;          // element index within 512-wide row
    int slot = tid >> 7;                 // 0/1: even/odd samples
    const float* qr = Q + ((size_t)(b * LL + l) * DD);
    float4 q = *(const float4*)(qr + e);
    const float* kbase = Kb + ((size_t)b * LL) * DD + e;
    __syncthreads();
    float mx = -1e30f, sm = 0.f;
    for (int s = slot; s < U; s += 2) {
        int j = js[s];
        float4 kv = *(const float4*)(kbase + (size_t)j * DD);
        float p = q.x * kv.x + q.y * kv.y + q.z * kv.z + q.w * kv.w;
        p = dpp_sum16(p);
        mx = fmaxf(mx, p);
        sm += p;
    }
    if ((tid & 15) == 0) {
        int head = (tid >> 4) & 7;
        red_mx[slot][head] = mx;
        red_sm[slot][head] = sm;
    }
    __syncthreads();
    if (tid < HH) {
        float m2 = fmaxf(red_mx[0][tid], red_mx[1][tid]);
        float s2 = red_sm[0][tid] + red_sm[1][tid];
        Mo[((size_t)(b * HH + tid)) * LL + l] = m2 - s2 * (1.0f / (float)LL);
    }
}

// ------------- radix-select top-40 per (b,h) row of M ----------------------
__global__ __launch_bounds__(256) void topk_k(
    const float* __restrict__ Mo, int* __restrict__ top, int U)
{
    __shared__ unsigned int hist[256];
    __shared__ unsigned int wsum[4];
    __shared__ unsigned int bc[2];
    __shared__ int ties[LL];
    __shared__ int cnt2[2];
    int bh = blockIdx.x, tid = threadIdx.x;
    int lane = tid & 63, w = tid >> 6;

    unsigned int my[8];
    #pragma unroll
    for (int i = 0; i < 8; i++) {
        unsigned int u = __float_as_uint(Mo[(size_t)bh * LL + tid + i * 256]);
        my[i] = u ^ ((u >> 31) ? 0xFFFFFFFFu : 0x80000000u);  // order-preserving
    }

    unsigned int prefix = 0, pmask = 0;
    unsigned int need = (unsigned int)U;
    unsigned int above = 0;

    for (int pass = 0; pass < 4; pass++) {
        int shift = 24 - pass * 8;
        hist[tid] = 0;
        __syncthreads();
        #pragma unroll
        for (int i = 0; i < 8; i++) {
            unsigned int u = my[i];
            if ((u & pmask) == prefix)
                atomicAdd(&hist[(u >> shift) & 255u], 1u);
        }
        __syncthreads();
        unsigned int h = hist[tid];
        #pragma unroll
        for (int off = 1; off < 64; off <<= 1) {
            unsigned int o = __shfl_down(h, off);
            if (lane + off < 64) h += o;
        }
        if (lane == 0) wsum[w] = h;
        __syncthreads();
        unsigned int tail = 0;
        #pragma unroll
        for (int w2 = 1; w2 < 4; w2++) if (w2 > w) tail += wsum[w2];
        h += tail;
        hist[tid] = h;
        __syncthreads();
        unsigned int St = h;
        unsigned int St1 = (tid < 255) ? hist[tid + 1] : 0u;
        if (St >= need && St1 < need) { bc[0] = (unsigned int)tid; bc[1] = St1; }
        __syncthreads();
        unsigned int dig = bc[0], abv = bc[1];
        above += abv;
        need -= abv;
        prefix |= dig << shift;
        pmask |= 0xFFu << shift;
        __syncthreads();
    }

    if (tid == 0) { cnt2[0] = 0; cnt2[1] = 0; }
    __syncthreads();
    #pragma unroll
    for (int i = 0; i < 8; i++) {
        unsigned int u = my[i];
        int idx = tid + i * 256;
        if (u > prefix) {
            int pos = atomicAdd(&cnt2[0], 1);
            top[bh * U + pos] = idx;
        } else if (u == prefix) {
            int pos = atomicAdd(&cnt2[1], 1);
            ties[pos] = idx;
        }
    }
    __syncthreads();
    int tcnt = cnt2[1];
    #pragma unroll
    for (int i = 0; i < 8; i++) {
        unsigned int u = my[i];
        if (u == prefix) {
            int idx = tid + i * 256;
            int rank = 0;
            for (int j = 0; j < tcnt; j++) rank += (ties[j] < idx) ? 1 : 0;
            if (rank < (int)need) top[bh * U + (int)above + rank] = idx;
        }
    }
}

// ------------- Vmean[b,h,d] (V bf16), 256 threads/block --------------------
__global__ __launch_bounds__(256) void vmean_k(
    const __bf16* __restrict__ V, float* __restrict__ Vm)
{
    __shared__ float osum[4][DKK];
    int bh = blockIdx.x;
    int b = bh >> 3, h = bh & 7;
    int tid = threadIdx.x, d = tid & 63, part = tid >> 6;
    const __bf16* vp = V + ((size_t)(b * LL + part * 512) * DD + h * DKK + d);
    float s = 0.f;
    for (int i = 0; i < 512; i++) s += (float)vp[(size_t)i * DD];
    osum[part][d] = s;
    __syncthreads();
    if (tid < DKK)
        Vm[bh * DKK + tid] = (osum[0][tid] + osum[1][tid] + osum[2][tid] + osum[3][tid]) * (1.0f / (float)LL);
}

// ------------- gather Q[top] -> qred[32][48][64] bf16, scaled by 1/8 -------
__global__ __launch_bounds__(256) void gather_qred(
    const float* __restrict__ Q, const int* __restrict__ top,
    __bf16* __restrict__ qred, int U)
{
    int bh = blockIdx.y;
    int b = bh >> 3, h = bh & 7;
    int e = blockIdx.x * 256 + threadIdx.x;   // 0..48*64-1
    int u = e >> 6, d = e & 63;
    float v = 0.f;
    if (u < U) {
        int l = top[bh * U + u];
        v = Q[((size_t)(b * LL + l) * DD + h * DKK) + d] * 0.125f;
    }
    qred[(size_t)bh * 48 * DKK + e] = (__bf16)v;
}

// ------------- batched S[bh][48][2048] = qred[bh] @ K[bh]^T (MFMA) ---------
// Swapped-operand MFMA -> float4 stores of S.
__global__ __launch_bounds__(256) void gemm_s(
    const __bf16* __restrict__ qred, const float* __restrict__ Kb,
    float* __restrict__ S)
{
    __shared__ __bf16 Qs[2 * 48 * 32];    // 2 panels of BK=32
    __shared__ __bf16 Ks[2 * 128 * 32];
    int bh = blockIdx.y, nc = blockIdx.x;
    int b = bh >> 3, h = bh & 7, l0 = nc * 128;
    int tid = threadIdx.x;
    const unsigned int* qsrc = (const unsigned int*)(qred + (size_t)bh * 48 * DKK);
    unsigned int* qdst = (unsigned int*)Qs;
    #pragma unroll
    for (int t = 0; t < 6; t++) {
        int ui = tid + t * 256;            // 0..1535
        int u = ui >> 5, kp = ui & 31;
        int p = kp >> 4, kl2 = kp & 15;
        qdst[p * 768 + u * 16 + kl2] = qsrc[ui];
    }
    #pragma unroll
    for (int t = 0; t < 8; t++) {
        int fi = tid + t * 256;            // 0..2047
        int row = fi >> 4, k4 = fi & 15;
        int p = k4 >> 3, kl = (k4 & 7) * 4;
        float4 kv = *(const float4*)(Kb + ((size_t)(b * LL + l0 + row) * DD + h * DKK + k4 * 4));
        __bf16* dst = Ks + p * 128 * 32 + row * 32 + kl;
        dst[0] = (__bf16)kv.x; dst[1] = (__bf16)kv.y;
        dst[2] = (__bf16)kv.z; dst[3] = (__bf16)kv.w;
    }
    __syncthreads();
    int wave = tid >> 6, lane = tid & 63, l15 = lane & 15, kq = lane >> 4;
    floatx4 acc[3][2] = {};
    #pragma unroll
    for (int p = 0; p < 2; p++) {
        bf16x8 bq[2];
        #pragma unroll
        for (int j = 0; j < 2; j++)
            bq[j] = *(const bf16x8*)(Ks + p * 4096 + (wave * 32 + j * 16 + l15) * 32 + kq * 8);
        #pragma unroll
        for (int i = 0; i < 3; i++) {
            bf16x8 aq = *(const bf16x8*)(Qs + p * 1536 + (i * 16 + l15) * 32 + kq * 8);
            #pragma unroll
            for (int j = 0; j < 2; j++)
                acc[i][j] = __builtin_amdgcn_mfma_f32_16x16x32_bf16(bq[j], aq, acc[i][j], 0, 0, 0);
        }
    }
    // thread holds S[row][col..col+3]: row = i*16+l15, col = l0+wave*32+j*16+kq*4
    #pragma unroll
    for (int i = 0; i < 3; i++) {
        int row = i * 16 + l15;
        #pragma unroll
        for (int j = 0; j < 2; j++) {
            int col = l0 + wave * 32 + j * 16 + kq * 4;
            *(float4*)&S[((size_t)bh * 48 + row) * LL + col] = *(float4*)&acc[i][j];
        }
    }
}

// ------------- row softmax, in-place: S row fp32 -> P row bf16 -------------
__global__ __launch_bounds__(256) void softmax_p(float* __restrict__ S, int U)
{
    __shared__ float red[256];
    int row = blockIdx.x;              // 32*U rows
    int bh = row / U, u = row % U;
    float* sr = S + ((size_t)bh * 48 + u) * LL;
    int tid = threadIdx.x;
    float sc[8]; float mx = -1e30f;
    #pragma unroll
    for (int i = 0; i < 8; i++) { sc[i] = sr[tid + i * 256]; mx = fmaxf(mx, sc[i]); }
    red[tid] = mx; __syncthreads();
    for (int s = 128; s > 0; s >>= 1) { if (tid < s) red[tid] = fmaxf(red[tid], red[tid + s]); __syncthreads(); }
    mx = red[0]; __syncthreads();
    float se = 0.f;
    #pragma unroll
    for (int i = 0; i < 8; i++) { sc[i] = __expf(sc[i] - mx); se += sc[i]; }
    red[tid] = se; __syncthreads();
    for (int s = 128; s > 0; s >>= 1) { if (tid < s) red[tid] += red[tid + s]; __syncthreads(); }
    float inv = 1.0f / red[0];
    __bf16* pr = (__bf16*)sr;
    #pragma unroll
    for (int i = 0; i < 8; i++) pr[tid + i * 256] = (__bf16)(sc[i] * inv);
}

// ------------- zero upd (pv_k accumulates via atomicAdd) -------------------
__global__ __launch_bounds__(256) void zero_upd(float* __restrict__ upd, int n)
{
    int i = blockIdx.x * 256 + threadIdx.x;
    if (i < n) upd[i] = 0.f;
}

// ------------- upd[bh][u][d] += sum_{l in chunk} P[u][l] * V[b,h,l,d] ------
// L split 4-way (1280 blocks = 5/CU); uint2 V loads; LDS partials + atomicAdd.
__global__ __launch_bounds__(256) void pv_k(
    const float* __restrict__ S, const __bf16* __restrict__ V,
    float* __restrict__ upd, int U)
{
    __shared__ __bf16 pls[4][512];        // 4 KB
    __shared__ float osum[16][4][DKK];    // 16 KB
    int uc = blockIdx.x, lc = blockIdx.y, bh = blockIdx.z;
    int b = bh >> 3, h = bh & 7, tid = threadIdx.x;
    #pragma unroll
    for (int t = 0; t < 4; t++) {
        int ui = tid + t * 256;          // 0..1023
        int up = ui >> 8, lw = ui & 255;
        ((unsigned int*)pls)[up * 256 + lw] =
            ((const unsigned int*)(S + ((size_t)bh * 48 + uc * 4 + up) * LL))[lc * 256 + lw];
    }
    __syncthreads();
    int d4 = tid & 15, part = tid >> 4;   // 16 parts of 32 l; d4 covers 4 d's
    const __bf16* vp = V + ((size_t)(b * LL + lc * 512 + part * 32)) * DD + h * DKK + d4 * 4;
    float a[4][4] = {};
    for (int i = 0; i < 32; i++) {
        union { uint2 u; __bf16 bb[4]; } cv;
        cv.u = *(const uint2*)(vp + (size_t)i * DD);
        float v0 = (float)cv.bb[0], v1 = (float)cv.bb[1];
        float v2 = (float)cv.bb[2], v3 = (float)cv.bb[3];
        int l = part * 32 + i;
        #pragma unroll
        for (int u2 = 0; u2 < 4; u2++) {
            float p = (float)pls[u2][l];
            a[u2][0] += p * v0; a[u2][1] += p * v1;
            a[u2][2] += p * v2; a[u2][3] += p * v3;
        }
    }
    #pragma unroll
    for (int u2 = 0; u2 < 4; u2++)
        #pragma unroll
        for (int j = 0; j < 4; j++)
            osum[part][u2][d4 * 4 + j] = a[u2][j];
    __syncthreads();
    int d = tid & 63, u2 = tid >> 6;
    float s = 0.f;
    #pragma unroll
    for (int p = 0; p < 16; p++) s += osum[p][u2][d];
    atomicAdd(&upd[((size_t)bh * U + uc * 4 + u2) * DKK + d], s);
}

// ------------- base[b][n] = cmean[b] . Wo[:,n]  (fp32, tiny) ---------------
__global__ __launch_bounds__(256) void base_k(
    const float* __restrict__ Vm, const float* __restrict__ Wo,
    float* __restrict__ base)
{
    __shared__ float cm[DD];
    __shared__ float part[8][32];
    int b = blockIdx.y, n0 = blockIdx.x * 32, tid = threadIdx.x;
    cm[tid] = Vm[b * DD + tid];
    cm[tid + 256] = Vm[b * DD + 256 + tid];
    __syncthreads();
    int n = n0 + (tid & 31), kg = tid >> 5;      // 8 k-groups of 64
    float s = 0.f;
    for (int k = kg * 64; k < kg * 64 + 64; k++) s += cm[k] * Wo[(size_t)k * DD + n];
    part[kg][tid & 31] = s;
    __syncthreads();
    if (tid < 32) {
        float t = 0.f;
        #pragma unroll
        for (int g = 0; g < 8; g++) t += part[g][tid];
        base[b * DD + n0 + tid] = t;
    }
}

// ------------- aout init: every row of batch b <- base[b] ------------------
__global__ __launch_bounds__(256) void aout_init(
    const float* __restrict__ base, float* __restrict__ aout)
{
    int idx = blockIdx.x * 256 + threadIdx.x;    // over B*L*512
    aout[idx] = base[((idx >> 20) << 9) + (idx & 511)];
}

// ------------- aw[bh][u48][d] = bf16(upd - Vm) -----------------------------
__global__ __launch_bounds__(256) void aw_prep(
    const float* __restrict__ upd, const float* __restrict__ Vm,
    __bf16* __restrict__ aw, int U)
{
    int bh = blockIdx.x, tid = threadIdx.x;
    #pragma unroll
    for (int t = 0; t < 12; t++) {
        int e = tid + t * 256;                   // 0..3071
        int u = e >> 6, d = e & 63;
        float v = (u < U) ? upd[((size_t)bh * U + u) * DKK + d] - Vm[bh * DKK + d] : 0.f;
        aw[(size_t)bh * 48 * DKK + e] = (__bf16)v;
    }
}

// ------------- corr GEMM + scatter-add: aout[b, top[u]] += aw @ Wo_h -------
__global__ __launch_bounds__(256) void corr_gemm(
    const __bf16* __restrict__ aw, const __bf16* __restrict__ WoT,
    const int* __restrict__ top, float* __restrict__ aout, int U)
{
    __shared__ __bf16 Qs[2 * 48 * 32];    // aw panels (BK=32)
    __shared__ __bf16 Ks[2 * 128 * 32];   // WoT-slice panels
    int bh = blockIdx.y, nc = blockIdx.x;
    int b = bh >> 3, h = bh & 7, n0 = nc * 128;
    int tid = threadIdx.x;
    const unsigned int* qsrc = (const unsigned int*)(aw + (size_t)bh * 48 * DKK);
    unsigned int* qdst = (unsigned int*)Qs;
    #pragma unroll
    for (int t = 0; t < 6; t++) {
        int ui = tid + t * 256;            // 0..1535
        int u = ui >> 5, kp = ui & 31;
        int p = kp >> 4, kl2 = kp & 15;
        qdst[p * 768 + u * 16 + kl2] = qsrc[ui];
    }
    const unsigned int* wsrc = (const unsigned int*)WoT;
    unsigned int* kdst = (unsigned int*)Ks;
    #pragma unroll
    for (int t = 0; t < 16; t++) {
        int ui = tid + t * 256;            // 0..4095
        int row = ui >> 5, c2 = ui & 31;
        int p = c2 >> 4, col2 = c2 & 15;
        kdst[p * 2048 + row * 16 + col2] = wsrc[(size_t)(n0 + row) * (DD / 2) + h * 32 + c2];
    }
    __syncthreads();
    int wave = tid >> 6, lane = tid & 63, l15 = lane & 15, kq = lane >> 4;
    floatx4 acc[3][2] = {};
    #pragma unroll
    for (int p = 0; p < 2; p++) {
        bf16x8 bq[2];
        #pragma unroll
        for (int j = 0; j < 2; j++)
            bq[j] = *(const bf16x8*)(Ks + p * 4096 + (wave * 32 + j * 16 + l15) * 32 + kq * 8);
        #pragma unroll
        for (int i = 0; i < 3; i++) {
            bf16x8 aq = *(const bf16x8*)(Qs + p * 1536 + (i * 16 + l15) * 32 + kq * 8);
            #pragma unroll
            for (int j = 0; j < 2; j++)
                acc[i][j] = __builtin_amdgcn_mfma_f32_16x16x32_bf16(bq[j], aq, acc[i][j], 0, 0, 0);
        }
    }
    #pragma unroll
    for (int i = 0; i < 3; i++) {
        int u = i * 16 + l15;
        if (u < U) {
            int l = top[bh * U + u];
            float* dst = aout + ((size_t)(b * LL + l)) * DD;
            #pragma unroll
            for (int j = 0; j < 2; j++) {
                int n = n0 + wave * 32 + j * 16 + kq * 4;
                atomicAdd(dst + n,     acc[i][j][0]);
                atomicAdd(dst + n + 1, acc[i][j][1]);
                atomicAdd(dst + n + 2, acc[i][j][2]);
                atomicAdd(dst + n + 3, acc[i][j][3]);
            }
        }
    }
}

// ------------- LN1: x1 = LN(x + aout) -> bf16 ------------------------------
__global__ __launch_bounds__(256) void ln1_k(
    const float* __restrict__ x, const float* __restrict__ aout,
    const float* __restrict__ g, const float* __restrict__ bb,
    __bf16* __restrict__ x1h)
{
    __shared__ float red[256];
    int row = blockIdx.x, tid = threadIdx.x;
    size_t base = (size_t)row * DD;
    float h0 = x[base + tid] + aout[base + tid];
    float h1 = x[base + 256 + tid] + aout[base + 256 + tid];
    red[tid] = h0 + h1; __syncthreads();
    for (int s = 128; s > 0; s >>= 1) { if (tid < s) red[tid] += red[tid + s]; __syncthreads(); }
    float mean = red[0] * (1.0f / DD); __syncthreads();
    float d0 = h0 - mean, d1 = h1 - mean;
    red[tid] = d0 * d0 + d1 * d1; __syncthreads();
    for (int s = 128; s > 0; s >>= 1) { if (tid < s) red[tid] += red[tid + s]; __syncthreads(); }
    float rstd = rsqrtf(red[0] * (1.0f / DD) + 1e-5f);
    x1h[base + tid]       = (__bf16)(d0 * rstd * g[tid] + bb[tid]);
    x1h[base + 256 + tid] = (__bf16)(d1 * rstd * g[256 + tid] + bb[256 + tid]);
}

// ------------- LN2: out = LN(x1 + ffn2 + b2) -> fp32 -----------------------
__global__ __launch_bounds__(256) void ln2_k(
    const __bf16* __restrict__ x1h, const float* __restrict__ f2o,
    const float* __restrict__ c2b,
    const float* __restrict__ g, const float* __restrict__ bb,
    float* __restrict__ out)
{
    __shared__ float red[256];
    int row = blockIdx.x, tid = threadIdx.x;
    size_t base = (size_t)row * DD;
    float h0 = (float)x1h[base + tid] + f2o[base + tid] + c2b[tid];
    float h1 = (float)x1h[base + 256 + tid] + f2o[base + 256 + tid] + c2b[256 + tid];
    red[tid] = h0 + h1; __syncthreads();
    for (int s = 128; s > 0; s >>= 1) { if (tid < s) red[tid] += red[tid + s]; __syncthreads(); }
    float mean = red[0] * (1.0f / DD); __syncthreads();
    float d0 = h0 - mean, d1 = h1 - mean;
    red[tid] = d0 * d0 + d1 * d1; __syncthreads();
    for (int s = 128; s > 0; s >>= 1) { if (tid < s) red[tid] += red[tid + s]; __syncthreads(); }
    float rstd = rsqrtf(red[0] * (1.0f / DD) + 1e-5f);
    out[base + tid]       = d0 * rstd * g[tid] + bb[tid];
    out[base + 256 + tid] = d1 * rstd * g[256 + tid] + bb[256 + tid];
}

// ---------------------------------------------------------------------------
extern "C" void kernel_launch(void* const* d_in, const int* in_sizes, int n_in,
                              void* d_out, int out_size, void* d_ws, size_t ws_size,
                              hipStream_t stream)
{
    const float* x   = (const float*)d_in[0];
    const float* Wq  = (const float*)d_in[1];
    const float* Wk  = (const float*)d_in[2];
    const float* Wv  = (const float*)d_in[3];
    const float* Wo  = (const float*)d_in[4];
    const float* g1  = (const float*)d_in[5];
    const float* b1  = (const float*)d_in[6];
    const float* c1w = (const float*)d_in[7];
    const float* c1b = (const float*)d_in[8];
    const float* c2w = (const float*)d_in[9];
    const float* c2b = (const float*)d_in[10];
    const float* g2  = (const float*)d_in[11];
    const float* b2  = (const float*)d_in[12];
    const int* sidx  = (const int*)d_in[13];
    float* out       = (float*)d_out;

    const int U = in_sizes[13] / LL;            // 40
    const int M = BB * LL;                       // 8192

    char* ws = (char*)d_ws;
    const size_t MB = (size_t)1 << 20;
    float*  Q    = (float*)(ws + 0);
    float*  Kb   = (float*)(ws + 16 * MB);
    __bf16* V    = (__bf16*)(ws + 32 * MB);
    __bf16* xhi  = (__bf16*)(ws + 40 * MB);
    __bf16* xlo  = (__bf16*)(ws + 48 * MB);
    float*  S    = (float*)(ws + 40 * MB);          // 32*48*2048*4 = 12.6 MB
    __bf16* wb   = (__bf16*)(ws + 56 * MB);
    __bf16* c1wb = (__bf16*)(ws + 59 * MB);
    __bf16* c2wb = (__bf16*)(ws + 61 * MB);
    float*  Mo   = (float*)(ws + 63 * MB);
    float*  upd  = (float*)(ws + 63 * MB + 256 * 1024);
    float*  Vm   = (float*)(ws + 63 * MB + 576 * 1024);
    int*    top  = (int*)  (ws + 63 * MB + 584 * 1024);
    __bf16* qred = (__bf16*)(ws + 63 * MB + 592 * 1024);  // 192K
    __bf16* aw   = (__bf16*)(ws + 63 * MB + 784 * 1024);  // 192K
    float*  basep= (float*)(ws + 63 * MB + 976 * 1024);   // 8K
    float*  aout = Q;                               // alias: Q dead after gather_qred
    float*  f2o  = Q;                               // alias: aout dead after ln1
    __bf16* ych  = (__bf16*)(ws + 16 * MB);         // FFN intermediate (32 MB region)
    __bf16* x1h  = xlo;                             // alias: S/P dead by ln1
    (void)ws_size; (void)n_in; (void)out_size;

    const size_t SZ = (size_t)DD * DD;
    __bf16* WqkHi = wb;                  // [WqT; WkT] hi, 1024 rows
    __bf16* WqkLo = wb + 2 * SZ;         // [WqT; WkT] lo
    __bf16* WvT   = wb + 4 * SZ;
    __bf16* WoT   = wb + 5 * SZ;

    // 1) weight prep + input split-cast
    prep_w<<<dim3(DD * DD / 256, 1, 4), 256, 0, stream>>>(Wq, Wk, Wv, Wo, wb);
    cast_cw<<<dim3(FF * DD / 256, 1, 2), 256, 0, stream>>>(c1w, c2w, c1wb, c2wb);
    split_cast_x<<<BB * LL * DD / 256, 256, 0, stream>>>(x, xhi, xlo);

    // 2) fused Q+K split-precision projection (B = [WqT;WkT], 2048 blocks =
    //    5 blocks/CU LDS-capped); V bf16 via 64x64 tile (1024 blocks = 4/CU)
    dim3 gqk((2 * DD) / 64, M / 64);
    gemm_split_qk<<<gqk, 256, 0, stream>>>(xhi, xlo, WqkHi, WqkLo, Q, Kb, M, DD);
    dim3 gsq(DD / 64, M / 64);
    gemm_sq64<4, 0, false, true ><<<gsq, 256, 0, stream>>>(xhi, WvT, nullptr, V, M, DD, DD);

    // 3) sampled sparsity measure M, top-k, V mean (+ zero upd for pv atomics)
    calc_m<<<BB * LL, 256, 0, stream>>>(Q, Kb, sidx, Mo, U);
    zero_upd<<<(BB * HH * U * DKK + 255) / 256, 256, 0, stream>>>(upd, BB * HH * U * DKK);
    topk_k<<<BB * HH, 256, 0, stream>>>(Mo, top, U);
    vmean_k<<<BB * HH, 256, 0, stream>>>(V, Vm);

    // 4) attention: gather -> batched MFMA S -> softmax(in-place bf16 P) -> PV
    gather_qred<<<dim3(48 * DKK / 256, BB * HH), 256, 0, stream>>>(Q, top, qred, U);
    gemm_s<<<dim3(LL / 128, BB * HH), 256, 0, stream>>>(qred, Kb, S);
    softmax_p<<<BB * HH * U, 256, 0, stream>>>(S, U);
    pv_k<<<dim3(U / 4, 4, BB * HH), 256, 0, stream>>>(S, V, upd, U);

    // 5) out-projection via base + rank-U correction (Wo-GEMM eliminated)
    base_k<<<dim3(16, BB), 256, 0, stream>>>(Vm, Wo, basep);
    aw_prep<<<BB * HH, 256, 0, stream>>>(upd, Vm, aw, U);
    aout_init<<<M * DD / 256, 256, 0, stream>>>(basep, aout);
    corr_gemm<<<dim3(DD / 128, BB * HH), 256, 0, stream>>>(aw, WoT, top, aout, U);

    // 6) LN1 -> x1h bf16 (aliases xlo; S/P dead)
    ln1_k<<<M, 256, 0, stream>>>(x, aout, g1, b1, x1h);

    // 7) FFN: gelu(x1 @ c1w^T + c1b) -> ych bf16 (BM=128, 1024 blocks = 4/CU);
    //    ych @ c2w^T -> f2o (64x64 tile: 1024 blocks = 4 blocks/CU)
    gemm_mfma<3, 1, true,  true ><<<dim3(FF / 128, M / 128), 256, 0, stream>>>(x1h, c1wb, c1b, ych, M, FF, DD);
    gemm_sq64<4, 0, false, false><<<gsq, 256, 0, stream>>>(ych, c2wb, nullptr, f2o, M, DD, FF);

    // 8) LN2 -> fp32 output
    ln2_k<<<M, 256, 0, stream>>>(x1h, f2o, c2b, g2, b2, out);
}

// Round 15
// 378.436 us; speedup vs baseline: 1.1352x; 1.0053x over previous
//
#include <hip/hip_runtime.h>
#include <hip/hip_bf16.h>

// Problem constants (B=4, L=2048, D=512, H=8, DK=64, FF=2048, U=40)
#define BB 4
#define LL 2048
#define DD 512
#define HH 8
#define DKK 64
#define FF 2048

typedef __bf16  bf16x8  __attribute__((ext_vector_type(8)));
typedef float   floatx4 __attribute__((ext_vector_type(4)));

// async 16B global->LDS copy (global_load_lds_dwordx4)
__device__ __forceinline__ void async_cp16(const void* g, void* l) {
    __builtin_amdgcn_global_load_lds(
        (const __attribute__((address_space(1))) unsigned int*)g,
        (__attribute__((address_space(3))) unsigned int*)l,
        16, 0, 0);
}

// exact-grade GELU: A&S 7.1.26 erf, |err| < 1.5e-7 (fp32-exact at our scale).
__device__ __forceinline__ float gelu_f(float v) {
    float z  = v * 0.70710678118654752f;
    float az = fabsf(z);
    float t  = __builtin_amdgcn_rcpf(1.0f + 0.3275911f * az);
    float p  = ((((1.061405429f * t - 1.453152027f) * t + 1.421413741f) * t
                 - 0.284496736f) * t + 0.254829592f) * t;
    float e  = __expf(-z * z);
    float er = 1.0f - p * e;
    er = (z < 0.0f) ? -er : er;
    return 0.5f * v * (1.0f + er);
}

// ---------- prep: transpose 512x512 fp32 -> bf16 (N,K) -----------------------
// Layout: [0,SZ) WqThi | [SZ,2SZ) WkThi | [2SZ,3SZ) WqTlo | [3SZ,4SZ) WkTlo |
//         [4SZ,5SZ) WvT | [5SZ,6SZ) WoT
__global__ __launch_bounds__(256) void prep_w(
    const float* __restrict__ Wq, const float* __restrict__ Wk,
    const float* __restrict__ Wv, const float* __restrict__ Wo,
    __bf16* __restrict__ wb)
{
    const size_t SZ = (size_t)DD * DD;
    int z = blockIdx.z;
    const float* s = (z == 0) ? Wq : (z == 1) ? Wk : (z == 2) ? Wv : Wo;
    __bf16* hi; __bf16* lo = nullptr;
    if (z == 0)      { hi = wb;          lo = wb + 2 * SZ; }
    else if (z == 1) { hi = wb + SZ;     lo = wb + 3 * SZ; }
    else if (z == 2) { hi = wb + 4 * SZ; }
    else             { hi = wb + 5 * SZ; }
    int idx = blockIdx.x * 256 + threadIdx.x;   // 0..512*512-1
    int k = idx >> 9, n = idx & 511;
    float v = s[idx];
    __bf16 h = (__bf16)v;
    hi[(size_t)n * DD + k] = h;
    if (lo) lo[(size_t)n * DD + k] = (__bf16)(v - (float)h);
}

// ---------- cast conv weights fp32 (N,K) -> bf16 -----------------------------
__global__ __launch_bounds__(256) void cast_cw(
    const float* __restrict__ c1w, const float* __restrict__ c2w,
    __bf16* __restrict__ d1, __bf16* __restrict__ d2)
{
    const float* s = blockIdx.z ? c2w : c1w;
    __bf16* d = blockIdx.z ? d2 : d1;
    int idx = blockIdx.x * 256 + threadIdx.x;   // 0..FF*DD-1
    d[idx] = (__bf16)s[idx];
}

// ---------- split-cast x fp32 -> bf16 hi + lo --------------------------------
__global__ __launch_bounds__(256) void split_cast_x(
    const float* __restrict__ x, __bf16* __restrict__ xhi, __bf16* __restrict__ xlo)
{
    int idx = blockIdx.x * 256 + threadIdx.x;
    float v = x[idx];
    __bf16 h = (__bf16)v;
    xhi[idx] = h;
    xlo[idx] = (__bf16)(v - (float)h);
}

// ---------- MFMA GEMM, 128x128 tile (FFN1: 1024 blocks = 4/CU) ---------------
template<int NB, int ACT, bool BIAS, bool OUT_BF16>
__global__ __launch_bounds__(256) void gemm_mfma(
    const __bf16* __restrict__ A, const __bf16* __restrict__ B,
    const float* __restrict__ bias, void* __restrict__ Cv,
    int M, int N, int K)
{
    __shared__ __bf16 As[NB][128 * 32];
    __shared__ __bf16 Bs[NB][128 * 32];
    const int tid = threadIdx.x;
    const int wave = tid >> 6, lane = tid & 63;
    const int gx = gridDim.x;
    const int nwg = gx * gridDim.y;
    const int hw = blockIdx.y * gx + blockIdx.x;
    const int virt = ((nwg & 7) == 0) ? ((hw & 7) * (nwg >> 3) + (hw >> 3)) : hw;
    const int m0 = (virt / gx) * 128, n0 = (virt % gx) * 128;
    const int wm = (wave >> 1) * 64, wn = (wave & 1) * 64;
    const int l15 = lane & 15, kq = lane >> 4;

    auto stage = [&](int buf, int k0) {           // 4 vmem insts per thread
        #pragma unroll
        for (int p = 0; p < 2; p++) {
            int c = p * 256 + tid;                // 16B chunk id 0..511
            int row = c >> 2;
            int col = ((c & 3) ^ ((row >> 1) & 3)) * 8;   // inverse-swizzled src
            async_cp16(A + (size_t)(m0 + row) * K + k0 + col, &As[buf][c * 8]);
            async_cp16(B + (size_t)(n0 + row) * K + k0 + col, &Bs[buf][c * 8]);
        }
    };

    floatx4 acc[4][4] = {};

    const int nt = K >> 5;
    #pragma unroll
    for (int pt = 0; pt < NB - 1; pt++) stage(pt, pt << 5);
    asm volatile("s_waitcnt vmcnt(4)"  ::: "memory");
    __builtin_amdgcn_s_barrier();
    int bi = 0;                                   // buffer of current tile
    for (int t = 0; t < nt; t++) {
        if (t + NB - 1 < nt) {
            int b2 = bi + NB - 1; if (b2 >= NB) b2 -= NB;
            stage(b2, (t + NB - 1) << 5);
        }
        asm volatile("" ::: "memory");
        bf16x8 af[4], bfr[4];
        #pragma unroll
        for (int i = 0; i < 4; i++) {
            int ra = wm + i * 16 + l15;
            af[i] = *(const bf16x8*)(&As[bi][ra * 32 + ((kq ^ ((ra >> 1) & 3)) << 3)]);
        }
        #pragma unroll
        for (int j = 0; j < 4; j++) {
            int rb = wn + j * 16 + l15;
            bfr[j] = *(const bf16x8*)(&Bs[bi][rb * 32 + ((kq ^ ((rb >> 1) & 3)) << 3)]);
        }
        #pragma unroll
        for (int i = 0; i < 4; i++)
            #pragma unroll
            for (int j = 0; j < 4; j++)
                acc[i][j] = __builtin_amdgcn_mfma_f32_16x16x32_bf16(bfr[j], af[i], acc[i][j], 0, 0, 0);
        asm volatile("" ::: "memory");
        if (t + 1 < nt) {                         // wait: tile t+1 landed
            int c = nt - 2 - t; if (c > NB - 2) c = NB - 2;
            if (c >= 2)      asm volatile("s_waitcnt vmcnt(8)"  ::: "memory");
            else if (c == 1) asm volatile("s_waitcnt vmcnt(4)"  ::: "memory");
            else             asm volatile("s_waitcnt vmcnt(0)"  ::: "memory");
            __builtin_amdgcn_s_barrier();
        }
        if (++bi == NB) bi = 0;
    }
    #pragma unroll
    for (int i = 0; i < 4; i++) {
        int m = m0 + wm + i * 16 + l15;
        #pragma unroll
        for (int j = 0; j < 4; j++) {
            int n = n0 + wn + j * 16 + kq * 4;
            floatx4 v4 = acc[i][j];
            if (BIAS) {
                float4 bv = *(const float4*)&bias[n];
                v4[0] += bv.x; v4[1] += bv.y; v4[2] += bv.z; v4[3] += bv.w;
            }
            if (ACT == 1) {
                v4[0] = gelu_f(v4[0]); v4[1] = gelu_f(v4[1]);
                v4[2] = gelu_f(v4[2]); v4[3] = gelu_f(v4[3]);
            }
            if (OUT_BF16) {
                union { __bf16 b[4]; uint2 u; } pk;
                pk.b[0] = (__bf16)v4[0]; pk.b[1] = (__bf16)v4[1];
                pk.b[2] = (__bf16)v4[2]; pk.b[3] = (__bf16)v4[3];
                *(uint2*)((__bf16*)Cv + (size_t)m * N + n) = pk.u;
            } else {
                *(float4*)((float*)Cv + (size_t)m * N + n) = *(float4*)&v4;
            }
        }
    }
}

// ---------- MFMA GEMM, 64x64 tile (FFN2: 1024 blocks = 4/CU) -----------------
template<int NB, int ACT, bool BIAS, bool OUT_BF16>
__global__ __launch_bounds__(256) void gemm_sq64(
    const __bf16* __restrict__ A, const __bf16* __restrict__ B,
    const float* __restrict__ bias, void* __restrict__ Cv,
    int M, int N, int K)
{
    __shared__ __bf16 As[NB][64 * 32];
    __shared__ __bf16 Bs[NB][64 * 32];
    const int tid = threadIdx.x;
    const int wave = tid >> 6, lane = tid & 63;
    const int gx = gridDim.x;
    const int nwg = gx * gridDim.y;
    const int hw = blockIdx.y * gx + blockIdx.x;
    const int virt = ((nwg & 7) == 0) ? ((hw & 7) * (nwg >> 3) + (hw >> 3)) : hw;
    const int m0 = (virt / gx) * 64, n0 = (virt % gx) * 64;
    const int wm = (wave >> 1) * 32, wn = (wave & 1) * 32;
    const int l15 = lane & 15, kq = lane >> 4;

    auto stage = [&](int buf, int k0) {           // 2 vmem insts per thread
        int c = tid;                              // 256 chunks = 64 rows x 4
        int row = c >> 2;
        int col = ((c & 3) ^ ((row >> 1) & 3)) * 8;
        async_cp16(A + (size_t)(m0 + row) * K + k0 + col, &As[buf][c * 8]);
        async_cp16(B + (size_t)(n0 + row) * K + k0 + col, &Bs[buf][c * 8]);
    };

    floatx4 acc[2][2] = {};

    const int nt = K >> 5;
    #pragma unroll
    for (int pt = 0; pt < NB - 1; pt++) stage(pt, pt << 5);
    asm volatile("s_waitcnt vmcnt(%0)" :: "i"(2 * (NB - 2)) : "memory");
    __builtin_amdgcn_s_barrier();
    int bi = 0;
    for (int t = 0; t < nt; t++) {
        if (t + NB - 1 < nt) {
            int b2 = bi + NB - 1; if (b2 >= NB) b2 -= NB;
            stage(b2, (t + NB - 1) << 5);
        }
        asm volatile("" ::: "memory");
        bf16x8 af[2], bfr[2];
        #pragma unroll
        for (int i = 0; i < 2; i++) {
            int ra = wm + i * 16 + l15;
            af[i] = *(const bf16x8*)(&As[bi][ra * 32 + ((kq ^ ((ra >> 1) & 3)) << 3)]);
        }
        #pragma unroll
        for (int j = 0; j < 2; j++) {
            int rb = wn + j * 16 + l15;
            bfr[j] = *(const bf16x8*)(&Bs[bi][rb * 32 + ((kq ^ ((rb >> 1) & 3)) << 3)]);
        }
        #pragma unroll
        for (int i = 0; i < 2; i++)
            #pragma unroll
            for (int j = 0; j < 2; j++)
                acc[i][j] = __builtin_amdgcn_mfma_f32_16x16x32_bf16(bfr[j], af[i], acc[i][j], 0, 0, 0);
        asm volatile("" ::: "memory");
        if (t + 1 < nt) {
            int c = nt - 2 - t; if (c > NB - 2) c = NB - 2;
            if (c >= 3)      asm volatile("s_waitcnt vmcnt(6)" ::: "memory");
            else if (c == 2) asm volatile("s_waitcnt vmcnt(4)" ::: "memory");
            else if (c == 1) asm volatile("s_waitcnt vmcnt(2)" ::: "memory");
            else             asm volatile("s_waitcnt vmcnt(0)" ::: "memory");
            __builtin_amdgcn_s_barrier();
        }
        if (++bi == NB) bi = 0;
    }
    #pragma unroll
    for (int i = 0; i < 2; i++) {
        int m = m0 + wm + i * 16 + l15;
        #pragma unroll
        for (int j = 0; j < 2; j++) {
            int n = n0 + wn + j * 16 + kq * 4;
            floatx4 v4 = acc[i][j];
            if (BIAS) {
                float4 bv = *(const float4*)&bias[n];
                v4[0] += bv.x; v4[1] += bv.y; v4[2] += bv.z; v4[3] += bv.w;
            }
            if (ACT == 1) {
                v4[0] = gelu_f(v4[0]); v4[1] = gelu_f(v4[1]);
                v4[2] = gelu_f(v4[2]); v4[3] = gelu_f(v4[3]);
            }
            if (OUT_BF16) {
                union { __bf16 b[4]; uint2 u; } pk;
                pk.b[0] = (__bf16)v4[0]; pk.b[1] = (__bf16)v4[1];
                pk.b[2] = (__bf16)v4[2]; pk.b[3] = (__bf16)v4[3];
                *(uint2*)((__bf16*)Cv + (size_t)m * N + n) = pk.u;
            } else {
                *(float4*)((float*)Cv + (size_t)m * N + n) = *(float4*)&v4;
            }
        }
    }
}

// ---------- fused Q+K+V projection, 64x64 tile -------------------------------
// B-columns 0..1023: split-precision (Ah+Al)(Bh+Bl)^T with B = [WqT;WkT],
// fp32 out to Q/Kb. B-columns 1024..1535: plain bf16 xhi @ WvT^T, packed-bf16
// out to V (block-uniform branch; V blocks stage 2 arrays and run 1/3 MFMA).
// Extends r14's fused QK (proven +): A (x) staged ONCE for all three outputs.
// Per-output MFMA order identical to the previous kernels -> bit-identical.
__global__ __launch_bounds__(256) void gemm_split_qkv(
    const __bf16* __restrict__ Ah, const __bf16* __restrict__ Al,
    const __bf16* __restrict__ Bqk_h, const __bf16* __restrict__ Bqk_l,
    const __bf16* __restrict__ Bv,
    float* __restrict__ Cq, float* __restrict__ Ck, __bf16* __restrict__ Cv,
    int M, int K)
{
    __shared__ __bf16 Ahs[2][64 * 32];
    __shared__ __bf16 Als[2][64 * 32];
    __shared__ __bf16 Bhs[2][64 * 32];
    __shared__ __bf16 Bls[2][64 * 32];
    const int tid = threadIdx.x;
    const int wave = tid >> 6, lane = tid & 63;
    const int gx = gridDim.x;                     // 24
    const int nwg = gx * gridDim.y;
    const int hw = blockIdx.y * gx + blockIdx.x;
    const int virt = ((nwg & 7) == 0) ? ((hw & 7) * (nwg >> 3) + (hw >> 3)) : hw;
    const int m0 = (virt / gx) * 64, n0 = (virt % gx) * 64;
    const int wm = (wave >> 1) * 32, wn = (wave & 1) * 32;
    const int l15 = lane & 15, kq = lane >> 4;
    const bool isV = (n0 >= 2 * DD);
    const __bf16* BhP = isV ? Bv : Bqk_h;
    const int nb0 = isV ? (n0 - 2 * DD) : n0;

    floatx4 acc[2][2] = {};
    const int nt = K >> 5;
    int bi = 0;

    if (!isV) {
        auto stage = [&](int buf, int k0) {       // 4 vmem insts per thread
            int c = tid;
            int row = c >> 2;
            int col = ((c & 3) ^ ((row >> 1) & 3)) * 8;
            size_t goA = (size_t)(m0 + row) * K + k0 + col;
            size_t goB = (size_t)(nb0 + row) * K + k0 + col;
            async_cp16(Ah + goA, &Ahs[buf][c * 8]);
            async_cp16(Al + goA, &Als[buf][c * 8]);
            async_cp16(BhP + goB, &Bhs[buf][c * 8]);
            async_cp16(Bqk_l + goB, &Bls[buf][c * 8]);
        };
        stage(0, 0);
        asm volatile("s_waitcnt vmcnt(0)" ::: "memory");
        __builtin_amdgcn_s_barrier();
        for (int t = 0; t < nt; t++) {
            if (t + 1 < nt) stage(bi ^ 1, (t + 1) << 5);
            asm volatile("" ::: "memory");
            bf16x8 ah[2], al[2], bh[2], bl[2];
            #pragma unroll
            for (int i = 0; i < 2; i++) {
                int ra = wm + i * 16 + l15;
                int off = ra * 32 + ((kq ^ ((ra >> 1) & 3)) << 3);
                ah[i] = *(const bf16x8*)(&Ahs[bi][off]);
                al[i] = *(const bf16x8*)(&Als[bi][off]);
            }
            #pragma unroll
            for (int j = 0; j < 2; j++) {
                int rb = wn + j * 16 + l15;
                int off = rb * 32 + ((kq ^ ((rb >> 1) & 3)) << 3);
                bh[j] = *(const bf16x8*)(&Bhs[bi][off]);
                bl[j] = *(const bf16x8*)(&Bls[bi][off]);
            }
            #pragma unroll
            for (int i = 0; i < 2; i++)
                #pragma unroll
                for (int j = 0; j < 2; j++) {
                    acc[i][j] = __builtin_amdgcn_mfma_f32_16x16x32_bf16(bh[j], ah[i], acc[i][j], 0, 0, 0);
                    acc[i][j] = __builtin_amdgcn_mfma_f32_16x16x32_bf16(bl[j], ah[i], acc[i][j], 0, 0, 0);
                    acc[i][j] = __builtin_amdgcn_mfma_f32_16x16x32_bf16(bh[j], al[i], acc[i][j], 0, 0, 0);
                }
            asm volatile("" ::: "memory");
            if (t + 1 < nt) {
                asm volatile("s_waitcnt vmcnt(0)" ::: "memory");
                __builtin_amdgcn_s_barrier();
            }
            bi ^= 1;
        }
        float* C = (n0 < DD) ? Cq : Ck;
        const int nc0 = n0 & (DD - 1);
        #pragma unroll
        for (int i = 0; i < 2; i++) {
            int m = m0 + wm + i * 16 + l15;
            #pragma unroll
            for (int j = 0; j < 2; j++) {
                int n = nc0 + wn + j * 16 + kq * 4;
                *(float4*)(C + (size_t)m * DD + n) = *(float4*)&acc[i][j];
            }
        }
    } else {
        auto stageV = [&](int buf, int k0) {      // 2 vmem insts per thread
            int c = tid;
            int row = c >> 2;
            int col = ((c & 3) ^ ((row >> 1) & 3)) * 8;
            async_cp16(Ah + (size_t)(m0 + row) * K + k0 + col, &Ahs[buf][c * 8]);
            async_cp16(BhP + (size_t)(nb0 + row) * K + k0 + col, &Bhs[buf][c * 8]);
        };
        stageV(0, 0);
        asm volatile("s_waitcnt vmcnt(0)" ::: "memory");
        __builtin_amdgcn_s_barrier();
        for (int t = 0; t < nt; t++) {
            if (t + 1 < nt) stageV(bi ^ 1, (t + 1) << 5);
            asm volatile("" ::: "memory");
            bf16x8 ah[2], bh[2];
            #pragma unroll
            for (int i = 0; i < 2; i++) {
                int ra = wm + i * 16 + l15;
                ah[i] = *(const bf16x8*)(&Ahs[bi][ra * 32 + ((kq ^ ((ra >> 1) & 3)) << 3)]);
            }
            #pragma unroll
            for (int j = 0; j < 2; j++) {
                int rb = wn + j * 16 + l15;
                bh[j] = *(const bf16x8*)(&Bhs[bi][rb * 32 + ((kq ^ ((rb >> 1) & 3)) << 3)]);
            }
            #pragma unroll
            for (int i = 0; i < 2; i++)
                #pragma unroll
                for (int j = 0; j < 2; j++)
                    acc[i][j] = __builtin_amdgcn_mfma_f32_16x16x32_bf16(bh[j], ah[i], acc[i][j], 0, 0, 0);
            asm volatile("" ::: "memory");
            if (t + 1 < nt) {
                asm volatile("s_waitcnt vmcnt(0)" ::: "memory");
                __builtin_amdgcn_s_barrier();
            }
            bi ^= 1;
        }
        #pragma unroll
        for (int i = 0; i < 2; i++) {
            int m = m0 + wm + i * 16 + l15;
            #pragma unroll
            for (int j = 0; j < 2; j++) {
                int n = nb0 + wn + j * 16 + kq * 4;
                union { __bf16 b[4]; uint2 u; } pk;
                pk.b[0] = (__bf16)acc[i][j][0]; pk.b[1] = (__bf16)acc[i][j][1];
                pk.b[2] = (__bf16)acc[i][j][2]; pk.b[3] = (__bf16)acc[i][j][3];
                *(uint2*)(Cv + (size_t)m * DD + n) = pk.u;
            }
        }
    }
}

// ------------- M[b,h,l] = max_s(q·k_s) - sum_s(q·k_s)/L  (sampled) ---------
__device__ __forceinline__ float dpp_sum16(float p) {
    int t;
    t = __builtin_amdgcn_update_dpp(0, __float_as_int(p), 0xB1,  0xF, 0xF, true); // quad_perm [1,0,3,2]
    p += __int_as_float(t);
    t = __builtin_amdgcn_update_dpp(0, __float_as_int(p), 0x4E,  0xF, 0xF, true); // quad_perm [2,3,0,1]
    p += __int_as_float(t);
    t = __builtin_amdgcn_update_dpp(0, __float_as_int(p), 0x141, 0xF, 0xF, true); // row_half_mirror
    p += __int_as_float(t);
    t = __builtin_amdgcn_update_dpp(0, __float_as_int(p), 0x140, 0xF, 0xF, true); // row_mirror
    p += __int_as_float(t);
    return p;
}

__global__ __launch_bounds__(256) void calc_m(
    const float* __restrict__ Q, const float* __restrict__ Kb,
    const int* __restrict__ sidx, float* __restrict__ Mo, int U)
{
    __shared__ int   js[64];
    __shared__ float red_mx[2][HH];
    __shared__ float red_sm[2][HH];
    int i = blockIdx.x;
    int b = i & 3, l = i >> 2;
    int tid = threadIdx.x;
    if (tid < U) js[tid] = sidx[l * U + tid];
    int e    = (tid & 127) * 4;          // element index within 512-wide row
    int slot = tid >> 7;                 // 0/1: even/odd samples
    const float* qr = Q + ((size_t)(b * LL + l) * DD);
    float4 q = *(const float4*)(qr + e);
    const float* kbase = Kb + ((size_t)b * LL) * DD + e;
    __syncthreads();
    float mx = -1e30f, sm = 0.f;
    for (int s = slot; s < U; s += 2) {
        int j = js[s];
        float4 kv = *(const float4*)(kbase + (size_t)j * DD);
        float p = q.x * kv.x + q.y * kv.y + q.z * kv.z + q.w * kv.w;
        p = dpp_sum16(p);
        mx = fmaxf(mx, p);
        sm += p;
    }
    if ((tid & 15) == 0) {
        int head = (tid >> 4) & 7;
        red_mx[slot][head] = mx;
        red_sm[slot][head] = sm;
    }
    __syncthreads();
    if (tid < HH) {
        float m2 = fmaxf(red_mx[0][tid], red_mx[1][tid]);
        float s2 = red_sm[0][tid] + red_sm[1][tid];
        Mo[((size_t)(b * HH + tid)) * LL + l] = m2 - s2 * (1.0f / (float)LL);
    }
}

// ------------- radix-select top-40 per (b,h) row of M ----------------------
__global__ __launch_bounds__(256) void topk_k(
    const float* __restrict__ Mo, int* __restrict__ top, int U)
{
    __shared__ unsigned int hist[256];
    __shared__ unsigned int wsum[4];
    __shared__ unsigned int bc[2];
    __shared__ int ties[LL];
    __shared__ int cnt2[2];
    int bh = blockIdx.x, tid = threadIdx.x;
    int lane = tid & 63, w = tid >> 6;

    unsigned int my[8];
    #pragma unroll
    for (int i = 0; i < 8; i++) {
        unsigned int u = __float_as_uint(Mo[(size_t)bh * LL + tid + i * 256]);
        my[i] = u ^ ((u >> 31) ? 0xFFFFFFFFu : 0x80000000u);  // order-preserving
    }

    unsigned int prefix = 0, pmask = 0;
    unsigned int need = (unsigned int)U;
    unsigned int above = 0;

    for (int pass = 0; pass < 4; pass++) {
        int shift = 24 - pass * 8;
        hist[tid] = 0;
        __syncthreads();
        #pragma unroll
        for (int i = 0; i < 8; i++) {
            unsigned int u = my[i];
            if ((u & pmask) == prefix)
                atomicAdd(&hist[(u >> shift) & 255u], 1u);
        }
        __syncthreads();
        unsigned int h = hist[tid];
        #pragma unroll
        for (int off = 1; off < 64; off <<= 1) {
            unsigned int o = __shfl_down(h, off);
            if (lane + off < 64) h += o;
        }
        if (lane == 0) wsum[w] = h;
        __syncthreads();
        unsigned int tail = 0;
        #pragma unroll
        for (int w2 = 1; w2 < 4; w2++) if (w2 > w) tail += wsum[w2];
        h += tail;
        hist[tid] = h;
        __syncthreads();
        unsigned int St = h;
        unsigned int St1 = (tid < 255) ? hist[tid + 1] : 0u;
        if (St >= need && St1 < need) { bc[0] = (unsigned int)tid; bc[1] = St1; }
        __syncthreads();
        unsigned int dig = bc[0], abv = bc[1];
        above += abv;
        need -= abv;
        prefix |= dig << shift;
        pmask |= 0xFFu << shift;
        __syncthreads();
    }

    if (tid == 0) { cnt2[0] = 0; cnt2[1] = 0; }
    __syncthreads();
    #pragma unroll
    for (int i = 0; i < 8; i++) {
        unsigned int u = my[i];
        int idx = tid + i * 256;
        if (u > prefix) {
            int pos = atomicAdd(&cnt2[0], 1);
            top[bh * U + pos] = idx;
        } else if (u == prefix) {
            int pos = atomicAdd(&cnt2[1], 1);
            ties[pos] = idx;
        }
    }
    __syncthreads();
    int tcnt = cnt2[1];
    #pragma unroll
    for (int i = 0; i < 8; i++) {
        unsigned int u = my[i];
        if (u == prefix) {
            int idx = tid + i * 256;
            int rank = 0;
            for (int j = 0; j < tcnt; j++) rank += (ties[j] < idx) ? 1 : 0;
            if (rank < (int)need) top[bh * U + (int)above + rank] = idx;
        }
    }
}

// ------------- Vmean[b,h,d] (V bf16), 256 threads/block --------------------
__global__ __launch_bounds__(256) void vmean_k(
    const __bf16* __restrict__ V, float* __restrict__ Vm)
{
    __shared__ float osum[4][DKK];
    int bh = blockIdx.x;
    int b = bh >> 3, h = bh & 7;
    int tid = threadIdx.x, d = tid & 63, part = tid >> 6;
    const __bf16* vp = V + ((size_t)(b * LL + part * 512) * DD + h * DKK + d);
    float s = 0.f;
    for (int i = 0; i < 512; i++) s += (float)vp[(size_t)i * DD];
    osum[part][d] = s;
    __syncthreads();
    if (tid < DKK)
        Vm[bh * DKK + tid] = (osum[0][tid] + osum[1][tid] + osum[2][tid] + osum[3][tid]) * (1.0f / (float)LL);
}

// ------------- gather Q[top] -> qred[32][48][64] bf16, scaled by 1/8 -------
__global__ __launch_bounds__(256) void gather_qred(
    const float* __restrict__ Q, const int* __restrict__ top,
    __bf16* __restrict__ qred, int U)
{
    int bh = blockIdx.y;
    int b = bh >> 3, h = bh & 7;
    int e = blockIdx.x * 256 + threadIdx.x;   // 0..48*64-1
    int u = e >> 6, d = e & 63;
    float v = 0.f;
    if (u < U) {
        int l = top[bh * U + u];
        v = Q[((size_t)(b * LL + l) * DD + h * DKK) + d] * 0.125f;
    }
    qred[(size_t)bh * 48 * DKK + e] = (__bf16)v;
}

// ------------- batched S[bh][48][2048] = qred[bh] @ K[bh]^T (MFMA) ---------
__global__ __launch_bounds__(256) void gemm_s(
    const __bf16* __restrict__ qred, const float* __restrict__ Kb,
    float* __restrict__ S)
{
    __shared__ __bf16 Qs[2 * 48 * 32];    // 2 panels of BK=32
    __shared__ __bf16 Ks[2 * 128 * 32];
    int bh = blockIdx.y, nc = blockIdx.x;
    int b = bh >> 3, h = bh & 7, l0 = nc * 128;
    int tid = threadIdx.x;
    const unsigned int* qsrc = (const unsigned int*)(qred + (size_t)bh * 48 * DKK);
    unsigned int* qdst = (unsigned int*)Qs;
    #pragma unroll
    for (int t = 0; t < 6; t++) {
        int ui = tid + t * 256;            // 0..1535
        int u = ui >> 5, kp = ui & 31;
        int p = kp >> 4, kl2 = kp & 15;
        qdst[p * 768 + u * 16 + kl2] = qsrc[ui];
    }
    #pragma unroll
    for (int t = 0; t < 8; t++) {
        int fi = tid + t * 256;            // 0..2047
        int row = fi >> 4, k4 = fi & 15;
        int p = k4 >> 3, kl = (k4 & 7) * 4;
        float4 kv = *(const float4*)(Kb + ((size_t)(b * LL + l0 + row) * DD + h * DKK + k4 * 4));
        __bf16* dst = Ks + p * 128 * 32 + row * 32 + kl;
        dst[0] = (__bf16)kv.x; dst[1] = (__bf16)kv.y;
        dst[2] = (__bf16)kv.z; dst[3] = (__bf16)kv.w;
    }
    __syncthreads();
    int wave = tid >> 6, lane = tid & 63, l15 = lane & 15, kq = lane >> 4;
    floatx4 acc[3][2] = {};
    #pragma unroll
    for (int p = 0; p < 2; p++) {
        bf16x8 bq[2];
        #pragma unroll
        for (int j = 0; j < 2; j++)
            bq[j] = *(const bf16x8*)(Ks + p * 4096 + (wave * 32 + j * 16 + l15) * 32 + kq * 8);
        #pragma unroll
        for (int i = 0; i < 3; i++) {
            bf16x8 aq = *(const bf16x8*)(Qs + p * 1536 + (i * 16 + l15) * 32 + kq * 8);
            #pragma unroll
            for (int j = 0; j < 2; j++)
                acc[i][j] = __builtin_amdgcn_mfma_f32_16x16x32_bf16(bq[j], aq, acc[i][j], 0, 0, 0);
        }
    }
    // thread holds S[row][col..col+3]: row = i*16+l15, col = l0+wave*32+j*16+kq*4
    #pragma unroll
    for (int i = 0; i < 3; i++) {
        int row = i * 16 + l15;
        #pragma unroll
        for (int j = 0; j < 2; j++) {
            int col = l0 + wave * 32 + j * 16 + kq * 4;
            *(float4*)&S[((size_t)bh * 48 + row) * LL + col] = *(float4*)&acc[i][j];
        }
    }
}

// ------------- row softmax, in-place: S row fp32 -> P row bf16 -------------
__global__ __launch_bounds__(256) void softmax_p(float* __restrict__ S, int U)
{
    __shared__ float red[256];
    int row = blockIdx.x;              // 32*U rows
    int bh = row / U, u = row % U;
    float* sr = S + ((size_t)bh * 48 + u) * LL;
    int tid = threadIdx.x;
    float sc[8]; float mx = -1e30f;
    #pragma unroll
    for (int i = 0; i < 8; i++) { sc[i] = sr[tid + i * 256]; mx = fmaxf(mx, sc[i]); }
    red[tid] = mx; __syncthreads();
    for (int s = 128; s > 0; s >>= 1) { if (tid < s) red[tid] = fmaxf(red[tid], red[tid + s]); __syncthreads(); }
    mx = red[0]; __syncthreads();
    float se = 0.f;
    #pragma unroll
    for (int i = 0; i < 8; i++) { sc[i] = __expf(sc[i] - mx); se += sc[i]; }
    red[tid] = se; __syncthreads();
    for (int s = 128; s > 0; s >>= 1) { if (tid < s) red[tid] += red[tid + s]; __syncthreads(); }
    float inv = 1.0f / red[0];
    __bf16* pr = (__bf16*)sr;
    #pragma unroll
    for (int i = 0; i < 8; i++) pr[tid + i * 256] = (__bf16)(sc[i] * inv);
}

// ------------- zero upd (pv_k accumulates via atomicAdd) -------------------
__global__ __launch_bounds__(256) void zero_upd(float* __restrict__ upd, int n)
{
    int i = blockIdx.x * 256 + threadIdx.x;
    if (i < n) upd[i] = 0.f;
}

// ------------- upd[bh][u][d] += sum_{l in chunk} P[u][l] * V[b,h,l,d] ------
__global__ __launch_bounds__(256) void pv_k(
    const float* __restrict__ S, const __bf16* __restrict__ V,
    float* __restrict__ upd, int U)
{
    __shared__ __bf16 pls[4][512];        // 4 KB
    __shared__ float osum[16][4][DKK];    // 16 KB
    int uc = blockIdx.x, lc = blockIdx.y, bh = blockIdx.z;
    int b = bh >> 3, h = bh & 7, tid = threadIdx.x;
    #pragma unroll
    for (int t = 0; t < 4; t++) {
        int ui = tid + t * 256;          // 0..1023
        int up = ui >> 8, lw = ui & 255;
        ((unsigned int*)pls)[up * 256 + lw] =
            ((const unsigned int*)(S + ((size_t)bh * 48 + uc * 4 + up) * LL))[lc * 256 + lw];
    }
    __syncthreads();
    int d4 = tid & 15, part = tid >> 4;   // 16 parts of 32 l; d4 covers 4 d's
    const __bf16* vp = V + ((size_t)(b * LL + lc * 512 + part * 32)) * DD + h * DKK + d4 * 4;
    float a[4][4] = {};
    for (int i = 0; i < 32; i++) {
        union { uint2 u; __bf16 bb[4]; } cv;
        cv.u = *(const uint2*)(vp + (size_t)i * DD);
        float v0 = (float)cv.bb[0], v1 = (float)cv.bb[1];
        float v2 = (float)cv.bb[2], v3 = (float)cv.bb[3];
        int l = part * 32 + i;
        #pragma unroll
        for (int u2 = 0; u2 < 4; u2++) {
            float p = (float)pls[u2][l];
            a[u2][0] += p * v0; a[u2][1] += p * v1;
            a[u2][2] += p * v2; a[u2][3] += p * v3;
        }
    }
    #pragma unroll
    for (int u2 = 0; u2 < 4; u2++)
        #pragma unroll
        for (int j = 0; j < 4; j++)
            osum[part][u2][d4 * 4 + j] = a[u2][j];
    __syncthreads();
    int d = tid & 63, u2 = tid >> 6;
    float s = 0.f;
    #pragma unroll
    for (int p = 0; p < 16; p++) s += osum[p][u2][d];
    atomicAdd(&upd[((size_t)bh * U + uc * 4 + u2) * DKK + d], s);
}

// ------------- base[b][n] = cmean[b] . Wo[:,n]  (fp32, tiny) ---------------
__global__ __launch_bounds__(256) void base_k(
    const float* __restrict__ Vm, const float* __restrict__ Wo,
    float* __restrict__ base)
{
    __shared__ float cm[DD];
    __shared__ float part[8][32];
    int b = blockIdx.y, n0 = blockIdx.x * 32, tid = threadIdx.x;
    cm[tid] = Vm[b * DD + tid];
    cm[tid + 256] = Vm[b * DD + 256 + tid];
    __syncthreads();
    int n = n0 + (tid & 31), kg = tid >> 5;      // 8 k-groups of 64
    float s = 0.f;
    for (int k = kg * 64; k < kg * 64 + 64; k++) s += cm[k] * Wo[(size_t)k * DD + n];
    part[kg][tid & 31] = s;
    __syncthreads();
    if (tid < 32) {
        float t = 0.f;
        #pragma unroll
        for (int g = 0; g < 8; g++) t += part[g][tid];
        base[b * DD + n0 + tid] = t;
    }
}

// ------------- aout init: every row of batch b <- base[b] ------------------
__global__ __launch_bounds__(256) void aout_init(
    const float* __restrict__ base, float* __restrict__ aout)
{
    int idx = blockIdx.x * 256 + threadIdx.x;    // over B*L*512
    aout[idx] = base[((idx >> 20) << 9) + (idx & 511)];
}

// ------------- aw[bh][u48][d] = bf16(upd - Vm) -----------------------------
__global__ __launch_bounds__(256) void aw_prep(
    const float* __restrict__ upd, const float* __restrict__ Vm,
    __bf16* __restrict__ aw, int U)
{
    int bh = blockIdx.x, tid = threadIdx.x;
    #pragma unroll
    for (int t = 0; t < 12; t++) {
        int e = tid + t * 256;                   // 0..3071
        int u = e >> 6, d = e & 63;
        float v = (u < U) ? upd[((size_t)bh * U + u) * DKK + d] - Vm[bh * DKK + d] : 0.f;
        aw[(size_t)bh * 48 * DKK + e] = (__bf16)v;
    }
}

// ------------- corr GEMM + scatter-add: aout[b, top[u]] += aw @ Wo_h -------
__global__ __launch_bounds__(256) void corr_gemm(
    const __bf16* __restrict__ aw, const __bf16* __restrict__ WoT,
    const int* __restrict__ top, float* __restrict__ aout, int U)
{
    __shared__ __bf16 Qs[2 * 48 * 32];    // aw panels (BK=32)
    __shared__ __bf16 Ks[2 * 128 * 32];   // WoT-slice panels
    int bh = blockIdx.y, nc = blockIdx.x;
    int b = bh >> 3, h = bh & 7, n0 = nc * 128;
    int tid = threadIdx.x;
    const unsigned int* qsrc = (const unsigned int*)(aw + (size_t)bh * 48 * DKK);
    unsigned int* qdst = (unsigned int*)Qs;
    #pragma unroll
    for (int t = 0; t < 6; t++) {
        int ui = tid + t * 256;            // 0..1535
        int u = ui >> 5, kp = ui & 31;
        int p = kp >> 4, kl2 = kp & 15;
        qdst[p * 768 + u * 16 + kl2] = qsrc[ui];
    }
    const unsigned int* wsrc = (const unsigned int*)WoT;
    unsigned int* kdst = (unsigned int*)Ks;
    #pragma unroll
    for (int t = 0; t < 16; t++) {
        int ui = tid + t * 256;            // 0..4095
        int row = ui >> 5, c2 = ui & 31;
        int p = c2 >> 4, col2 = c2 & 15;
        kdst[p * 2048 + row * 16 + col2] = wsrc[(size_t)(n0 + row) * (DD / 2) + h * 32 + c2];
    }
    __syncthreads();
    int wave = tid >> 6, lane = tid & 63, l15 = lane & 15, kq = lane >> 4;
    floatx4 acc[3][2] = {};
    #pragma unroll
    for (int p = 0; p < 2; p++) {
        bf16x8 bq[2];
        #pragma unroll
        for (int j = 0; j < 2; j++)
            bq[j] = *(const bf16x8*)(Ks + p * 4096 + (wave * 32 + j * 16 + l15) * 32 + kq * 8);
        #pragma unroll
        for (int i = 0; i < 3; i++) {
            bf16x8 aq = *(const bf16x8*)(Qs + p * 1536 + (i * 16 + l15) * 32 + kq * 8);
            #pragma unroll
            for (int j = 0; j < 2; j++)
                acc[i][j] = __builtin_amdgcn_mfma_f32_16x16x32_bf16(bq[j], aq, acc[i][j], 0, 0, 0);
        }
    }
    #pragma unroll
    for (int i = 0; i < 3; i++) {
        int u = i * 16 + l15;
        if (u < U) {
            int l = top[bh * U + u];
            float* dst = aout + ((size_t)(b * LL + l)) * DD;
            #pragma unroll
            for (int j = 0; j < 2; j++) {
                int n = n0 + wave * 32 + j * 16 + kq * 4;
                atomicAdd(dst + n,     acc[i][j][0]);
                atomicAdd(dst + n + 1, acc[i][j][1]);
                atomicAdd(dst + n + 2, acc[i][j][2]);
                atomicAdd(dst + n + 3, acc[i][j][3]);
            }
        }
    }
}

// ------------- LN1: x1 = LN(x + aout) -> bf16 ------------------------------
__global__ __launch_bounds__(256) void ln1_k(
    const float* __restrict__ x, const float* __restrict__ aout,
    const float* __restrict__ g, const float* __restrict__ bb,
    __bf16* __restrict__ x1h)
{
    __shared__ float red[256];
    int row = blockIdx.x, tid = threadIdx.x;
    size_t base = (size_t)row * DD;
    float h0 = x[base + tid] + aout[base + tid];
    float h1 = x[base + 256 + tid] + aout[base + 256 + tid];
    red[tid] = h0 + h1; __syncthreads();
    for (int s = 128; s > 0; s >>= 1) { if (tid < s) red[tid] += red[tid + s]; __syncthreads(); }
    float mean = red[0] * (1.0f / DD); __syncthreads();
    float d0 = h0 - mean, d1 = h1 - mean;
    red[tid] = d0 * d0 + d1 * d1; __syncthreads();
    for (int s = 128; s > 0; s >>= 1) { if (tid < s) red[tid] += red[tid + s]; __syncthreads(); }
    float rstd = rsqrtf(red[0] * (1.0f / DD) + 1e-5f);
    x1h[base + tid]       = (__bf16)(d0 * rstd * g[tid] + bb[tid]);
    x1h[base + 256 + tid] = (__bf16)(d1 * rstd * g[256 + tid] + bb[256 + tid]);
}

// ------------- LN2: out = LN(x1 + ffn2 + b2) -> fp32 -----------------------
__global__ __launch_bounds__(256) void ln2_k(
    const __bf16* __restrict__ x1h, const float* __restrict__ f2o,
    const float* __restrict__ c2b,
    const float* __restrict__ g, const float* __restrict__ bb,
    float* __restrict__ out)
{
    __shared__ float red[256];
    int row = blockIdx.x, tid = threadIdx.x;
    size_t base = (size_t)row * DD;
    float h0 = (float)x1h[base + tid] + f2o[base + tid] + c2b[tid];
    float h1 = (float)x1h[base + 256 + tid] + f2o[base + 256 + tid] + c2b[256 + tid];
    red[tid] = h0 + h1; __syncthreads();
    for (int s = 128; s > 0; s >>= 1) { if (tid < s) red[tid] += red[tid + s]; __syncthreads(); }
    float mean = red[0] * (1.0f / DD); __syncthreads();
    float d0 = h0 - mean, d1 = h1 - mean;
    red[tid] = d0 * d0 + d1 * d1; __syncthreads();
    for (int s = 128; s > 0; s >>= 1) { if (tid < s) red[tid] += red[tid + s]; __syncthreads(); }
    float rstd = rsqrtf(red[0] * (1.0f / DD) + 1e-5f);
    out[base + tid]       = d0 * rstd * g[tid] + bb[tid];
    out[base + 256 + tid] = d1 * rstd * g[256 + tid] + bb[256 + tid];
}

// ---------------------------------------------------------------------------
extern "C" void kernel_launch(void* const* d_in, const int* in_sizes, int n_in,
                              void* d_out, int out_size, void* d_ws, size_t ws_size,
                              hipStream_t stream)
{
    const float* x   = (const float*)d_in[0];
    const float* Wq  = (const float*)d_in[1];
    const float* Wk  = (const float*)d_in[2];
    const float* Wv  = (const float*)d_in[3];
    const float* Wo  = (const float*)d_in[4];
    const float* g1  = (const float*)d_in[5];
    const float* b1  = (const float*)d_in[6];
    const float* c1w = (const float*)d_in[7];
    const float* c1b = (const float*)d_in[8];
    const float* c2w = (const float*)d_in[9];
    const float* c2b = (const float*)d_in[10];
    const float* g2  = (const float*)d_in[11];
    const float* b2  = (const float*)d_in[12];
    const int* sidx  = (const int*)d_in[13];
    float* out       = (float*)d_out;

    const int U = in_sizes[13] / LL;            // 40
    const int M = BB * LL;                       // 8192

    char* ws = (char*)d_ws;
    const size_t MB = (size_t)1 << 20;
    float*  Q    = (float*)(ws + 0);
    float*  Kb   = (float*)(ws + 16 * MB);
    __bf16* V    = (__bf16*)(ws + 32 * MB);
    __bf16* xhi  = (__bf16*)(ws + 40 * MB);
    __bf16* xlo  = (__bf16*)(ws + 48 * MB);
    float*  S    = (float*)(ws + 40 * MB);          // 32*48*2048*4 = 12.6 MB
    __bf16* wb   = (__bf16*)(ws + 56 * MB);
    __bf16* c1wb = (__bf16*)(ws + 59 * MB);
    __bf16* c2wb = (__bf16*)(ws + 61 * MB);
    float*  Mo   = (float*)(ws + 63 * MB);
    float*  upd  = (float*)(ws + 63 * MB + 256 * 1024);
    float*  Vm   = (float*)(ws + 63 * MB + 576 * 1024);
    int*    top  = (int*)  (ws + 63 * MB + 584 * 1024);
    __bf16* qred = (__bf16*)(ws + 63 * MB + 592 * 1024);  // 192K
    __bf16* aw   = (__bf16*)(ws + 63 * MB + 784 * 1024);  // 192K
    float*  basep= (float*)(ws + 63 * MB + 976 * 1024);   // 8K
    float*  aout = Q;                               // alias: Q dead after gather_qred
    float*  f2o  = Q;                               // alias: aout dead after ln1
    __bf16* ych  = (__bf16*)(ws + 16 * MB);         // FFN intermediate (32 MB region)
    __bf16* x1h  = xlo;                             // alias: S/P dead by ln1
    (void)ws_size; (void)n_in; (void)out_size;

    const size_t SZ = (size_t)DD * DD;
    __bf16* WqkHi = wb;                  // [WqT; WkT] hi, 1024 rows
    __bf16* WqkLo = wb + 2 * SZ;         // [WqT; WkT] lo
    __bf16* WvT   = wb + 4 * SZ;
    __bf16* WoT   = wb + 5 * SZ;

    // 1) weight prep + input split-cast
    prep_w<<<dim3(DD * DD / 256, 1, 4), 256, 0, stream>>>(Wq, Wk, Wv, Wo, wb);
    cast_cw<<<dim3(FF * DD / 256, 1, 2), 256, 0, stream>>>(c1w, c2w, c1wb, c2wb);
    split_cast_x<<<BB * LL * DD / 256, 256, 0, stream>>>(x, xhi, xlo);

    // 2) fused Q+K+V projection: B = [Wqk split (1024) | WvT bf16 (512)];
    //    3072 blocks, x staged once for all three outputs
    dim3 gqkv((3 * DD) / 64, M / 64);
    gemm_split_qkv<<<gqkv, 256, 0, stream>>>(xhi, xlo, WqkHi, WqkLo, WvT,
                                             Q, Kb, V, M, DD);

    // 3) sampled sparsity measure M, top-k, V mean (+ zero upd for pv atomics)
    calc_m<<<BB * LL, 256, 0, stream>>>(Q, Kb, sidx, Mo, U);
    zero_upd<<<(BB * HH * U * DKK + 255) / 256, 256, 0, stream>>>(upd, BB * HH * U * DKK);
    topk_k<<<BB * HH, 256, 0, stream>>>(Mo, top, U);
    vmean_k<<<BB * HH, 256, 0, stream>>>(V, Vm);

    // 4) attention: gather -> batched MFMA S -> softmax(in-place bf16 P) -> PV
    gather_qred<<<dim3(48 * DKK / 256, BB * HH), 256, 0, stream>>>(Q, top, qred, U);
    gemm_s<<<dim3(LL / 128, BB * HH), 256, 0, stream>>>(qred, Kb, S);
    softmax_p<<<BB * HH * U, 256, 0, stream>>>(S, U);
    pv_k<<<dim3(U / 4, 4, BB * HH), 256, 0, stream>>>(S, V, upd, U);

    // 5) out-projection via base + rank-U correction (Wo-GEMM eliminated)
    base_k<<<dim3(16, BB), 256, 0, stream>>>(Vm, Wo, basep);
    aw_prep<<<BB * HH, 256, 0, stream>>>(upd, Vm, aw, U);
    aout_init<<<M * DD / 256, 256, 0, stream>>>(basep, aout);
    corr_gemm<<<dim3(DD / 128, BB * HH), 256, 0, stream>>>(aw, WoT, top, aout, U);

    // 6) LN1 -> x1h bf16 (aliases xlo; S/P dead)
    ln1_k<<<M, 256, 0, stream>>>(x, aout, g1, b1, x1h);

    // 7) FFN: gelu(x1 @ c1w^T + c1b) -> ych bf16 (BM=128, 1024 blocks = 4/CU);
    //    ych @ c2w^T -> f2o (64x64 tile: 1024 blocks = 4 blocks/CU)
    gemm_mfma<3, 1, true,  true ><<<dim3(FF / 128, M / 128), 256, 0, stream>>>(x1h, c1wb, c1b, ych, M, FF, DD);
    dim3 gsq(DD / 64, M / 64);
    gemm_sq64<4, 0, false, false><<<gsq, 256, 0, stream>>>(ych, c2wb, nullptr, f2o, M, DD, FF);

    // 8) LN2 -> fp32 output
    ln2_k<<<M, 256, 0, stream>>>(x1h, f2o, c2b, g2, b2, out);
}